// Round 1
// baseline (354.749 us; speedup 1.0000x reference)
//
#include <hip/hip_runtime.h>
#include <hip/hip_bf16.h>

typedef __hip_bfloat16 bf16;
typedef __bf16 bf16x8 __attribute__((ext_vector_type(8)));
typedef float f32x4 __attribute__((ext_vector_type(4)));

#define LQ 1024
#define SK 1024
#define MMEM 256
#define NB 8
#define EE 512
#define NH 8
#define HD 64
#define NBH 64  // NB*NH batched (n,h) pairs

__device__ inline __bf16 tobf(float f) {
  __hip_bfloat16 h = __float2bfloat16(f);
  return *reinterpret_cast<__bf16*>(&h);
}
__device__ inline float bf2f(__bf16 x) {
  unsigned short u; __builtin_memcpy(&u, &x, 2);
  unsigned int v = (unsigned int)u << 16;
  float f; __builtin_memcpy(&f, &v, 4);
  return f;
}
__device__ inline f32x4 MFMA(bf16x8 a, bf16x8 b, f32x4 c) {
  return __builtin_amdgcn_mfma_f32_16x16x32_bf16(a, b, c, 0, 0, 0);
}

// async global->LDS, 16B per lane. LDS dest is wave-uniform base + lane*16.
__device__ inline void gload_lds16(const bf16* g, void* l) {
  __builtin_amdgcn_global_load_lds(
      (const __attribute__((address_space(1))) void*)g,
      (__attribute__((address_space(3))) void*)l, 16, 0, 0);
}

__device__ inline bf16x8 load8(const float* p) {
  float4 a = *(const float4*)p;
  float4 b = *(const float4*)(p + 4);
  bf16x8 r;
  r[0] = tobf(a.x); r[1] = tobf(a.y); r[2] = tobf(a.z); r[3] = tobf(a.w);
  r[4] = tobf(b.x); r[5] = tobf(b.y); r[6] = tobf(b.z); r[7] = tobf(b.w);
  return r;
}

// ================= bf16 pre-conversion of GEMM inputs ============================
#define CVT_T0 524288   // threads per q/k/v region (8 elems each)
#define CVT_T3 98304    // ipw
#define CVT_T4 32768    // opw
__global__ __launch_bounds__(256) void convert5(
    const float* __restrict__ q, const float* __restrict__ k,
    const float* __restrict__ v, const float* __restrict__ w,
    const float* __restrict__ o, bf16* __restrict__ qc, bf16* __restrict__ kc,
    bf16* __restrict__ vc, bf16* __restrict__ wc, bf16* __restrict__ oc)
{
  long long t = (long long)blockIdx.x * 256 + threadIdx.x;
  const float* src; bf16* dst; long long idx;
  if (t < CVT_T0)               { src = q; dst = qc; idx = t; }
  else if (t < 2 * CVT_T0)      { src = k; dst = kc; idx = t - CVT_T0; }
  else if (t < 3 * CVT_T0)      { src = v; dst = vc; idx = t - 2 * CVT_T0; }
  else if (t < 3 * CVT_T0 + CVT_T3) { src = w; dst = wc; idx = t - 3 * CVT_T0; }
  else                          { src = o; dst = oc; idx = t - 3 * CVT_T0 - CVT_T3; }
  *(bf16x8*)(dst + idx * 8) = load8(src + idx * 8);
}

// ================= 3-in-1 projection GEMM, m97-structure =========================
// 128x128 tile, BK=64, 4 waves (2x2), each wave owns 64x64 output (4x4 frags).
// Staging via global_load_lds dwordx4 into LINEAR [128][64] LDS (no pad -- the
// instruction writes wave-uniform base + lane*16; padding would corrupt layout).
// z=0: Qh = rotary(q*scale) head-reshaped; z=1: Kh = rotary(k); z=2: v_raw plain.
__global__ __launch_bounds__(256) void gemm_proj3(
    const bf16* __restrict__ qc, const bf16* __restrict__ kc,
    const bf16* __restrict__ vc, const bf16* __restrict__ ipwb,
    const float* __restrict__ ipb, const float* __restrict__ rot_q,
    const float* __restrict__ rot_k, bf16* __restrict__ Qh,
    bf16* __restrict__ Kh, bf16* __restrict__ v_raw)
{
  // 33792 B: staging uses [0,32768) as As[128][64] + Bs[128][64];
  // epilogue reuses all of it as Cs[128][132] (pad 4 -> 2-way max on read).
  __shared__ __align__(16) char smem[33792];
  __bf16* As = (__bf16*)smem;             // [128][64] linear, 16384 B
  __bf16* Bs = (__bf16*)(smem + 16384);   // [128][64] linear, 16384 B
  const int z = blockIdx.z;
  const bf16* A = (z == 0) ? qc : (z == 1) ? kc : vc;
  const bf16* W = ipwb + (long long)z * EE * EE;
  const float* bias = ipb + z * EE;
  const float alpha = (z == 0) ? 0.125f : 1.f;
  const int tm0 = blockIdx.y << 7, tn0 = blockIdx.x << 7;  // 128 x 128
  const int t = threadIdx.x;
  const int wave = t >> 6, lane = t & 63;
  const int wrow0 = (wave & 1) << 6, wcol0 = (wave >> 1) << 6;
  const int m16 = lane & 15, quad = lane >> 4;

  const f32x4 zero = {0.f, 0.f, 0.f, 0.f};
  f32x4 acc[4][4];
#pragma unroll
  for (int mi = 0; mi < 4; ++mi)
#pragma unroll
    for (int ni = 0; ni < 4; ++ni) acc[mi][ni] = zero;

  const bf16* Ab = A + (long long)tm0 * EE;
  const bf16* Bb = W + (long long)tn0 * EE;
  const int ob_u = wave << 10;  // wave-uniform byte base within 4KB chunk

  for (int k0 = 0; k0 < EE; k0 += 64) {
    // stage A/B tiles: 16KB each = 4 chunks of 4KB (1KB per wave per chunk)
#pragma unroll
    for (int c = 0; c < 4; ++c) {
      int ob = (c << 12) + ob_u;          // uniform LDS byte base
      int obl = ob + (lane << 4);         // this lane's slot
      int row = obl >> 7;                 // tile row (stride 128 B)
      int ce = (obl & 127) >> 1;          // element within row
      gload_lds16(Ab + (long long)row * EE + k0 + ce, smem + ob);
      gload_lds16(Bb + (long long)row * EE + k0 + ce, smem + 16384 + ob);
    }
    __syncthreads();   // compiler emits vmcnt(0) drain here
#pragma unroll
    for (int kh = 0; kh < 2; ++kh) {
      bf16x8 av[4], bv[4];
#pragma unroll
      for (int i = 0; i < 4; ++i) {
        av[i] = *(bf16x8*)(As + ((wrow0 + (i << 4) + m16) << 6) + (kh << 5) + (quad << 3));
        bv[i] = *(bf16x8*)(Bs + ((wcol0 + (i << 4) + m16) << 6) + (kh << 5) + (quad << 3));
      }
#pragma unroll
      for (int mi = 0; mi < 4; ++mi)
#pragma unroll
        for (int ni = 0; ni < 4; ++ni)
          acc[mi][ni] = MFMA(av[mi], bv[ni], acc[mi][ni]);
    }
    __syncthreads();
  }

  // ---- epilogue: stage full 128x128 C in LDS, fuse bias/scale, then rotary ----
  __bf16 (*Cs)[132] = (__bf16(*)[132])smem;
#pragma unroll
  for (int mi = 0; mi < 4; ++mi)
#pragma unroll
    for (int ni = 0; ni < 4; ++ni) {
      int col = wcol0 + (ni << 4) + m16;
      float bv = bias[tn0 + col];
#pragma unroll
      for (int r = 0; r < 4; ++r)
        Cs[wrow0 + (mi << 4) + (quad << 2) + r][col] =
            tobf((acc[mi][ni][r] + bv) * alpha);
    }
  __syncthreads();

  const int crow = t >> 1, ch0 = (t & 1) << 6;   // 2 threads/row, 64 cols each
  const int grow = tm0 + crow;                   // = l*NB + n
  if (z == 2) {
    long long gb = (long long)grow * EE + tn0 + ch0;
#pragma unroll
    for (int j = 0; j < 64; j += 8)
      *(uint4*)(v_raw + gb + j) = *(uint4*)&Cs[crow][ch0 + j];
  } else {
    const int l = grow >> 3, n = grow & 7;
    const float* rot = (z == 0) ? rot_q : rot_k;
    bf16* Out2 = (z == 0) ? Qh : Kh;
#pragma unroll
    for (int cc = 0; cc < 4; ++cc) {             // 4 chunks of 16 cols
      int e0 = tn0 + ch0 + (cc << 4);            // multiple of 16
      int h = e0 >> 6, d0 = e0 & 63;
      const float* rp = rot + ((((long long)n * LQ + l) * EE + e0) << 1);
      __bf16 vals[16];
#pragma unroll
      for (int j = 0; j < 16; j += 2) {
        float4 cs4 = *(const float4*)(rp + (j << 1));  // c0,s0,c1,s1
        float x0 = bf2f(Cs[crow][ch0 + (cc << 4) + j]);
        float x1 = bf2f(Cs[crow][ch0 + (cc << 4) + j + 1]);
        vals[j]     = tobf(x0 * cs4.x - x1 * cs4.y);
        vals[j + 1] = tobf(x1 * cs4.z + x0 * cs4.w);
      }
      bf16* dst = Out2 + ((((long long)(n * NH + h) * LQ) + l) * HD + d0);
      *(uint4*)dst = *(uint4*)&vals[0];
      *(uint4*)(dst + 8) = *(uint4*)&vals[8];
    }
  }
}

// ================= colsum: csum[b][s] = sum_l exp(Q[l]·K[s]) (no P write) ========
__global__ __launch_bounds__(256) void colsum_kernel(
    const bf16* __restrict__ Qh, const bf16* __restrict__ Kh,
    float* __restrict__ csum)
{
  __shared__ __align__(16) __bf16 Ks[64][72];
  __shared__ __align__(16) __bf16 Qs[64][72];
  __shared__ float cpart[64][2];
  const int b = blockIdx.y;
  const int st0 = blockIdx.x << 6;
  const int t = threadIdx.x;
  const int lrow = t >> 2, lcol = (t & 3) << 4;
  const int wave = t >> 6, lane = t & 63;
  const int wm = (wave & 1) << 5, wn = (wave >> 1) << 5;
  const int m16 = lane & 15, quad = lane >> 4;

  {
    const bf16* kp = Kh + ((long long)b * SK + st0 + lrow) * HD + lcol;
    *(bf16x8*)&Ks[lrow][lcol] = *(const bf16x8*)kp;
    *(bf16x8*)&Ks[lrow][lcol + 8] = *(const bf16x8*)(kp + 8);
  }
  __syncthreads();
  bf16x8 bk[2][2];   // [ni][kh]
#pragma unroll
  for (int ni = 0; ni < 2; ++ni)
#pragma unroll
    for (int kh = 0; kh < 2; ++kh)
      bk[ni][kh] = *(bf16x8*)&Ks[wn + (ni << 4) + m16][(kh << 5) + (quad << 3)];
  __syncthreads();

  const f32x4 zero = {0.f, 0.f, 0.f, 0.f};
  float colp[2] = {0.f, 0.f};
  for (int lt = 0; lt < 16; ++lt) {
    const bf16* qp = Qh + ((long long)b * LQ + (lt << 6) + lrow) * HD + lcol;
    *(bf16x8*)&Qs[lrow][lcol] = *(const bf16x8*)qp;
    *(bf16x8*)&Qs[lrow][lcol + 8] = *(const bf16x8*)(qp + 8);
    __syncthreads();
    f32x4 s00 = zero, s01 = zero, s10 = zero, s11 = zero;
#pragma unroll
    for (int kh = 0; kh < 2; ++kh) {
      bf16x8 a0 = *(bf16x8*)&Qs[wm + m16][(kh << 5) + (quad << 3)];
      bf16x8 a1 = *(bf16x8*)&Qs[wm + 16 + m16][(kh << 5) + (quad << 3)];
      s00 = MFMA(a0, bk[0][kh], s00);
      s01 = MFMA(a0, bk[1][kh], s01);
      s10 = MFMA(a1, bk[0][kh], s10);
      s11 = MFMA(a1, bk[1][kh], s11);
    }
    f32x4 sacc[2][2] = {{s00, s01}, {s10, s11}};
#pragma unroll
    for (int mi = 0; mi < 2; ++mi)
#pragma unroll
      for (int ni = 0; ni < 2; ++ni)
#pragma unroll
        for (int r = 0; r < 4; ++r)
          colp[ni] += __expf(sacc[mi][ni][r]);
    __syncthreads();
  }
  for (int ni = 0; ni < 2; ++ni) {
    float v = colp[ni];
    v += __shfl_down(v, 32, 64);
    v += __shfl_down(v, 16, 64);
    if (quad == 0) cpart[wn + (ni << 4) + m16][wm >> 5] = v;
  }
  __syncthreads();
  if (t < 64) csum[b * SK + st0 + t] = cpart[t][0] + cpart[t][1];
}

// ================= Vsum[b][d] = sum_s Vt[b][d][s] ================================
__global__ __launch_bounds__(256) void vsum_kernel(
    const bf16* __restrict__ Vt, float* __restrict__ Vsum)
{
  int wid = blockIdx.x * 4 + (threadIdx.x >> 6);
  int lane = threadIdx.x & 63;
  const bf16* p = Vt + (long long)wid * SK + lane * 16;
  float s = 0.f;
  bf16x8 v0 = *(const bf16x8*)p;
  bf16x8 v1 = *(const bf16x8*)(p + 8);
#pragma unroll
  for (int j = 0; j < 8; ++j) s += bf2f(v0[j]) + bf2f(v1[j]);
  for (int off = 32; off; off >>= 1) s += __shfl_down(s, off, 64);
  if (lane == 0) Vsum[wid] = s;
}

// ================= flash slot-attn: recompute scores, normalize, @V ==============
__global__ __launch_bounds__(256) void attn_flash(
    const bf16* __restrict__ Qh, const bf16* __restrict__ Kh,
    const bf16* __restrict__ Vt, const float* __restrict__ csum,
    const float* __restrict__ Vsum, bf16* __restrict__ attn)
{
  __shared__ __align__(16) __bf16 Ks[64][72];
  __shared__ __align__(16) __bf16 Vs[64][72];
  __shared__ __align__(16) __bf16 Ps[64][72];
  __shared__ float rcs[SK];
  __shared__ float rpart[64][2];
  const int b = blockIdx.y;
  const int tm0 = blockIdx.x << 6;
  const int t = threadIdx.x;
  const int lrow = t >> 2, lcol = (t & 3) << 4;
  const int wave = t >> 6, lane = t & 63;
  const int wm = (wave & 1) << 5, wn = (wave >> 1) << 5;
  const int m16 = lane & 15, quad = lane >> 4;

#pragma unroll
  for (int i = 0; i < 4; ++i)
    rcs[t + i * 256] = 1.f / csum[b * SK + t + i * 256];
  {
    const bf16* qp = Qh + ((long long)b * LQ + tm0 + lrow) * HD + lcol;
    *(bf16x8*)&Ks[lrow][lcol] = *(const bf16x8*)qp;
    *(bf16x8*)&Ks[lrow][lcol + 8] = *(const bf16x8*)(qp + 8);
  }
  __syncthreads();
  bf16x8 aq[2][2];
#pragma unroll
  for (int mi = 0; mi < 2; ++mi)
#pragma unroll
    for (int kh = 0; kh < 2; ++kh)
      aq[mi][kh] = *(bf16x8*)&Ks[wm + (mi << 4) + m16][(kh << 5) + (quad << 3)];
  __syncthreads();

  const f32x4 zero = {0.f, 0.f, 0.f, 0.f};
  f32x4 o00 = zero, o01 = zero, o10 = zero, o11 = zero;
  float rsumr[2][4] = {{0.f, 0.f, 0.f, 0.f}, {0.f, 0.f, 0.f, 0.f}};

  for (int st = 0; st < 16; ++st) {
    const bf16* kp = Kh + ((long long)b * SK + (st << 6) + lrow) * HD + lcol;
    *(bf16x8*)&Ks[lrow][lcol] = *(const bf16x8*)kp;
    *(bf16x8*)&Ks[lrow][lcol + 8] = *(const bf16x8*)(kp + 8);
    const bf16* vp = Vt + ((long long)b * HD + lrow) * SK + (st << 6) + lcol;
    *(bf16x8*)&Vs[lrow][lcol] = *(const bf16x8*)vp;
    *(bf16x8*)&Vs[lrow][lcol + 8] = *(const bf16x8*)(vp + 8);
    __syncthreads();
    f32x4 s00 = zero, s01 = zero, s10 = zero, s11 = zero;
#pragma unroll
    for (int kh = 0; kh < 2; ++kh) {
      bf16x8 b0 = *(bf16x8*)&Ks[wn + m16][(kh << 5) + (quad << 3)];
      bf16x8 b1 = *(bf16x8*)&Ks[wn + 16 + m16][(kh << 5) + (quad << 3)];
      s00 = MFMA(aq[0][kh], b0, s00);
      s01 = MFMA(aq[0][kh], b1, s01);
      s10 = MFMA(aq[1][kh], b0, s10);
      s11 = MFMA(aq[1][kh], b1, s11);
    }
    f32x4 sacc[2][2] = {{s00, s01}, {s10, s11}};
#pragma unroll
    for (int mi = 0; mi < 2; ++mi)
#pragma unroll
      for (int ni = 0; ni < 2; ++ni) {
        int col = wn + (ni << 4) + m16;
        float rc = rcs[(st << 6) + col];
#pragma unroll
        for (int r = 0; r < 4; ++r) {
          float p = __expf(sacc[mi][ni][r]) * rc;
          rsumr[mi][r] += p;
          Ps[wm + (mi << 4) + (quad << 2) + r][col] = tobf(p);
        }
      }
    __syncthreads();
#pragma unroll
    for (int kh = 0; kh < 2; ++kh) {
      bf16x8 ap0 = *(bf16x8*)&Ps[wm + m16][(kh << 5) + (quad << 3)];
      bf16x8 ap1 = *(bf16x8*)&Ps[wm + 16 + m16][(kh << 5) + (quad << 3)];
      bf16x8 bv0 = *(bf16x8*)&Vs[wn + m16][(kh << 5) + (quad << 3)];
      bf16x8 bv1 = *(bf16x8*)&Vs[wn + 16 + m16][(kh << 5) + (quad << 3)];
      o00 = MFMA(ap0, bv0, o00);
      o01 = MFMA(ap0, bv1, o01);
      o10 = MFMA(ap1, bv0, o10);
      o11 = MFMA(ap1, bv1, o11);
    }
    __syncthreads();
  }
#pragma unroll
  for (int mi = 0; mi < 2; ++mi)
#pragma unroll
    for (int r = 0; r < 4; ++r) {
      float v = rsumr[mi][r];
      v += __shfl_xor(v, 1, 64);
      v += __shfl_xor(v, 2, 64);
      v += __shfl_xor(v, 4, 64);
      v += __shfl_xor(v, 8, 64);
      if (m16 == 0) rpart[wm + (mi << 4) + (quad << 2) + r][wn >> 5] = v;
    }
  __syncthreads();
  const float* vs = Vsum + b * HD;
  f32x4 oacc[2][2] = {{o00, o01}, {o10, o11}};
  for (int mi = 0; mi < 2; ++mi)
    for (int ni = 0; ni < 2; ++ni) {
      int col = wn + (ni << 4) + m16;
      float vsc = 1e-8f * vs[col];
      for (int r = 0; r < 4; ++r) {
        int row = wm + (mi << 4) + (quad << 2) + r;
        float rs = rpart[row][0] + rpart[row][1];
        Ps[row][col] = tobf((oacc[mi][ni][r] + vsc) / (rs + (float)SK * 1e-8f));
      }
    }
  __syncthreads();
  uint4 u0 = *(uint4*)&Ps[lrow][lcol];
  uint4 u1 = *(uint4*)&Ps[lrow][lcol + 8];
  long long gb = ((long long)b * LQ + tm0 + lrow) * HD + lcol;
  *(uint4*)(attn + gb) = u0;
  *(uint4*)(attn + gb + 8) = u1;
}

// ================= fully-fused mem branch (flash-style) ==========================
__global__ __launch_bounds__(256) void mem_flash(
    const bf16* __restrict__ Qh, const bf16* __restrict__ km,
    const bf16* __restrict__ vmt, const int* __restrict__ mask,
    bf16* __restrict__ omb)
{
  __shared__ __align__(16) __bf16 Ks[64][72];
  __shared__ __align__(16) __bf16 Vs[64][72];
  __shared__ __align__(16) __bf16 Ps[64][72];
  __shared__ float mskf[MMEM];
  __shared__ float rpart[64][2];
  const int b = blockIdx.y;
  const int n = b >> 3;
  const int tm0 = blockIdx.x << 6;
  const int t = threadIdx.x;
  const int wave = t >> 6, lane = t & 63;
  const int wm = (wave & 1) << 5, wn = (wave >> 1) << 5;
  const int m16 = lane & 15, quad = lane >> 4;
  const int lrow = t >> 2, lcol = (t & 3) << 4;

  mskf[t] = mask[n * MMEM + t] ? 0.f : 1.f;
  {
    const bf16* qp = Qh + ((long long)b * LQ + tm0 + lrow) * HD + lcol;
    *(bf16x8*)&Ks[lrow][lcol] = *(const bf16x8*)qp;
    *(bf16x8*)&Ks[lrow][lcol + 8] = *(const bf16x8*)(qp + 8);
  }
  __syncthreads();
  bf16x8 aq[2][2];
#pragma unroll
  for (int mi = 0; mi < 2; ++mi)
#pragma unroll
    for (int kh = 0; kh < 2; ++kh)
      aq[mi][kh] = *(bf16x8*)&Ks[wm + (mi << 4) + m16][(kh << 5) + (quad << 3)];
  __syncthreads();

  const f32x4 zero = {0.f, 0.f, 0.f, 0.f};
  f32x4 o00 = zero, o01 = zero, o10 = zero, o11 = zero;
  float rsumr[2][4] = {{0.f, 0.f, 0.f, 0.f}, {0.f, 0.f, 0.f, 0.f}};

  for (int mt = 0; mt < 4; ++mt) {
    const bf16* kp = km + ((long long)b * MMEM + (mt << 6) + lrow) * HD + lcol;
    *(bf16x8*)&Ks[lrow][lcol] = *(const bf16x8*)kp;
    *(bf16x8*)&Ks[lrow][lcol + 8] = *(const bf16x8*)(kp + 8);
    const bf16* vp = vmt + ((long long)b * HD + lrow) * MMEM + (mt << 6) + lcol;
    *(bf16x8*)&Vs[lrow][lcol] = *(const bf16x8*)vp;
    *(bf16x8*)&Vs[lrow][lcol + 8] = *(const bf16x8*)(vp + 8);
    __syncthreads();
    f32x4 s00 = zero, s01 = zero, s10 = zero, s11 = zero;
#pragma unroll
    for (int kh = 0; kh < 2; ++kh) {
      bf16x8 b0 = *(bf16x8*)&Ks[wn + m16][(kh << 5) + (quad << 3)];
      bf16x8 b1 = *(bf16x8*)&Ks[wn + 16 + m16][(kh << 5) + (quad << 3)];
      s00 = MFMA(aq[0][kh], b0, s00);
      s01 = MFMA(aq[0][kh], b1, s01);
      s10 = MFMA(aq[1][kh], b0, s10);
      s11 = MFMA(aq[1][kh], b1, s11);
    }
    f32x4 sacc[2][2] = {{s00, s01}, {s10, s11}};
#pragma unroll
    for (int mi = 0; mi < 2; ++mi)
#pragma unroll
      for (int ni = 0; ni < 2; ++ni) {
        int col = wn + (ni << 4) + m16;
        float mf = mskf[(mt << 6) + col];
#pragma unroll
        for (int r = 0; r < 4; ++r) {
          float p = __expf(sacc[mi][ni][r]) * mf;
          rsumr[mi][r] += p;
          Ps[wm + (mi << 4) + (quad << 2) + r][col] = tobf(p);
        }
      }
    __syncthreads();
#pragma unroll
    for (int kh = 0; kh < 2; ++kh) {
      bf16x8 ap0 = *(bf16x8*)&Ps[wm + m16][(kh << 5) + (quad << 3)];
      bf16x8 ap1 = *(bf16x8*)&Ps[wm + 16 + m16][(kh << 5) + (quad << 3)];
      bf16x8 bv0 = *(bf16x8*)&Vs[wn + m16][(kh << 5) + (quad << 3)];
      bf16x8 bv1 = *(bf16x8*)&Vs[wn + 16 + m16][(kh << 5) + (quad << 3)];
      o00 = MFMA(ap0, bv0, o00);
      o01 = MFMA(ap0, bv1, o01);
      o10 = MFMA(ap1, bv0, o10);
      o11 = MFMA(ap1, bv1, o11);
    }
    __syncthreads();
  }
#pragma unroll
  for (int mi = 0; mi < 2; ++mi)
#pragma unroll
    for (int r = 0; r < 4; ++r) {
      float v = rsumr[mi][r];
      v += __shfl_xor(v, 1, 64);
      v += __shfl_xor(v, 2, 64);
      v += __shfl_xor(v, 4, 64);
      v += __shfl_xor(v, 8, 64);
      if (m16 == 0) rpart[wm + (mi << 4) + (quad << 2) + r][wn >> 5] = v;
    }
  __syncthreads();
  f32x4 oacc[2][2] = {{o00, o01}, {o10, o11}};
  for (int mi = 0; mi < 2; ++mi)
    for (int ni = 0; ni < 2; ++ni) {
      int col = wn + (ni << 4) + m16;
      for (int r = 0; r < 4; ++r) {
        int row = wm + (mi << 4) + (quad << 2) + r;
        float rs = rpart[row][0] + rpart[row][1];
        Ps[row][col] = tobf(oacc[mi][ni][r] / rs);
      }
    }
  __syncthreads();
  uint4 u0 = *(uint4*)&Ps[lrow][lcol];
  uint4 u1 = *(uint4*)&Ps[lrow][lcol + 8];
  long long gb = ((long long)b * LQ + tm0 + lrow) * HD + lcol;
  *(uint4*)(omb + gb) = u0;
  *(uint4*)(omb + gb + 8) = u1;
}

// ================= out proj with fused gate-combine A (bf16 W) ===================
__global__ __launch_bounds__(256) void gemm_out(
    const bf16* __restrict__ attn, const bf16* __restrict__ omb,
    const float* __restrict__ gate, const bf16* __restrict__ opwb,
    const float* __restrict__ opb, float* __restrict__ out)
{
  __shared__ __align__(16) __bf16 As[64][40];
  __shared__ __align__(16) __bf16 Bs[64][40];
  __shared__ float sg[NH];
  const int tm0 = blockIdx.y << 6, tn0 = blockIdx.x << 6;
  const int t = threadIdx.x;
  const int lrow = t >> 2, lk = (t & 3) << 3;
  const int wave = t >> 6, lane = t & 63;
  const int wm = (wave & 1) << 5, wn = (wave >> 1) << 5;
  const int m16 = lane & 15, quad = lane >> 4;

  if (t < NH) sg[t] = 1.f / (1.f + __expf(-gate[t]));
  __syncthreads();

  const f32x4 zero = {0.f, 0.f, 0.f, 0.f};
  f32x4 acc00 = zero, acc01 = zero, acc10 = zero, acc11 = zero;

  const int row = tm0 + lrow;
  const int l = row >> 3, n = row & 7;
  const bf16* bg = opwb + (long long)(tn0 + lrow) * EE + lk;
  for (int k0 = 0; k0 < EE; k0 += 32) {
    int e = k0 + lk;
    int h = e >> 6, d = e & 63;
    float g = sg[h];
    long long src = (((long long)(n * NH + h) * LQ) + l) * HD + d;
    bf16x8 a8 = *(const bf16x8*)(attn + src);
    bf16x8 o8 = *(const bf16x8*)(omb + src);
    bf16x8 ap;
#pragma unroll
    for (int j = 0; j < 8; ++j)
      ap[j] = tobf(g * bf2f(o8[j]) + (1.f - g) * bf2f(a8[j]));
    *(bf16x8*)&As[lrow][lk] = ap;
    *(bf16x8*)&Bs[lrow][lk] = *(const bf16x8*)(bg + k0);
    __syncthreads();
    bf16x8 a0 = *(bf16x8*)&As[wm + m16][quad << 3];
    bf16x8 a1 = *(bf16x8*)&As[wm + 16 + m16][quad << 3];
    bf16x8 b0 = *(bf16x8*)&Bs[wn + m16][quad << 3];
    bf16x8 b1 = *(bf16x8*)&Bs[wn + 16 + m16][quad << 3];
    acc00 = MFMA(a0, b0, acc00);
    acc01 = MFMA(a0, b1, acc01);
    acc10 = MFMA(a1, b0, acc10);
    acc11 = MFMA(a1, b1, acc11);
    __syncthreads();
  }
  f32x4 accs[2][2] = {{acc00, acc01}, {acc10, acc11}};
  for (int mi = 0; mi < 2; ++mi)
    for (int ni = 0; ni < 2; ++ni) {
      int col = tn0 + wn + (ni << 4) + m16;
      float bv = opb[col];
      long long base = (long long)(tm0 + wm + (mi << 4) + (quad << 2)) * EE + col;
      for (int r = 0; r < 4; ++r)
        out[base + (long long)r * EE] = accs[mi][ni][r] + bv;
    }
}

// ================= elementwise prep kernels ======================================
__global__ __launch_bounds__(256) void v_transpose(
    const bf16* __restrict__ raw, bf16* __restrict__ Vt)
{
  long long i = (long long)blockIdx.x * 256 + threadIdx.x;
  int e = (int)(i & 511);
  long long t2 = i >> 9;
  int n = (int)(t2 & 7);
  int s = (int)(t2 >> 3);
  int h = e >> 6, d = e & 63;
  Vt[(((long long)(n * NH + h) * HD) + d) * SK + s] = raw[i];
}

__global__ __launch_bounds__(256) void mem_prep(
    const float* __restrict__ k_mem, const float* __restrict__ v_mem,
    bf16* __restrict__ km, bf16* __restrict__ vmt)
{
  long long i = (long long)blockIdx.x * 256 + threadIdx.x;
  int e = (int)(i & 511);
  long long t2 = i >> 9;
  int n = (int)(t2 & 7);
  int m = (int)(t2 >> 3);
  int h = e >> 6, d = e & 63;
  km[(((long long)(n * NH + h) * MMEM) + m) * HD + d] = (bf16)k_mem[i];
  vmt[(((long long)(n * NH + h) * HD) + d) * MMEM + m] = (bf16)v_mem[i];
}

extern "C" void kernel_launch(void* const* d_in, const int* in_sizes, int n_in,
                              void* d_out, int out_size, void* d_ws, size_t ws_size,
                              hipStream_t stream) {
  const float* query = (const float*)d_in[0];
  const float* key   = (const float*)d_in[1];
  const float* value = (const float*)d_in[2];
  const float* ipw   = (const float*)d_in[3];
  const float* ipb   = (const float*)d_in[4];
  const float* opw   = (const float*)d_in[5];
  const float* opb   = (const float*)d_in[6];
  const float* rot_q = (const float*)d_in[7];
  const float* rot_k = (const float*)d_in[8];
  const float* k_mem = (const float*)d_in[9];
  const float* v_mem = (const float*)d_in[10];
  const float* gate  = (const float*)d_in[11];
  const int*  mask   = (const int*)d_in[12];
  float* out = (float*)d_out;

  char* w = (char*)d_ws;
  size_t off = 0;
  auto carve = [&](size_t bytes) -> char* {
    char* p = w + off;
    off += (bytes + 255) & ~(size_t)255;
    return p;
  };
  bf16* qc    = (bf16*)carve((size_t)LQ * NB * EE * 2);
  bf16* kc    = (bf16*)carve((size_t)SK * NB * EE * 2);
  bf16* vc    = (bf16*)carve((size_t)SK * NB * EE * 2);
  bf16* ipwb  = (bf16*)carve((size_t)3 * EE * EE * 2);
  bf16* opwb  = (bf16*)carve((size_t)EE * EE * 2);
  bf16* v_raw = (bf16*)carve((size_t)SK * NB * EE * 2);
  bf16* Qh    = (bf16*)carve((size_t)NBH * LQ * HD * 2);
  bf16* Kh    = (bf16*)carve((size_t)NBH * SK * HD * 2);
  bf16* Vt    = (bf16*)carve((size_t)NBH * HD * SK * 2);
  bf16* km    = (bf16*)carve((size_t)NBH * MMEM * HD * 2);
  bf16* vmt   = (bf16*)carve((size_t)NBH * HD * MMEM * 2);
  float* csum = (float*)carve((size_t)NBH * SK * 4);
  float* Vsum = (float*)carve((size_t)NBH * HD * 4);
  bf16* attn  = (bf16*)carve((size_t)NBH * LQ * HD * 2);
  bf16* omb   = (bf16*)carve((size_t)NBH * LQ * HD * 2);
  if (off > ws_size) {
    hipMemsetAsync(d_out, 0, (size_t)out_size * 4, stream);
    return;
  }

  // 0) pre-convert GEMM inputs to bf16 (identical rounding point as before)
  convert5<<<(3 * CVT_T0 + CVT_T3 + CVT_T4) / 256, 256, 0, stream>>>(
      query, key, value, ipw, opw, qc, kc, vc, ipwb, opwb);

  // 1) q/k/v projections, 128x128 tiles (m97 structure), rotary fused
  gemm_proj3<<<dim3(EE / 128, (LQ * NB) / 128, 3), 256, 0, stream>>>(
      qc, kc, vc, ipwb, ipb, rot_q, rot_k, Qh, Kh, v_raw);

  // 2) v transpose (+Vsum); mem k/v repack
  v_transpose<<<(SK * NB * EE) / 256, 256, 0, stream>>>(v_raw, Vt);
  vsum_kernel<<<(NBH * HD) / 4, 256, 0, stream>>>(Vt, Vsum);
  mem_prep<<<(MMEM * NB * EE) / 256, 256, 0, stream>>>(k_mem, v_mem, km, vmt);

  // 3) column sums of exp(scores) -- no P materialization
  colsum_kernel<<<dim3(SK / 64, NBH), 256, 0, stream>>>(Qh, Kh, csum);

  // 4) flash-style slot attn (recompute scores) + mem branch
  attn_flash<<<dim3(LQ / 64, NBH), 256, 0, stream>>>(Qh, Kh, Vt, csum, Vsum, attn);
  mem_flash<<<dim3(LQ / 64, NBH), 256, 0, stream>>>(Qh, km, vmt, mask, omb);

  // 5) out-proj with fused sigmoid-gate combine (f32 out direct)
  gemm_out<<<dim3(EE / 64, (LQ * NB) / 64, 1), 256, 0, stream>>>(attn, omb, gate, opwb, opb, out);
}

// Round 2
// 330.431 us; speedup vs baseline: 1.0736x; 1.0736x over previous
//
#include <hip/hip_runtime.h>
#include <hip/hip_bf16.h>

typedef __hip_bfloat16 bf16;
typedef __bf16 bf16x8 __attribute__((ext_vector_type(8)));
typedef float f32x4 __attribute__((ext_vector_type(4)));

#define LQ 1024
#define SK 1024
#define MMEM 256
#define NB 8
#define EE 512
#define NH 8
#define HD 64
#define NBH 64  // NB*NH batched (n,h) pairs

__device__ inline __bf16 tobf(float f) {
  __hip_bfloat16 h = __float2bfloat16(f);
  return *reinterpret_cast<__bf16*>(&h);
}
__device__ inline float bf2f(__bf16 x) {
  unsigned short u; __builtin_memcpy(&u, &x, 2);
  unsigned int v = (unsigned int)u << 16;
  float f; __builtin_memcpy(&f, &v, 4);
  return f;
}
__device__ inline f32x4 MFMA(bf16x8 a, bf16x8 b, f32x4 c) {
  return __builtin_amdgcn_mfma_f32_16x16x32_bf16(a, b, c, 0, 0, 0);
}

// async global->LDS, 16B per lane. LDS dest is wave-uniform base + lane*16.
__device__ inline void gload_lds16(const bf16* g, void* l) {
  __builtin_amdgcn_global_load_lds(
      (const __attribute__((address_space(1))) void*)g,
      (__attribute__((address_space(3))) void*)l, 16, 0, 0);
}

__device__ inline bf16x8 load8(const float* p) {
  float4 a = *(const float4*)p;
  float4 b = *(const float4*)(p + 4);
  bf16x8 r;
  r[0] = tobf(a.x); r[1] = tobf(a.y); r[2] = tobf(a.z); r[3] = tobf(a.w);
  r[4] = tobf(b.x); r[5] = tobf(b.y); r[6] = tobf(b.z); r[7] = tobf(b.w);
  return r;
}

// ================= bf16 pre-conversion of GEMM inputs ============================
#define CVT_T0 524288   // threads per q/k/v region (8 elems each)
#define CVT_T3 98304    // ipw
#define CVT_T4 32768    // opw
__global__ __launch_bounds__(256) void convert5(
    const float* __restrict__ q, const float* __restrict__ k,
    const float* __restrict__ v, const float* __restrict__ w,
    const float* __restrict__ o, bf16* __restrict__ qc, bf16* __restrict__ kc,
    bf16* __restrict__ vc, bf16* __restrict__ wc, bf16* __restrict__ oc)
{
  long long t = (long long)blockIdx.x * 256 + threadIdx.x;
  const float* src; bf16* dst; long long idx;
  if (t < CVT_T0)               { src = q; dst = qc; idx = t; }
  else if (t < 2 * CVT_T0)      { src = k; dst = kc; idx = t - CVT_T0; }
  else if (t < 3 * CVT_T0)      { src = v; dst = vc; idx = t - 2 * CVT_T0; }
  else if (t < 3 * CVT_T0 + CVT_T3) { src = w; dst = wc; idx = t - 3 * CVT_T0; }
  else                          { src = o; dst = oc; idx = t - 3 * CVT_T0 - CVT_T3; }
  *(bf16x8*)(dst + idx * 8) = load8(src + idx * 8);
}

// ================= 3-in-1 projection GEMM, m97-structure, PURE GEMM ==============
// 128x128 tile, BK=64, 4 waves (2x2), each wave owns 64x64 output (4x4 frags).
// Staging via global_load_lds dwordx4 into LINEAR [128][64] LDS.
// Epilogue: bias+scale, row-major 128B-contiguous stores. Rotary is a separate
// streaming kernel (fusing it here made the kernel latency-bound on rot reads).
__global__ __launch_bounds__(256) void gemm_proj3(
    const bf16* __restrict__ qc, const bf16* __restrict__ kc,
    const bf16* __restrict__ vc, const bf16* __restrict__ ipwb,
    const float* __restrict__ ipb, bf16* __restrict__ pq,
    bf16* __restrict__ pk, bf16* __restrict__ v_raw)
{
  __shared__ __align__(16) char smem[33792];
  __bf16* As = (__bf16*)smem;             // [128][64] linear, 16384 B
  __bf16* Bs = (__bf16*)(smem + 16384);   // [128][64] linear, 16384 B
  const int z = blockIdx.z;
  const bf16* A = (z == 0) ? qc : (z == 1) ? kc : vc;
  const bf16* W = ipwb + (long long)z * EE * EE;
  const float* bias = ipb + z * EE;
  const float alpha = (z == 0) ? 0.125f : 1.f;
  const int tm0 = blockIdx.y << 7, tn0 = blockIdx.x << 7;  // 128 x 128
  const int t = threadIdx.x;
  const int wave = t >> 6, lane = t & 63;
  const int wrow0 = (wave & 1) << 6, wcol0 = (wave >> 1) << 6;
  const int m16 = lane & 15, quad = lane >> 4;

  const f32x4 zero = {0.f, 0.f, 0.f, 0.f};
  f32x4 acc[4][4];
#pragma unroll
  for (int mi = 0; mi < 4; ++mi)
#pragma unroll
    for (int ni = 0; ni < 4; ++ni) acc[mi][ni] = zero;

  const bf16* Ab = A + (long long)tm0 * EE;
  const bf16* Bb = W + (long long)tn0 * EE;
  const int ob_u = wave << 10;  // wave-uniform byte base within 4KB chunk

  for (int k0 = 0; k0 < EE; k0 += 64) {
#pragma unroll
    for (int c = 0; c < 4; ++c) {
      int ob = (c << 12) + ob_u;          // uniform LDS byte base
      int obl = ob + (lane << 4);         // this lane's slot
      int row = obl >> 7;                 // tile row (stride 128 B)
      int ce = (obl & 127) >> 1;          // element within row
      gload_lds16(Ab + (long long)row * EE + k0 + ce, smem + ob);
      gload_lds16(Bb + (long long)row * EE + k0 + ce, smem + 16384 + ob);
    }
    __syncthreads();
#pragma unroll
    for (int kh = 0; kh < 2; ++kh) {
      bf16x8 av[4], bv[4];
#pragma unroll
      for (int i = 0; i < 4; ++i) {
        av[i] = *(bf16x8*)(As + ((wrow0 + (i << 4) + m16) << 6) + (kh << 5) + (quad << 3));
        bv[i] = *(bf16x8*)(Bs + ((wcol0 + (i << 4) + m16) << 6) + (kh << 5) + (quad << 3));
      }
#pragma unroll
      for (int mi = 0; mi < 4; ++mi)
#pragma unroll
        for (int ni = 0; ni < 4; ++ni)
          acc[mi][ni] = MFMA(av[mi], bv[ni], acc[mi][ni]);
    }
    __syncthreads();
  }

  // ---- epilogue: stage C in LDS (bias+scale), then 128B-contiguous stores ----
  __bf16 (*Cs)[132] = (__bf16(*)[132])smem;
#pragma unroll
  for (int mi = 0; mi < 4; ++mi)
#pragma unroll
    for (int ni = 0; ni < 4; ++ni) {
      int col = wcol0 + (ni << 4) + m16;
      float bv = bias[tn0 + col];
#pragma unroll
      for (int r = 0; r < 4; ++r)
        Cs[wrow0 + (mi << 4) + (quad << 2) + r][col] =
            tobf((acc[mi][ni][r] + bv) * alpha);
    }
  __syncthreads();
  bf16* O = (z == 0) ? pq : (z == 1) ? pk : v_raw;
  const int crow = t >> 1, ch0 = (t & 1) << 6;   // 2 threads/row, 64 cols each
  long long gb = (long long)(tm0 + crow) * EE + tn0 + ch0;
#pragma unroll
  for (int j = 0; j < 64; j += 8)
    *(uint4*)(O + gb + j) = *(uint4*)&Cs[crow][ch0 + j];
}

// ================= rotary + head-reshape, pure streaming =========================
// blockIdx.y: 0 = q, 1 = k. Per block: 4 rows (l*8+n) of 512 elems.
// Reads 1KB/wave of proj, 4KB/wave of rot (f32), writes 8x128B head chunks.
__global__ __launch_bounds__(256) void rotary_kernel(
    const bf16* __restrict__ pq, const bf16* __restrict__ pk,
    const float* __restrict__ rot_q, const float* __restrict__ rot_k,
    bf16* __restrict__ Qh, bf16* __restrict__ Kh)
{
  const bf16* src = blockIdx.y ? pk : pq;
  const float* rot = blockIdx.y ? rot_k : rot_q;
  bf16* dst = blockIdx.y ? Kh : Qh;
  const int t = threadIdx.x;
  const int row = (blockIdx.x << 2) + (t >> 6);   // l*NB + n
  const int e0 = (t & 63) << 3;                   // 8 elems per lane
  const int l = row >> 3, n = row & 7;
  bf16x8 x = *(const bf16x8*)(src + (long long)row * EE + e0);
  const float* rp = rot + ((((long long)n * LQ + l) * EE + e0) << 1);
  __bf16 vals[8];
#pragma unroll
  for (int j = 0; j < 8; j += 2) {
    float4 cs4 = *(const float4*)(rp + (j << 1));  // c0,s0,c1,s1
    float x0 = bf2f(x[j]);
    float x1 = bf2f(x[j + 1]);
    vals[j]     = tobf(x0 * cs4.x - x1 * cs4.y);
    vals[j + 1] = tobf(x1 * cs4.z + x0 * cs4.w);
  }
  const int h = e0 >> 6, d0 = e0 & 63;
  *(uint4*)(dst + (((long long)(n * NH + h) * LQ + l) * HD + d0)) = *(uint4*)vals;
}

// ================= colsum: csum[b][s] = sum_l exp(Q[l]·K[s]) (no P write) ========
__global__ __launch_bounds__(256) void colsum_kernel(
    const bf16* __restrict__ Qh, const bf16* __restrict__ Kh,
    float* __restrict__ csum)
{
  __shared__ __align__(16) __bf16 Ks[64][72];
  __shared__ __align__(16) __bf16 Qs[64][72];
  __shared__ float cpart[64][2];
  const int b = blockIdx.y;
  const int st0 = blockIdx.x << 6;
  const int t = threadIdx.x;
  const int lrow = t >> 2, lcol = (t & 3) << 4;
  const int wave = t >> 6, lane = t & 63;
  const int wm = (wave & 1) << 5, wn = (wave >> 1) << 5;
  const int m16 = lane & 15, quad = lane >> 4;

  {
    const bf16* kp = Kh + ((long long)b * SK + st0 + lrow) * HD + lcol;
    *(bf16x8*)&Ks[lrow][lcol] = *(const bf16x8*)kp;
    *(bf16x8*)&Ks[lrow][lcol + 8] = *(const bf16x8*)(kp + 8);
  }
  __syncthreads();
  bf16x8 bk[2][2];   // [ni][kh]
#pragma unroll
  for (int ni = 0; ni < 2; ++ni)
#pragma unroll
    for (int kh = 0; kh < 2; ++kh)
      bk[ni][kh] = *(bf16x8*)&Ks[wn + (ni << 4) + m16][(kh << 5) + (quad << 3)];
  __syncthreads();

  const f32x4 zero = {0.f, 0.f, 0.f, 0.f};
  float colp[2] = {0.f, 0.f};
  for (int lt = 0; lt < 16; ++lt) {
    const bf16* qp = Qh + ((long long)b * LQ + (lt << 6) + lrow) * HD + lcol;
    *(bf16x8*)&Qs[lrow][lcol] = *(const bf16x8*)qp;
    *(bf16x8*)&Qs[lrow][lcol + 8] = *(const bf16x8*)(qp + 8);
    __syncthreads();
    f32x4 s00 = zero, s01 = zero, s10 = zero, s11 = zero;
#pragma unroll
    for (int kh = 0; kh < 2; ++kh) {
      bf16x8 a0 = *(bf16x8*)&Qs[wm + m16][(kh << 5) + (quad << 3)];
      bf16x8 a1 = *(bf16x8*)&Qs[wm + 16 + m16][(kh << 5) + (quad << 3)];
      s00 = MFMA(a0, bk[0][kh], s00);
      s01 = MFMA(a0, bk[1][kh], s01);
      s10 = MFMA(a1, bk[0][kh], s10);
      s11 = MFMA(a1, bk[1][kh], s11);
    }
    f32x4 sacc[2][2] = {{s00, s01}, {s10, s11}};
#pragma unroll
    for (int mi = 0; mi < 2; ++mi)
#pragma unroll
      for (int ni = 0; ni < 2; ++ni)
#pragma unroll
        for (int r = 0; r < 4; ++r)
          colp[ni] += __expf(sacc[mi][ni][r]);
    __syncthreads();
  }
  for (int ni = 0; ni < 2; ++ni) {
    float v = colp[ni];
    v += __shfl_down(v, 32, 64);
    v += __shfl_down(v, 16, 64);
    if (quad == 0) cpart[wn + (ni << 4) + m16][wm >> 5] = v;
  }
  __syncthreads();
  if (t < 64) csum[b * SK + st0 + t] = cpart[t][0] + cpart[t][1];
}

// ================= Vsum[b][d] = sum_s Vt[b][d][s] ================================
__global__ __launch_bounds__(256) void vsum_kernel(
    const bf16* __restrict__ Vt, float* __restrict__ Vsum)
{
  int wid = blockIdx.x * 4 + (threadIdx.x >> 6);
  int lane = threadIdx.x & 63;
  const bf16* p = Vt + (long long)wid * SK + lane * 16;
  float s = 0.f;
  bf16x8 v0 = *(const bf16x8*)p;
  bf16x8 v1 = *(const bf16x8*)(p + 8);
#pragma unroll
  for (int j = 0; j < 8; ++j) s += bf2f(v0[j]) + bf2f(v1[j]);
  for (int off = 32; off; off >>= 1) s += __shfl_down(s, off, 64);
  if (lane == 0) Vsum[wid] = s;
}

// ================= flash slot-attn: recompute scores, normalize, @V ==============
__global__ __launch_bounds__(256) void attn_flash(
    const bf16* __restrict__ Qh, const bf16* __restrict__ Kh,
    const bf16* __restrict__ Vt, const float* __restrict__ csum,
    const float* __restrict__ Vsum, bf16* __restrict__ attn)
{
  __shared__ __align__(16) __bf16 Ks[64][72];
  __shared__ __align__(16) __bf16 Vs[64][72];
  __shared__ __align__(16) __bf16 Ps[64][72];
  __shared__ float rcs[SK];
  __shared__ float rpart[64][2];
  const int b = blockIdx.y;
  const int tm0 = blockIdx.x << 6;
  const int t = threadIdx.x;
  const int lrow = t >> 2, lcol = (t & 3) << 4;
  const int wave = t >> 6, lane = t & 63;
  const int wm = (wave & 1) << 5, wn = (wave >> 1) << 5;
  const int m16 = lane & 15, quad = lane >> 4;

#pragma unroll
  for (int i = 0; i < 4; ++i)
    rcs[t + i * 256] = 1.f / csum[b * SK + t + i * 256];
  {
    const bf16* qp = Qh + ((long long)b * LQ + tm0 + lrow) * HD + lcol;
    *(bf16x8*)&Ks[lrow][lcol] = *(const bf16x8*)qp;
    *(bf16x8*)&Ks[lrow][lcol + 8] = *(const bf16x8*)(qp + 8);
  }
  __syncthreads();
  bf16x8 aq[2][2];
#pragma unroll
  for (int mi = 0; mi < 2; ++mi)
#pragma unroll
    for (int kh = 0; kh < 2; ++kh)
      aq[mi][kh] = *(bf16x8*)&Ks[wm + (mi << 4) + m16][(kh << 5) + (quad << 3)];
  __syncthreads();

  const f32x4 zero = {0.f, 0.f, 0.f, 0.f};
  f32x4 o00 = zero, o01 = zero, o10 = zero, o11 = zero;
  float rsumr[2][4] = {{0.f, 0.f, 0.f, 0.f}, {0.f, 0.f, 0.f, 0.f}};

  for (int st = 0; st < 16; ++st) {
    const bf16* kp = Kh + ((long long)b * SK + (st << 6) + lrow) * HD + lcol;
    *(bf16x8*)&Ks[lrow][lcol] = *(const bf16x8*)kp;
    *(bf16x8*)&Ks[lrow][lcol + 8] = *(const bf16x8*)(kp + 8);
    const bf16* vp = Vt + ((long long)b * HD + lrow) * SK + (st << 6) + lcol;
    *(bf16x8*)&Vs[lrow][lcol] = *(const bf16x8*)vp;
    *(bf16x8*)&Vs[lrow][lcol + 8] = *(const bf16x8*)(vp + 8);
    __syncthreads();
    f32x4 s00 = zero, s01 = zero, s10 = zero, s11 = zero;
#pragma unroll
    for (int kh = 0; kh < 2; ++kh) {
      bf16x8 b0 = *(bf16x8*)&Ks[wn + m16][(kh << 5) + (quad << 3)];
      bf16x8 b1 = *(bf16x8*)&Ks[wn + 16 + m16][(kh << 5) + (quad << 3)];
      s00 = MFMA(aq[0][kh], b0, s00);
      s01 = MFMA(aq[0][kh], b1, s01);
      s10 = MFMA(aq[1][kh], b0, s10);
      s11 = MFMA(aq[1][kh], b1, s11);
    }
    f32x4 sacc[2][2] = {{s00, s01}, {s10, s11}};
#pragma unroll
    for (int mi = 0; mi < 2; ++mi)
#pragma unroll
      for (int ni = 0; ni < 2; ++ni) {
        int col = wn + (ni << 4) + m16;
        float rc = rcs[(st << 6) + col];
#pragma unroll
        for (int r = 0; r < 4; ++r) {
          float p = __expf(sacc[mi][ni][r]) * rc;
          rsumr[mi][r] += p;
          Ps[wm + (mi << 4) + (quad << 2) + r][col] = tobf(p);
        }
      }
    __syncthreads();
#pragma unroll
    for (int kh = 0; kh < 2; ++kh) {
      bf16x8 ap0 = *(bf16x8*)&Ps[wm + m16][(kh << 5) + (quad << 3)];
      bf16x8 ap1 = *(bf16x8*)&Ps[wm + 16 + m16][(kh << 5) + (quad << 3)];
      bf16x8 bv0 = *(bf16x8*)&Vs[wn + m16][(kh << 5) + (quad << 3)];
      bf16x8 bv1 = *(bf16x8*)&Vs[wn + 16 + m16][(kh << 5) + (quad << 3)];
      o00 = MFMA(ap0, bv0, o00);
      o01 = MFMA(ap0, bv1, o01);
      o10 = MFMA(ap1, bv0, o10);
      o11 = MFMA(ap1, bv1, o11);
    }
    __syncthreads();
  }
#pragma unroll
  for (int mi = 0; mi < 2; ++mi)
#pragma unroll
    for (int r = 0; r < 4; ++r) {
      float v = rsumr[mi][r];
      v += __shfl_xor(v, 1, 64);
      v += __shfl_xor(v, 2, 64);
      v += __shfl_xor(v, 4, 64);
      v += __shfl_xor(v, 8, 64);
      if (m16 == 0) rpart[wm + (mi << 4) + (quad << 2) + r][wn >> 5] = v;
    }
  __syncthreads();
  const float* vs = Vsum + b * HD;
  f32x4 oacc[2][2] = {{o00, o01}, {o10, o11}};
  for (int mi = 0; mi < 2; ++mi)
    for (int ni = 0; ni < 2; ++ni) {
      int col = wn + (ni << 4) + m16;
      float vsc = 1e-8f * vs[col];
      for (int r = 0; r < 4; ++r) {
        int row = wm + (mi << 4) + (quad << 2) + r;
        float rs = rpart[row][0] + rpart[row][1];
        Ps[row][col] = tobf((oacc[mi][ni][r] + vsc) / (rs + (float)SK * 1e-8f));
      }
    }
  __syncthreads();
  uint4 u0 = *(uint4*)&Ps[lrow][lcol];
  uint4 u1 = *(uint4*)&Ps[lrow][lcol + 8];
  long long gb = ((long long)b * LQ + tm0 + lrow) * HD + lcol;
  *(uint4*)(attn + gb) = u0;
  *(uint4*)(attn + gb + 8) = u1;
}

// ================= fully-fused mem branch (flash-style) ==========================
__global__ __launch_bounds__(256) void mem_flash(
    const bf16* __restrict__ Qh, const bf16* __restrict__ km,
    const bf16* __restrict__ vmt, const int* __restrict__ mask,
    bf16* __restrict__ omb)
{
  __shared__ __align__(16) __bf16 Ks[64][72];
  __shared__ __align__(16) __bf16 Vs[64][72];
  __shared__ __align__(16) __bf16 Ps[64][72];
  __shared__ float mskf[MMEM];
  __shared__ float rpart[64][2];
  const int b = blockIdx.y;
  const int n = b >> 3;
  const int tm0 = blockIdx.x << 6;
  const int t = threadIdx.x;
  const int wave = t >> 6, lane = t & 63;
  const int wm = (wave & 1) << 5, wn = (wave >> 1) << 5;
  const int m16 = lane & 15, quad = lane >> 4;
  const int lrow = t >> 2, lcol = (t & 3) << 4;

  mskf[t] = mask[n * MMEM + t] ? 0.f : 1.f;
  {
    const bf16* qp = Qh + ((long long)b * LQ + tm0 + lrow) * HD + lcol;
    *(bf16x8*)&Ks[lrow][lcol] = *(const bf16x8*)qp;
    *(bf16x8*)&Ks[lrow][lcol + 8] = *(const bf16x8*)(qp + 8);
  }
  __syncthreads();
  bf16x8 aq[2][2];
#pragma unroll
  for (int mi = 0; mi < 2; ++mi)
#pragma unroll
    for (int kh = 0; kh < 2; ++kh)
      aq[mi][kh] = *(bf16x8*)&Ks[wm + (mi << 4) + m16][(kh << 5) + (quad << 3)];
  __syncthreads();

  const f32x4 zero = {0.f, 0.f, 0.f, 0.f};
  f32x4 o00 = zero, o01 = zero, o10 = zero, o11 = zero;
  float rsumr[2][4] = {{0.f, 0.f, 0.f, 0.f}, {0.f, 0.f, 0.f, 0.f}};

  for (int mt = 0; mt < 4; ++mt) {
    const bf16* kp = km + ((long long)b * MMEM + (mt << 6) + lrow) * HD + lcol;
    *(bf16x8*)&Ks[lrow][lcol] = *(const bf16x8*)kp;
    *(bf16x8*)&Ks[lrow][lcol + 8] = *(const bf16x8*)(kp + 8);
    const bf16* vp = vmt + ((long long)b * HD + lrow) * MMEM + (mt << 6) + lcol;
    *(bf16x8*)&Vs[lrow][lcol] = *(const bf16x8*)vp;
    *(bf16x8*)&Vs[lrow][lcol + 8] = *(const bf16x8*)(vp + 8);
    __syncthreads();
    f32x4 s00 = zero, s01 = zero, s10 = zero, s11 = zero;
#pragma unroll
    for (int kh = 0; kh < 2; ++kh) {
      bf16x8 b0 = *(bf16x8*)&Ks[wn + m16][(kh << 5) + (quad << 3)];
      bf16x8 b1 = *(bf16x8*)&Ks[wn + 16 + m16][(kh << 5) + (quad << 3)];
      s00 = MFMA(aq[0][kh], b0, s00);
      s01 = MFMA(aq[0][kh], b1, s01);
      s10 = MFMA(aq[1][kh], b0, s10);
      s11 = MFMA(aq[1][kh], b1, s11);
    }
    f32x4 sacc[2][2] = {{s00, s01}, {s10, s11}};
#pragma unroll
    for (int mi = 0; mi < 2; ++mi)
#pragma unroll
      for (int ni = 0; ni < 2; ++ni) {
        int col = wn + (ni << 4) + m16;
        float mf = mskf[(mt << 6) + col];
#pragma unroll
        for (int r = 0; r < 4; ++r) {
          float p = __expf(sacc[mi][ni][r]) * mf;
          rsumr[mi][r] += p;
          Ps[wm + (mi << 4) + (quad << 2) + r][col] = tobf(p);
        }
      }
    __syncthreads();
#pragma unroll
    for (int kh = 0; kh < 2; ++kh) {
      bf16x8 ap0 = *(bf16x8*)&Ps[wm + m16][(kh << 5) + (quad << 3)];
      bf16x8 ap1 = *(bf16x8*)&Ps[wm + 16 + m16][(kh << 5) + (quad << 3)];
      bf16x8 bv0 = *(bf16x8*)&Vs[wn + m16][(kh << 5) + (quad << 3)];
      bf16x8 bv1 = *(bf16x8*)&Vs[wn + 16 + m16][(kh << 5) + (quad << 3)];
      o00 = MFMA(ap0, bv0, o00);
      o01 = MFMA(ap0, bv1, o01);
      o10 = MFMA(ap1, bv0, o10);
      o11 = MFMA(ap1, bv1, o11);
    }
    __syncthreads();
  }
#pragma unroll
  for (int mi = 0; mi < 2; ++mi)
#pragma unroll
    for (int r = 0; r < 4; ++r) {
      float v = rsumr[mi][r];
      v += __shfl_xor(v, 1, 64);
      v += __shfl_xor(v, 2, 64);
      v += __shfl_xor(v, 4, 64);
      v += __shfl_xor(v, 8, 64);
      if (m16 == 0) rpart[wm + (mi << 4) + (quad << 2) + r][wn >> 5] = v;
    }
  __syncthreads();
  f32x4 oacc[2][2] = {{o00, o01}, {o10, o11}};
  for (int mi = 0; mi < 2; ++mi)
    for (int ni = 0; ni < 2; ++ni) {
      int col = wn + (ni << 4) + m16;
      for (int r = 0; r < 4; ++r) {
        int row = wm + (mi << 4) + (quad << 2) + r;
        float rs = rpart[row][0] + rpart[row][1];
        Ps[row][col] = tobf(oacc[mi][ni][r] / rs);
      }
    }
  __syncthreads();
  uint4 u0 = *(uint4*)&Ps[lrow][lcol];
  uint4 u1 = *(uint4*)&Ps[lrow][lcol + 8];
  long long gb = ((long long)b * LQ + tm0 + lrow) * HD + lcol;
  *(uint4*)(omb + gb) = u0;
  *(uint4*)(omb + gb + 8) = u1;
}

// ================= out proj with fused gate-combine A (bf16 W) ===================
__global__ __launch_bounds__(256) void gemm_out(
    const bf16* __restrict__ attn, const bf16* __restrict__ omb,
    const float* __restrict__ gate, const bf16* __restrict__ opwb,
    const float* __restrict__ opb, float* __restrict__ out)
{
  __shared__ __align__(16) __bf16 As[64][40];
  __shared__ __align__(16) __bf16 Bs[64][40];
  __shared__ float sg[NH];
  const int tm0 = blockIdx.y << 6, tn0 = blockIdx.x << 6;
  const int t = threadIdx.x;
  const int lrow = t >> 2, lk = (t & 3) << 3;
  const int wave = t >> 6, lane = t & 63;
  const int wm = (wave & 1) << 5, wn = (wave >> 1) << 5;
  const int m16 = lane & 15, quad = lane >> 4;

  if (t < NH) sg[t] = 1.f / (1.f + __expf(-gate[t]));
  __syncthreads();

  const f32x4 zero = {0.f, 0.f, 0.f, 0.f};
  f32x4 acc00 = zero, acc01 = zero, acc10 = zero, acc11 = zero;

  const int row = tm0 + lrow;
  const int l = row >> 3, n = row & 7;
  const bf16* bg = opwb + (long long)(tn0 + lrow) * EE + lk;
  for (int k0 = 0; k0 < EE; k0 += 32) {
    int e = k0 + lk;
    int h = e >> 6, d = e & 63;
    float g = sg[h];
    long long src = (((long long)(n * NH + h) * LQ) + l) * HD + d;
    bf16x8 a8 = *(const bf16x8*)(attn + src);
    bf16x8 o8 = *(const bf16x8*)(omb + src);
    bf16x8 ap;
#pragma unroll
    for (int j = 0; j < 8; ++j)
      ap[j] = tobf(g * bf2f(o8[j]) + (1.f - g) * bf2f(a8[j]));
    *(bf16x8*)&As[lrow][lk] = ap;
    *(bf16x8*)&Bs[lrow][lk] = *(const bf16x8*)(bg + k0);
    __syncthreads();
    bf16x8 a0 = *(bf16x8*)&As[wm + m16][quad << 3];
    bf16x8 a1 = *(bf16x8*)&As[wm + 16 + m16][quad << 3];
    bf16x8 b0 = *(bf16x8*)&Bs[wn + m16][quad << 3];
    bf16x8 b1 = *(bf16x8*)&Bs[wn + 16 + m16][quad << 3];
    acc00 = MFMA(a0, b0, acc00);
    acc01 = MFMA(a0, b1, acc01);
    acc10 = MFMA(a1, b0, acc10);
    acc11 = MFMA(a1, b1, acc11);
    __syncthreads();
  }
  f32x4 accs[2][2] = {{acc00, acc01}, {acc10, acc11}};
  for (int mi = 0; mi < 2; ++mi)
    for (int ni = 0; ni < 2; ++ni) {
      int col = tn0 + wn + (ni << 4) + m16;
      float bv = opb[col];
      long long base = (long long)(tm0 + wm + (mi << 4) + (quad << 2)) * EE + col;
      for (int r = 0; r < 4; ++r)
        out[base + (long long)r * EE] = accs[mi][ni][r] + bv;
    }
}

// ================= LDS-tiled transposes (no 2B-granular scatter) =================
// v_raw[(s*NB+n)][h*64+d] -> Vt[(n*NH+h)*HD+d][s], 64x64 tiles through LDS.
__global__ __launch_bounds__(256) void v_transpose(
    const bf16* __restrict__ raw, bf16* __restrict__ Vt)
{
  __shared__ __align__(16) __bf16 Ts[64][72];
  const int bh = blockIdx.y;             // n*NH + h
  const int n = bh >> 3, h = bh & 7;
  const int s0 = blockIdx.x << 6;
  const int t = threadIdx.x;
  const int i = t >> 2, c0 = (t & 3) << 4;
  const bf16* rp = raw + ((long long)(s0 + i) * NB + n) * EE + h * HD + c0;
  *(bf16x8*)&Ts[i][c0] = *(const bf16x8*)rp;
  *(bf16x8*)&Ts[i][c0 + 8] = *(const bf16x8*)(rp + 8);
  __syncthreads();
  const int d = t >> 2, j0 = (t & 3) << 4;
  __bf16 vals[16];
#pragma unroll
  for (int j = 0; j < 16; ++j) vals[j] = Ts[j0 + j][d];
  bf16* wp = Vt + ((long long)bh * HD + d) * SK + s0 + j0;
  *(uint4*)wp = *(uint4*)&vals[0];
  *(uint4*)(wp + 8) = *(uint4*)&vals[8];
}

// k_mem/v_mem f32 -> km (coalesced) + vmt (tiled transpose), per (bh, m-tile).
__global__ __launch_bounds__(256) void mem_prep(
    const float* __restrict__ k_mem, const float* __restrict__ v_mem,
    bf16* __restrict__ km, bf16* __restrict__ vmt)
{
  __shared__ __align__(16) __bf16 Ts[64][72];
  const int bh = blockIdx.y;             // n*NH + h
  const int n = bh >> 3, h = bh & 7;
  const int m0 = blockIdx.x << 6;
  const int t = threadIdx.x;
  const int i = t >> 2, c0 = (t & 3) << 4;
  const float* kp = k_mem + ((long long)(m0 + i) * NB + n) * EE + h * HD + c0;
  const float* vp = v_mem + ((long long)(m0 + i) * NB + n) * EE + h * HD + c0;
  bf16x8 kv0 = load8(kp), kv1 = load8(kp + 8);
  bf16x8 vv0 = load8(vp), vv1 = load8(vp + 8);
  bf16* kw = km + ((long long)bh * MMEM + m0 + i) * HD + c0;
  *(bf16x8*)kw = kv0;
  *(bf16x8*)(kw + 8) = kv1;
  *(bf16x8*)&Ts[i][c0] = vv0;
  *(bf16x8*)&Ts[i][c0 + 8] = vv1;
  __syncthreads();
  const int d = t >> 2, j0 = (t & 3) << 4;
  __bf16 vals[16];
#pragma unroll
  for (int j = 0; j < 16; ++j) vals[j] = Ts[j0 + j][d];
  bf16* wp = vmt + ((long long)bh * HD + d) * MMEM + m0 + j0;
  *(uint4*)wp = *(uint4*)&vals[0];
  *(uint4*)(wp + 8) = *(uint4*)&vals[8];
}

extern "C" void kernel_launch(void* const* d_in, const int* in_sizes, int n_in,
                              void* d_out, int out_size, void* d_ws, size_t ws_size,
                              hipStream_t stream) {
  const float* query = (const float*)d_in[0];
  const float* key   = (const float*)d_in[1];
  const float* value = (const float*)d_in[2];
  const float* ipw   = (const float*)d_in[3];
  const float* ipb   = (const float*)d_in[4];
  const float* opw   = (const float*)d_in[5];
  const float* opb   = (const float*)d_in[6];
  const float* rot_q = (const float*)d_in[7];
  const float* rot_k = (const float*)d_in[8];
  const float* k_mem = (const float*)d_in[9];
  const float* v_mem = (const float*)d_in[10];
  const float* gate  = (const float*)d_in[11];
  const int*  mask   = (const int*)d_in[12];
  float* out = (float*)d_out;

  char* w = (char*)d_ws;
  size_t off = 0;
  auto carve = [&](size_t bytes) -> char* {
    char* p = w + off;
    off += (bytes + 255) & ~(size_t)255;
    return p;
  };
  bf16* qc    = (bf16*)carve((size_t)LQ * NB * EE * 2);
  bf16* kc    = (bf16*)carve((size_t)SK * NB * EE * 2);
  bf16* vc    = (bf16*)carve((size_t)SK * NB * EE * 2);
  bf16* ipwb  = (bf16*)carve((size_t)3 * EE * EE * 2);
  bf16* opwb  = (bf16*)carve((size_t)EE * EE * 2);
  bf16* v_raw = (bf16*)carve((size_t)SK * NB * EE * 2);
  bf16* Qh    = (bf16*)carve((size_t)NBH * LQ * HD * 2);
  bf16* Kh    = (bf16*)carve((size_t)NBH * SK * HD * 2);
  bf16* Vt    = (bf16*)carve((size_t)NBH * HD * SK * 2);
  bf16* km    = (bf16*)carve((size_t)NBH * MMEM * HD * 2);
  bf16* vmt   = (bf16*)carve((size_t)NBH * HD * MMEM * 2);
  float* csum = (float*)carve((size_t)NBH * SK * 4);
  float* Vsum = (float*)carve((size_t)NBH * HD * 4);
  bf16* attn  = (bf16*)carve((size_t)NBH * LQ * HD * 2);
  bf16* omb   = (bf16*)carve((size_t)NBH * LQ * HD * 2);
  if (off > ws_size) {
    hipMemsetAsync(d_out, 0, (size_t)out_size * 4, stream);
    return;
  }
  // pq/pk alias attn/omb: those buffers are only written later (attn_flash /
  // mem_flash), well after rotary_kernel has consumed pq/pk.
  bf16* pq = attn;
  bf16* pk = omb;

  // 0) pre-convert GEMM inputs to bf16 (identical rounding point as before)
  convert5<<<(3 * CVT_T0 + CVT_T3 + CVT_T4) / 256, 256, 0, stream>>>(
      query, key, value, ipw, opw, qc, kc, vc, ipwb, opwb);

  // 1) q/k/v projections, pure GEMM (128x128 m97 structure)
  gemm_proj3<<<dim3(EE / 128, (LQ * NB) / 128, 3), 256, 0, stream>>>(
      qc, kc, vc, ipwb, ipb, pq, pk, v_raw);

  // 1b) rotary + head reshape as a pure streaming kernel
  rotary_kernel<<<dim3((LQ * NB) / 4, 2), 256, 0, stream>>>(
      pq, pk, rot_q, rot_k, Qh, Kh);

  // 2) v transpose (LDS-tiled) + Vsum; mem k/v repack (LDS-tiled)
  v_transpose<<<dim3(SK / 64, NBH), 256, 0, stream>>>(v_raw, Vt);
  vsum_kernel<<<(NBH * HD) / 4, 256, 0, stream>>>(Vt, Vsum);
  mem_prep<<<dim3(MMEM / 64, NBH), 256, 0, stream>>>(k_mem, v_mem, km, vmt);

  // 3) column sums of exp(scores) -- no P materialization
  colsum_kernel<<<dim3(SK / 64, NBH), 256, 0, stream>>>(Qh, Kh, csum);

  // 4) flash-style slot attn (recompute scores) + mem branch
  attn_flash<<<dim3(LQ / 64, NBH), 256, 0, stream>>>(Qh, Kh, Vt, csum, Vsum, attn);
  mem_flash<<<dim3(LQ / 64, NBH), 256, 0, stream>>>(Qh, km, vmt, mask, omb);

  // 5) out-proj with fused sigmoid-gate combine (f32 out direct)
  gemm_out<<<dim3(EE / 64, (LQ * NB) / 64, 1), 256, 0, stream>>>(attn, omb, gate, opwb, opb, out);
}

// Round 3
// 309.856 us; speedup vs baseline: 1.1449x; 1.0664x over previous
//
#include <hip/hip_runtime.h>
#include <hip/hip_bf16.h>

typedef __hip_bfloat16 bf16;
typedef __bf16 bf16x8 __attribute__((ext_vector_type(8)));
typedef float f32x4 __attribute__((ext_vector_type(4)));

#define LQ 1024
#define SK 1024
#define MMEM 256
#define NB 8
#define EE 512
#define NH 8
#define HD 64
#define NBH 64  // NB*NH batched (n,h) pairs

__device__ inline __bf16 tobf(float f) {
  __hip_bfloat16 h = __float2bfloat16(f);
  return *reinterpret_cast<__bf16*>(&h);
}
__device__ inline float bf2f(__bf16 x) {
  unsigned short u; __builtin_memcpy(&u, &x, 2);
  unsigned int v = (unsigned int)u << 16;
  float f; __builtin_memcpy(&f, &v, 4);
  return f;
}
__device__ inline f32x4 MFMA(bf16x8 a, bf16x8 b, f32x4 c) {
  return __builtin_amdgcn_mfma_f32_16x16x32_bf16(a, b, c, 0, 0, 0);
}

// async global->LDS, 16B per lane. LDS dest is wave-uniform base + lane*16.
__device__ inline void gload_lds16(const bf16* g, void* l) {
  __builtin_amdgcn_global_load_lds(
      (const __attribute__((address_space(1))) void*)g,
      (__attribute__((address_space(3))) void*)l, 16, 0, 0);
}

__device__ inline bf16x8 load8(const float* p) {
  float4 a = *(const float4*)p;
  float4 b = *(const float4*)(p + 4);
  bf16x8 r;
  r[0] = tobf(a.x); r[1] = tobf(a.y); r[2] = tobf(a.z); r[3] = tobf(a.w);
  r[4] = tobf(b.x); r[5] = tobf(b.y); r[6] = tobf(b.z); r[7] = tobf(b.w);
  return r;
}

// ================= bf16 pre-conversion of GEMM inputs ============================
#define CVT_T0 524288   // threads per q/k/v region (8 elems each)
#define CVT_T3 98304    // ipw
#define CVT_T4 32768    // opw
__global__ __launch_bounds__(256) void convert5(
    const float* __restrict__ q, const float* __restrict__ k,
    const float* __restrict__ v, const float* __restrict__ w,
    const float* __restrict__ o, bf16* __restrict__ qc, bf16* __restrict__ kc,
    bf16* __restrict__ vc, bf16* __restrict__ wc, bf16* __restrict__ oc)
{
  long long t = (long long)blockIdx.x * 256 + threadIdx.x;
  const float* src; bf16* dst; long long idx;
  if (t < CVT_T0)               { src = q; dst = qc; idx = t; }
  else if (t < 2 * CVT_T0)      { src = k; dst = kc; idx = t - CVT_T0; }
  else if (t < 3 * CVT_T0)      { src = v; dst = vc; idx = t - 2 * CVT_T0; }
  else if (t < 3 * CVT_T0 + CVT_T3) { src = w; dst = wc; idx = t - 3 * CVT_T0; }
  else                          { src = o; dst = oc; idx = t - 3 * CVT_T0 - CVT_T3; }
  *(bf16x8*)(dst + idx * 8) = load8(src + idx * 8);
}

// ================= 3-in-1 projection GEMM, m97-structure, PURE GEMM ==============
// 128x128 tile, BK=64, 4 waves (2x2), each wave owns 64x64 output (4x4 frags).
// XCD swizzle: each XCD gets 8 consecutive m-panels x all 4 n-panels.
__global__ __launch_bounds__(256) void gemm_proj3(
    const bf16* __restrict__ qc, const bf16* __restrict__ kc,
    const bf16* __restrict__ vc, const bf16* __restrict__ ipwb,
    const float* __restrict__ ipb, bf16* __restrict__ pq,
    bf16* __restrict__ pk, bf16* __restrict__ v_raw)
{
  __shared__ __align__(16) char smem[33792];
  __bf16* As = (__bf16*)smem;             // [128][64] linear, 16384 B
  __bf16* Bs = (__bf16*)(smem + 16384);   // [128][64] linear, 16384 B
  const int z = blockIdx.z;
  const bf16* A = (z == 0) ? qc : (z == 1) ? kc : vc;
  const bf16* W = ipwb + (long long)z * EE * EE;
  const float* bias = ipb + z * EE;
  const float alpha = (z == 0) ? 0.125f : 1.f;
  // XCD-aware remap (bijective): bid2 in [0,256) per z
  const int bid2 = blockIdx.y * gridDim.x + blockIdx.x;
  const int xcd = bid2 & 7, sub = bid2 >> 3;       // sub in [0,32)
  const int by = (xcd << 3) + (sub >> 2);          // 0..63
  const int bx = sub & 3;                          // 0..3
  const int tm0 = by << 7, tn0 = bx << 7;          // 128 x 128
  const int t = threadIdx.x;
  const int wave = t >> 6, lane = t & 63;
  const int wrow0 = (wave & 1) << 6, wcol0 = (wave >> 1) << 6;
  const int m16 = lane & 15, quad = lane >> 4;

  const f32x4 zero = {0.f, 0.f, 0.f, 0.f};
  f32x4 acc[4][4];
#pragma unroll
  for (int mi = 0; mi < 4; ++mi)
#pragma unroll
    for (int ni = 0; ni < 4; ++ni) acc[mi][ni] = zero;

  const bf16* Ab = A + (long long)tm0 * EE;
  const bf16* Bb = W + (long long)tn0 * EE;
  const int ob_u = wave << 10;  // wave-uniform byte base within 4KB chunk

  for (int k0 = 0; k0 < EE; k0 += 64) {
#pragma unroll
    for (int c = 0; c < 4; ++c) {
      int ob = (c << 12) + ob_u;          // uniform LDS byte base
      int obl = ob + (lane << 4);         // this lane's slot
      int row = obl >> 7;                 // tile row (stride 128 B)
      int ce = (obl & 127) >> 1;          // element within row
      gload_lds16(Ab + (long long)row * EE + k0 + ce, smem + ob);
      gload_lds16(Bb + (long long)row * EE + k0 + ce, smem + 16384 + ob);
    }
    __syncthreads();
#pragma unroll
    for (int kh = 0; kh < 2; ++kh) {
      bf16x8 av[4], bv[4];
#pragma unroll
      for (int i = 0; i < 4; ++i) {
        av[i] = *(bf16x8*)(As + ((wrow0 + (i << 4) + m16) << 6) + (kh << 5) + (quad << 3));
        bv[i] = *(bf16x8*)(Bs + ((wcol0 + (i << 4) + m16) << 6) + (kh << 5) + (quad << 3));
      }
#pragma unroll
      for (int mi = 0; mi < 4; ++mi)
#pragma unroll
        for (int ni = 0; ni < 4; ++ni)
          acc[mi][ni] = MFMA(av[mi], bv[ni], acc[mi][ni]);
    }
    __syncthreads();
  }

  // ---- epilogue: stage C in LDS (bias+scale), then 128B-contiguous stores ----
  __bf16 (*Cs)[132] = (__bf16(*)[132])smem;
#pragma unroll
  for (int mi = 0; mi < 4; ++mi)
#pragma unroll
    for (int ni = 0; ni < 4; ++ni) {
      int col = wcol0 + (ni << 4) + m16;
      float bv = bias[tn0 + col];
#pragma unroll
      for (int r = 0; r < 4; ++r)
        Cs[wrow0 + (mi << 4) + (quad << 2) + r][col] =
            tobf((acc[mi][ni][r] + bv) * alpha);
    }
  __syncthreads();
  bf16* O = (z == 0) ? pq : (z == 1) ? pk : v_raw;
  const int crow = t >> 1, ch0 = (t & 1) << 6;   // 2 threads/row, 64 cols each
  long long gb = (long long)(tm0 + crow) * EE + tn0 + ch0;
#pragma unroll
  for (int j = 0; j < 64; j += 8)
    *(uint4*)(O + gb + j) = *(uint4*)&Cs[crow][ch0 + j];
}

// ================= rotary + head-reshape, pure streaming =========================
__global__ __launch_bounds__(256) void rotary_kernel(
    const bf16* __restrict__ pq, const bf16* __restrict__ pk,
    const float* __restrict__ rot_q, const float* __restrict__ rot_k,
    bf16* __restrict__ Qh, bf16* __restrict__ Kh)
{
  const bf16* src = blockIdx.y ? pk : pq;
  const float* rot = blockIdx.y ? rot_k : rot_q;
  bf16* dst = blockIdx.y ? Kh : Qh;
  const int t = threadIdx.x;
  const int row = (blockIdx.x << 2) + (t >> 6);   // l*NB + n
  const int e0 = (t & 63) << 3;                   // 8 elems per lane
  const int l = row >> 3, n = row & 7;
  bf16x8 x = *(const bf16x8*)(src + (long long)row * EE + e0);
  const float* rp = rot + ((((long long)n * LQ + l) * EE + e0) << 1);
  __bf16 vals[8];
#pragma unroll
  for (int j = 0; j < 8; j += 2) {
    float4 cs4 = *(const float4*)(rp + (j << 1));  // c0,s0,c1,s1
    float x0 = bf2f(x[j]);
    float x1 = bf2f(x[j + 1]);
    vals[j]     = tobf(x0 * cs4.x - x1 * cs4.y);
    vals[j + 1] = tobf(x1 * cs4.z + x0 * cs4.w);
  }
  const int h = e0 >> 6, d0 = e0 & 63;
  *(uint4*)(dst + (((long long)(n * NH + h) * LQ + l) * HD + d0)) = *(uint4*)vals;
}

// ================= colsum: csum[b][s] = sum_l exp(Q[l]·K[s]) (no P write) ========
// XCD swizzle: all 16 st-tiles of one b on the same XCD (share its 128KB Q).
// T14: next Q tile prefetched to regs under the MFMA/exp body.
__global__ __launch_bounds__(256) void colsum_kernel(
    const bf16* __restrict__ Qh, const bf16* __restrict__ Kh,
    float* __restrict__ csum)
{
  __shared__ __align__(16) __bf16 Ks[64][72];
  __shared__ __align__(16) __bf16 Qs[64][72];
  __shared__ float cpart[64][2];
  const int bid = blockIdx.y * gridDim.x + blockIdx.x;   // 0..1023
  const int xcd = bid & 7, sub = bid >> 3;               // sub in [0,128)
  const int b = (xcd << 3) + (sub >> 4);                 // 0..63
  const int st0 = (sub & 15) << 6;
  const int t = threadIdx.x;
  const int lrow = t >> 2, lcol = (t & 3) << 4;
  const int wave = t >> 6, lane = t & 63;
  const int wm = (wave & 1) << 5, wn = (wave >> 1) << 5;
  const int m16 = lane & 15, quad = lane >> 4;

  {
    const bf16* kp = Kh + ((long long)b * SK + st0 + lrow) * HD + lcol;
    *(bf16x8*)&Ks[lrow][lcol] = *(const bf16x8*)kp;
    *(bf16x8*)&Ks[lrow][lcol + 8] = *(const bf16x8*)(kp + 8);
  }
  __syncthreads();
  bf16x8 bk[2][2];   // [ni][kh]
#pragma unroll
  for (int ni = 0; ni < 2; ++ni)
#pragma unroll
    for (int kh = 0; kh < 2; ++kh)
      bk[ni][kh] = *(bf16x8*)&Ks[wn + (ni << 4) + m16][(kh << 5) + (quad << 3)];
  __syncthreads();

  const f32x4 zero = {0.f, 0.f, 0.f, 0.f};
  float colp[2] = {0.f, 0.f};
  const bf16* qbase = Qh + ((long long)b * LQ + lrow) * HD + lcol;
  bf16x8 qr0 = *(const bf16x8*)qbase;
  bf16x8 qr1 = *(const bf16x8*)(qbase + 8);
  for (int lt = 0; lt < 16; ++lt) {
    *(bf16x8*)&Qs[lrow][lcol] = qr0;
    *(bf16x8*)&Qs[lrow][lcol + 8] = qr1;
    __syncthreads();
    if (lt < 15) {            // prefetch next Q tile under compute
      const bf16* qp = qbase + (long long)((lt + 1) << 6) * HD;
      qr0 = *(const bf16x8*)qp;
      qr1 = *(const bf16x8*)(qp + 8);
    }
    f32x4 s00 = zero, s01 = zero, s10 = zero, s11 = zero;
#pragma unroll
    for (int kh = 0; kh < 2; ++kh) {
      bf16x8 a0 = *(bf16x8*)&Qs[wm + m16][(kh << 5) + (quad << 3)];
      bf16x8 a1 = *(bf16x8*)&Qs[wm + 16 + m16][(kh << 5) + (quad << 3)];
      s00 = MFMA(a0, bk[0][kh], s00);
      s01 = MFMA(a0, bk[1][kh], s01);
      s10 = MFMA(a1, bk[0][kh], s10);
      s11 = MFMA(a1, bk[1][kh], s11);
    }
    f32x4 sacc[2][2] = {{s00, s01}, {s10, s11}};
#pragma unroll
    for (int mi = 0; mi < 2; ++mi)
#pragma unroll
      for (int ni = 0; ni < 2; ++ni)
#pragma unroll
        for (int r = 0; r < 4; ++r)
          colp[ni] += __expf(sacc[mi][ni][r]);
    __syncthreads();
  }
  for (int ni = 0; ni < 2; ++ni) {
    float v = colp[ni];
    v += __shfl_down(v, 32, 64);
    v += __shfl_down(v, 16, 64);
    if (quad == 0) cpart[wn + (ni << 4) + m16][wm >> 5] = v;
  }
  __syncthreads();
  if (t < 64) csum[b * SK + st0 + t] = cpart[t][0] + cpart[t][1];
}

// ================= Vsum[b][d] = sum_s Vt[b][d][s] ================================
__global__ __launch_bounds__(256) void vsum_kernel(
    const bf16* __restrict__ Vt, float* __restrict__ Vsum)
{
  int wid = blockIdx.x * 4 + (threadIdx.x >> 6);
  int lane = threadIdx.x & 63;
  const bf16* p = Vt + (long long)wid * SK + lane * 16;
  float s = 0.f;
  bf16x8 v0 = *(const bf16x8*)p;
  bf16x8 v1 = *(const bf16x8*)(p + 8);
#pragma unroll
  for (int j = 0; j < 8; ++j) s += bf2f(v0[j]) + bf2f(v1[j]);
  for (int off = 32; off; off >>= 1) s += __shfl_down(s, off, 64);
  if (lane == 0) Vsum[wid] = s;
}

// ================= flash slot-attn: recompute scores, normalize, @V ==============
// XCD swizzle: all 16 l-tiles of one b on the same XCD (share its 256KB K/V).
// T14: next K/V tiles prefetched to regs under the QK/softmax/PV body.
__global__ __launch_bounds__(256) void attn_flash(
    const bf16* __restrict__ Qh, const bf16* __restrict__ Kh,
    const bf16* __restrict__ Vt, const float* __restrict__ csum,
    const float* __restrict__ Vsum, bf16* __restrict__ attn)
{
  __shared__ __align__(16) __bf16 Ks[64][72];
  __shared__ __align__(16) __bf16 Vs[64][72];
  __shared__ __align__(16) __bf16 Ps[64][72];
  __shared__ float rcs[SK];
  __shared__ float rpart[64][2];
  const int bid = blockIdx.y * gridDim.x + blockIdx.x;   // 0..1023
  const int xcd = bid & 7, sub = bid >> 3;               // sub in [0,128)
  const int b = (xcd << 3) + (sub >> 4);                 // 0..63
  const int tm0 = (sub & 15) << 6;
  const int t = threadIdx.x;
  const int lrow = t >> 2, lcol = (t & 3) << 4;
  const int wave = t >> 6, lane = t & 63;
  const int wm = (wave & 1) << 5, wn = (wave >> 1) << 5;
  const int m16 = lane & 15, quad = lane >> 4;

#pragma unroll
  for (int i = 0; i < 4; ++i)
    rcs[t + i * 256] = 1.f / csum[b * SK + t + i * 256];
  {
    const bf16* qp = Qh + ((long long)b * LQ + tm0 + lrow) * HD + lcol;
    *(bf16x8*)&Ks[lrow][lcol] = *(const bf16x8*)qp;
    *(bf16x8*)&Ks[lrow][lcol + 8] = *(const bf16x8*)(qp + 8);
  }
  __syncthreads();
  bf16x8 aq[2][2];
#pragma unroll
  for (int mi = 0; mi < 2; ++mi)
#pragma unroll
    for (int kh = 0; kh < 2; ++kh)
      aq[mi][kh] = *(bf16x8*)&Ks[wm + (mi << 4) + m16][(kh << 5) + (quad << 3)];
  __syncthreads();

  const f32x4 zero = {0.f, 0.f, 0.f, 0.f};
  f32x4 o00 = zero, o01 = zero, o10 = zero, o11 = zero;
  float rsumr[2][4] = {{0.f, 0.f, 0.f, 0.f}, {0.f, 0.f, 0.f, 0.f}};

  const bf16* kbase = Kh + ((long long)b * SK + lrow) * HD + lcol;
  const bf16* vbase = Vt + ((long long)b * HD + lrow) * SK + lcol;
  bf16x8 kr0 = *(const bf16x8*)kbase;
  bf16x8 kr1 = *(const bf16x8*)(kbase + 8);
  bf16x8 vr0 = *(const bf16x8*)vbase;
  bf16x8 vr1 = *(const bf16x8*)(vbase + 8);

  for (int st = 0; st < 16; ++st) {
    *(bf16x8*)&Ks[lrow][lcol] = kr0;
    *(bf16x8*)&Ks[lrow][lcol + 8] = kr1;
    *(bf16x8*)&Vs[lrow][lcol] = vr0;
    *(bf16x8*)&Vs[lrow][lcol + 8] = vr1;
    __syncthreads();
    if (st < 15) {            // prefetch next K/V tiles under compute
      const bf16* kp = kbase + (long long)((st + 1) << 6) * HD;
      const bf16* vp = vbase + ((st + 1) << 6);
      kr0 = *(const bf16x8*)kp;
      kr1 = *(const bf16x8*)(kp + 8);
      vr0 = *(const bf16x8*)vp;
      vr1 = *(const bf16x8*)(vp + 8);
    }
    f32x4 s00 = zero, s01 = zero, s10 = zero, s11 = zero;
#pragma unroll
    for (int kh = 0; kh < 2; ++kh) {
      bf16x8 b0 = *(bf16x8*)&Ks[wn + m16][(kh << 5) + (quad << 3)];
      bf16x8 b1 = *(bf16x8*)&Ks[wn + 16 + m16][(kh << 5) + (quad << 3)];
      s00 = MFMA(aq[0][kh], b0, s00);
      s01 = MFMA(aq[0][kh], b1, s01);
      s10 = MFMA(aq[1][kh], b0, s10);
      s11 = MFMA(aq[1][kh], b1, s11);
    }
    f32x4 sacc[2][2] = {{s00, s01}, {s10, s11}};
#pragma unroll
    for (int mi = 0; mi < 2; ++mi)
#pragma unroll
      for (int ni = 0; ni < 2; ++ni) {
        int col = wn + (ni << 4) + m16;
        float rc = rcs[(st << 6) + col];
#pragma unroll
        for (int r = 0; r < 4; ++r) {
          float p = __expf(sacc[mi][ni][r]) * rc;
          rsumr[mi][r] += p;
          Ps[wm + (mi << 4) + (quad << 2) + r][col] = tobf(p);
        }
      }
    __syncthreads();
#pragma unroll
    for (int kh = 0; kh < 2; ++kh) {
      bf16x8 ap0 = *(bf16x8*)&Ps[wm + m16][(kh << 5) + (quad << 3)];
      bf16x8 ap1 = *(bf16x8*)&Ps[wm + 16 + m16][(kh << 5) + (quad << 3)];
      bf16x8 bv0 = *(bf16x8*)&Vs[wn + m16][(kh << 5) + (quad << 3)];
      bf16x8 bv1 = *(bf16x8*)&Vs[wn + 16 + m16][(kh << 5) + (quad << 3)];
      o00 = MFMA(ap0, bv0, o00);
      o01 = MFMA(ap0, bv1, o01);
      o10 = MFMA(ap1, bv0, o10);
      o11 = MFMA(ap1, bv1, o11);
    }
    __syncthreads();
  }
#pragma unroll
  for (int mi = 0; mi < 2; ++mi)
#pragma unroll
    for (int r = 0; r < 4; ++r) {
      float v = rsumr[mi][r];
      v += __shfl_xor(v, 1, 64);
      v += __shfl_xor(v, 2, 64);
      v += __shfl_xor(v, 4, 64);
      v += __shfl_xor(v, 8, 64);
      if (m16 == 0) rpart[wm + (mi << 4) + (quad << 2) + r][wn >> 5] = v;
    }
  __syncthreads();
  const float* vs = Vsum + b * HD;
  f32x4 oacc[2][2] = {{o00, o01}, {o10, o11}};
  for (int mi = 0; mi < 2; ++mi)
    for (int ni = 0; ni < 2; ++ni) {
      int col = wn + (ni << 4) + m16;
      float vsc = 1e-8f * vs[col];
      for (int r = 0; r < 4; ++r) {
        int row = wm + (mi << 4) + (quad << 2) + r;
        float rs = rpart[row][0] + rpart[row][1];
        Ps[row][col] = tobf((oacc[mi][ni][r] + vsc) / (rs + (float)SK * 1e-8f));
      }
    }
  __syncthreads();
  uint4 u0 = *(uint4*)&Ps[lrow][lcol];
  uint4 u1 = *(uint4*)&Ps[lrow][lcol + 8];
  long long gb = ((long long)b * LQ + tm0 + lrow) * HD + lcol;
  *(uint4*)(attn + gb) = u0;
  *(uint4*)(attn + gb + 8) = u1;
}

// ================= fully-fused mem branch (flash-style) ==========================
__global__ __launch_bounds__(256) void mem_flash(
    const bf16* __restrict__ Qh, const bf16* __restrict__ km,
    const bf16* __restrict__ vmt, const int* __restrict__ mask,
    bf16* __restrict__ omb)
{
  __shared__ __align__(16) __bf16 Ks[64][72];
  __shared__ __align__(16) __bf16 Vs[64][72];
  __shared__ __align__(16) __bf16 Ps[64][72];
  __shared__ float mskf[MMEM];
  __shared__ float rpart[64][2];
  const int bid = blockIdx.y * gridDim.x + blockIdx.x;   // 0..1023
  const int xcd = bid & 7, sub = bid >> 3;               // sub in [0,128)
  const int b = (xcd << 3) + (sub >> 4);                 // 0..63
  const int tm0 = (sub & 15) << 6;
  const int n = b >> 3;
  const int t = threadIdx.x;
  const int wave = t >> 6, lane = t & 63;
  const int wm = (wave & 1) << 5, wn = (wave >> 1) << 5;
  const int m16 = lane & 15, quad = lane >> 4;
  const int lrow = t >> 2, lcol = (t & 3) << 4;

  mskf[t] = mask[n * MMEM + t] ? 0.f : 1.f;
  {
    const bf16* qp = Qh + ((long long)b * LQ + tm0 + lrow) * HD + lcol;
    *(bf16x8*)&Ks[lrow][lcol] = *(const bf16x8*)qp;
    *(bf16x8*)&Ks[lrow][lcol + 8] = *(const bf16x8*)(qp + 8);
  }
  __syncthreads();
  bf16x8 aq[2][2];
#pragma unroll
  for (int mi = 0; mi < 2; ++mi)
#pragma unroll
    for (int kh = 0; kh < 2; ++kh)
      aq[mi][kh] = *(bf16x8*)&Ks[wm + (mi << 4) + m16][(kh << 5) + (quad << 3)];
  __syncthreads();

  const f32x4 zero = {0.f, 0.f, 0.f, 0.f};
  f32x4 o00 = zero, o01 = zero, o10 = zero, o11 = zero;
  float rsumr[2][4] = {{0.f, 0.f, 0.f, 0.f}, {0.f, 0.f, 0.f, 0.f}};

  const bf16* kbase = km + ((long long)b * MMEM + lrow) * HD + lcol;
  const bf16* vbase = vmt + ((long long)b * HD + lrow) * MMEM + lcol;
  bf16x8 kr0 = *(const bf16x8*)kbase;
  bf16x8 kr1 = *(const bf16x8*)(kbase + 8);
  bf16x8 vr0 = *(const bf16x8*)vbase;
  bf16x8 vr1 = *(const bf16x8*)(vbase + 8);

  for (int mt = 0; mt < 4; ++mt) {
    *(bf16x8*)&Ks[lrow][lcol] = kr0;
    *(bf16x8*)&Ks[lrow][lcol + 8] = kr1;
    *(bf16x8*)&Vs[lrow][lcol] = vr0;
    *(bf16x8*)&Vs[lrow][lcol + 8] = vr1;
    __syncthreads();
    if (mt < 3) {             // prefetch next K/V tiles under compute
      const bf16* kp = kbase + (long long)((mt + 1) << 6) * HD;
      const bf16* vp = vbase + ((mt + 1) << 6);
      kr0 = *(const bf16x8*)kp;
      kr1 = *(const bf16x8*)(kp + 8);
      vr0 = *(const bf16x8*)vp;
      vr1 = *(const bf16x8*)(vp + 8);
    }
    f32x4 s00 = zero, s01 = zero, s10 = zero, s11 = zero;
#pragma unroll
    for (int kh = 0; kh < 2; ++kh) {
      bf16x8 b0 = *(bf16x8*)&Ks[wn + m16][(kh << 5) + (quad << 3)];
      bf16x8 b1 = *(bf16x8*)&Ks[wn + 16 + m16][(kh << 5) + (quad << 3)];
      s00 = MFMA(aq[0][kh], b0, s00);
      s01 = MFMA(aq[0][kh], b1, s01);
      s10 = MFMA(aq[1][kh], b0, s10);
      s11 = MFMA(aq[1][kh], b1, s11);
    }
    f32x4 sacc[2][2] = {{s00, s01}, {s10, s11}};
#pragma unroll
    for (int mi = 0; mi < 2; ++mi)
#pragma unroll
      for (int ni = 0; ni < 2; ++ni) {
        int col = wn + (ni << 4) + m16;
        float mf = mskf[(mt << 6) + col];
#pragma unroll
        for (int r = 0; r < 4; ++r) {
          float p = __expf(sacc[mi][ni][r]) * mf;
          rsumr[mi][r] += p;
          Ps[wm + (mi << 4) + (quad << 2) + r][col] = tobf(p);
        }
      }
    __syncthreads();
#pragma unroll
    for (int kh = 0; kh < 2; ++kh) {
      bf16x8 ap0 = *(bf16x8*)&Ps[wm + m16][(kh << 5) + (quad << 3)];
      bf16x8 ap1 = *(bf16x8*)&Ps[wm + 16 + m16][(kh << 5) + (quad << 3)];
      bf16x8 bv0 = *(bf16x8*)&Vs[wn + m16][(kh << 5) + (quad << 3)];
      bf16x8 bv1 = *(bf16x8*)&Vs[wn + 16 + m16][(kh << 5) + (quad << 3)];
      o00 = MFMA(ap0, bv0, o00);
      o01 = MFMA(ap0, bv1, o01);
      o10 = MFMA(ap1, bv0, o10);
      o11 = MFMA(ap1, bv1, o11);
    }
    __syncthreads();
  }
#pragma unroll
  for (int mi = 0; mi < 2; ++mi)
#pragma unroll
    for (int r = 0; r < 4; ++r) {
      float v = rsumr[mi][r];
      v += __shfl_xor(v, 1, 64);
      v += __shfl_xor(v, 2, 64);
      v += __shfl_xor(v, 4, 64);
      v += __shfl_xor(v, 8, 64);
      if (m16 == 0) rpart[wm + (mi << 4) + (quad << 2) + r][wn >> 5] = v;
    }
  __syncthreads();
  f32x4 oacc[2][2] = {{o00, o01}, {o10, o11}};
  for (int mi = 0; mi < 2; ++mi)
    for (int ni = 0; ni < 2; ++ni) {
      int col = wn + (ni << 4) + m16;
      for (int r = 0; r < 4; ++r) {
        int row = wm + (mi << 4) + (quad << 2) + r;
        float rs = rpart[row][0] + rpart[row][1];
        Ps[row][col] = tobf(oacc[mi][ni][r] / rs);
      }
    }
  __syncthreads();
  uint4 u0 = *(uint4*)&Ps[lrow][lcol];
  uint4 u1 = *(uint4*)&Ps[lrow][lcol + 8];
  long long gb = ((long long)b * LQ + tm0 + lrow) * HD + lcol;
  *(uint4*)(omb + gb) = u0;
  *(uint4*)(omb + gb + 8) = u1;
}

// ================= out proj with fused gate-combine A (bf16 W) ===================
// XCD swizzle: each XCD gets 16 consecutive m-tiles x all 8 n-tiles, so the
// gate-combined A panels (attn/omb reads) are L2-resident across n-tiles.
__global__ __launch_bounds__(256) void gemm_out(
    const bf16* __restrict__ attn, const bf16* __restrict__ omb,
    const float* __restrict__ gate, const bf16* __restrict__ opwb,
    const float* __restrict__ opb, float* __restrict__ out)
{
  __shared__ __align__(16) __bf16 As[64][40];
  __shared__ __align__(16) __bf16 Bs[64][40];
  __shared__ float sg[NH];
  const int bid = blockIdx.y * gridDim.x + blockIdx.x;   // 0..1023
  const int xcd = bid & 7, sub = bid >> 3;               // sub in [0,128)
  const int by = (xcd << 4) + (sub >> 3);                // 0..127
  const int bx = sub & 7;                                // 0..7
  const int tm0 = by << 6, tn0 = bx << 6;
  const int t = threadIdx.x;
  const int lrow = t >> 2, lk = (t & 3) << 3;
  const int wave = t >> 6, lane = t & 63;
  const int wm = (wave & 1) << 5, wn = (wave >> 1) << 5;
  const int m16 = lane & 15, quad = lane >> 4;

  if (t < NH) sg[t] = 1.f / (1.f + __expf(-gate[t]));
  __syncthreads();

  const f32x4 zero = {0.f, 0.f, 0.f, 0.f};
  f32x4 acc00 = zero, acc01 = zero, acc10 = zero, acc11 = zero;

  const int row = tm0 + lrow;
  const int l = row >> 3, n = row & 7;
  const bf16* bg = opwb + (long long)(tn0 + lrow) * EE + lk;
  for (int k0 = 0; k0 < EE; k0 += 32) {
    int e = k0 + lk;
    int h = e >> 6, d = e & 63;
    float g = sg[h];
    long long src = (((long long)(n * NH + h) * LQ) + l) * HD + d;
    bf16x8 a8 = *(const bf16x8*)(attn + src);
    bf16x8 o8 = *(const bf16x8*)(omb + src);
    bf16x8 ap;
#pragma unroll
    for (int j = 0; j < 8; ++j)
      ap[j] = tobf(g * bf2f(o8[j]) + (1.f - g) * bf2f(a8[j]));
    *(bf16x8*)&As[lrow][lk] = ap;
    *(bf16x8*)&Bs[lrow][lk] = *(const bf16x8*)(bg + k0);
    __syncthreads();
    bf16x8 a0 = *(bf16x8*)&As[wm + m16][quad << 3];
    bf16x8 a1 = *(bf16x8*)&As[wm + 16 + m16][quad << 3];
    bf16x8 b0 = *(bf16x8*)&Bs[wn + m16][quad << 3];
    bf16x8 b1 = *(bf16x8*)&Bs[wn + 16 + m16][quad << 3];
    acc00 = MFMA(a0, b0, acc00);
    acc01 = MFMA(a0, b1, acc01);
    acc10 = MFMA(a1, b0, acc10);
    acc11 = MFMA(a1, b1, acc11);
    __syncthreads();
  }
  f32x4 accs[2][2] = {{acc00, acc01}, {acc10, acc11}};
  for (int mi = 0; mi < 2; ++mi)
    for (int ni = 0; ni < 2; ++ni) {
      int col = tn0 + wn + (ni << 4) + m16;
      float bv = opb[col];
      long long base = (long long)(tm0 + wm + (mi << 4) + (quad << 2)) * EE + col;
      for (int r = 0; r < 4; ++r)
        out[base + (long long)r * EE] = accs[mi][ni][r] + bv;
    }
}

// ================= LDS-tiled transposes (no 2B-granular scatter) =================
__global__ __launch_bounds__(256) void v_transpose(
    const bf16* __restrict__ raw, bf16* __restrict__ Vt)
{
  __shared__ __align__(16) __bf16 Ts[64][72];
  const int bh = blockIdx.y;             // n*NH + h
  const int n = bh >> 3, h = bh & 7;
  const int s0 = blockIdx.x << 6;
  const int t = threadIdx.x;
  const int i = t >> 2, c0 = (t & 3) << 4;
  const bf16* rp = raw + ((long long)(s0 + i) * NB + n) * EE + h * HD + c0;
  *(bf16x8*)&Ts[i][c0] = *(const bf16x8*)rp;
  *(bf16x8*)&Ts[i][c0 + 8] = *(const bf16x8*)(rp + 8);
  __syncthreads();
  const int d = t >> 2, j0 = (t & 3) << 4;
  __bf16 vals[16];
#pragma unroll
  for (int j = 0; j < 16; ++j) vals[j] = Ts[j0 + j][d];
  bf16* wp = Vt + ((long long)bh * HD + d) * SK + s0 + j0;
  *(uint4*)wp = *(uint4*)&vals[0];
  *(uint4*)(wp + 8) = *(uint4*)&vals[8];
}

__global__ __launch_bounds__(256) void mem_prep(
    const float* __restrict__ k_mem, const float* __restrict__ v_mem,
    bf16* __restrict__ km, bf16* __restrict__ vmt)
{
  __shared__ __align__(16) __bf16 Ts[64][72];
  const int bh = blockIdx.y;             // n*NH + h
  const int n = bh >> 3, h = bh & 7;
  const int m0 = blockIdx.x << 6;
  const int t = threadIdx.x;
  const int i = t >> 2, c0 = (t & 3) << 4;
  const float* kp = k_mem + ((long long)(m0 + i) * NB + n) * EE + h * HD + c0;
  const float* vp = v_mem + ((long long)(m0 + i) * NB + n) * EE + h * HD + c0;
  bf16x8 kv0 = load8(kp), kv1 = load8(kp + 8);
  bf16x8 vv0 = load8(vp), vv1 = load8(vp + 8);
  bf16* kw = km + ((long long)bh * MMEM + m0 + i) * HD + c0;
  *(bf16x8*)kw = kv0;
  *(bf16x8*)(kw + 8) = kv1;
  *(bf16x8*)&Ts[i][c0] = vv0;
  *(bf16x8*)&Ts[i][c0 + 8] = vv1;
  __syncthreads();
  const int d = t >> 2, j0 = (t & 3) << 4;
  __bf16 vals[16];
#pragma unroll
  for (int j = 0; j < 16; ++j) vals[j] = Ts[j0 + j][d];
  bf16* wp = vmt + ((long long)bh * HD + d) * MMEM + m0 + j0;
  *(uint4*)wp = *(uint4*)&vals[0];
  *(uint4*)(wp + 8) = *(uint4*)&vals[8];
}

extern "C" void kernel_launch(void* const* d_in, const int* in_sizes, int n_in,
                              void* d_out, int out_size, void* d_ws, size_t ws_size,
                              hipStream_t stream) {
  const float* query = (const float*)d_in[0];
  const float* key   = (const float*)d_in[1];
  const float* value = (const float*)d_in[2];
  const float* ipw   = (const float*)d_in[3];
  const float* ipb   = (const float*)d_in[4];
  const float* opw   = (const float*)d_in[5];
  const float* opb   = (const float*)d_in[6];
  const float* rot_q = (const float*)d_in[7];
  const float* rot_k = (const float*)d_in[8];
  const float* k_mem = (const float*)d_in[9];
  const float* v_mem = (const float*)d_in[10];
  const float* gate  = (const float*)d_in[11];
  const int*  mask   = (const int*)d_in[12];
  float* out = (float*)d_out;

  char* w = (char*)d_ws;
  size_t off = 0;
  auto carve = [&](size_t bytes) -> char* {
    char* p = w + off;
    off += (bytes + 255) & ~(size_t)255;
    return p;
  };
  bf16* qc    = (bf16*)carve((size_t)LQ * NB * EE * 2);
  bf16* kc    = (bf16*)carve((size_t)SK * NB * EE * 2);
  bf16* vc    = (bf16*)carve((size_t)SK * NB * EE * 2);
  bf16* ipwb  = (bf16*)carve((size_t)3 * EE * EE * 2);
  bf16* opwb  = (bf16*)carve((size_t)EE * EE * 2);
  bf16* v_raw = (bf16*)carve((size_t)SK * NB * EE * 2);
  bf16* Qh    = (bf16*)carve((size_t)NBH * LQ * HD * 2);
  bf16* Kh    = (bf16*)carve((size_t)NBH * SK * HD * 2);
  bf16* Vt    = (bf16*)carve((size_t)NBH * HD * SK * 2);
  bf16* km    = (bf16*)carve((size_t)NBH * MMEM * HD * 2);
  bf16* vmt   = (bf16*)carve((size_t)NBH * HD * MMEM * 2);
  float* csum = (float*)carve((size_t)NBH * SK * 4);
  float* Vsum = (float*)carve((size_t)NBH * HD * 4);
  bf16* attn  = (bf16*)carve((size_t)NBH * LQ * HD * 2);
  bf16* omb   = (bf16*)carve((size_t)NBH * LQ * HD * 2);
  if (off > ws_size) {
    hipMemsetAsync(d_out, 0, (size_t)out_size * 4, stream);
    return;
  }
  // pq/pk alias attn/omb: those buffers are only written later (attn_flash /
  // mem_flash), well after rotary_kernel has consumed pq/pk.
  bf16* pq = attn;
  bf16* pk = omb;

  // 0) pre-convert GEMM inputs to bf16 (identical rounding point as before)
  convert5<<<(3 * CVT_T0 + CVT_T3 + CVT_T4) / 256, 256, 0, stream>>>(
      query, key, value, ipw, opw, qc, kc, vc, ipwb, opwb);

  // 1) q/k/v projections, pure GEMM (128x128 m97 structure, XCD-swizzled)
  gemm_proj3<<<dim3(EE / 128, (LQ * NB) / 128, 3), 256, 0, stream>>>(
      qc, kc, vc, ipwb, ipb, pq, pk, v_raw);

  // 1b) rotary + head reshape as a pure streaming kernel
  rotary_kernel<<<dim3((LQ * NB) / 4, 2), 256, 0, stream>>>(
      pq, pk, rot_q, rot_k, Qh, Kh);

  // 2) v transpose (LDS-tiled) + Vsum; mem k/v repack (LDS-tiled)
  v_transpose<<<dim3(SK / 64, NBH), 256, 0, stream>>>(v_raw, Vt);
  vsum_kernel<<<(NBH * HD) / 4, 256, 0, stream>>>(Vt, Vsum);
  mem_prep<<<dim3(MMEM / 64, NBH), 256, 0, stream>>>(k_mem, v_mem, km, vmt);

  // 3) column sums of exp(scores) -- no P materialization (XCD-swizzled)
  colsum_kernel<<<dim3(SK / 64, NBH), 256, 0, stream>>>(Qh, Kh, csum);

  // 4) flash-style slot attn (recompute scores) + mem branch (XCD-swizzled)
  attn_flash<<<dim3(LQ / 64, NBH), 256, 0, stream>>>(Qh, Kh, Vt, csum, Vsum, attn);
  mem_flash<<<dim3(LQ / 64, NBH), 256, 0, stream>>>(Qh, km, vmt, mask, omb);

  // 5) out-proj with fused sigmoid-gate combine (XCD-swizzled)
  gemm_out<<<dim3(EE / 64, (LQ * NB) / 64, 1), 256, 0, stream>>>(attn, omb, gate, opwb, opb, out);
}

// Round 4
// 306.008 us; speedup vs baseline: 1.1593x; 1.0126x over previous
//
#include <hip/hip_runtime.h>
#include <hip/hip_bf16.h>

typedef __hip_bfloat16 bf16;
typedef __bf16 bf16x8 __attribute__((ext_vector_type(8)));
typedef float f32x4 __attribute__((ext_vector_type(4)));

#define LQ 1024
#define SK 1024
#define MMEM 256
#define NB 8
#define EE 512
#define NH 8
#define HD 64
#define NBH 64  // NB*NH batched (n,h) pairs

__device__ inline __bf16 tobf(float f) {
  __hip_bfloat16 h = __float2bfloat16(f);
  return *reinterpret_cast<__bf16*>(&h);
}
__device__ inline float bf2f(__bf16 x) {
  unsigned short u; __builtin_memcpy(&u, &x, 2);
  unsigned int v = (unsigned int)u << 16;
  float f; __builtin_memcpy(&f, &v, 4);
  return f;
}
__device__ inline f32x4 MFMA(bf16x8 a, bf16x8 b, f32x4 c) {
  return __builtin_amdgcn_mfma_f32_16x16x32_bf16(a, b, c, 0, 0, 0);
}

// async global->LDS, 16B per lane. LDS dest is wave-uniform base + lane*16.
__device__ inline void gload_lds16(const bf16* g, void* l) {
  __builtin_amdgcn_global_load_lds(
      (const __attribute__((address_space(1))) void*)g,
      (__attribute__((address_space(3))) void*)l, 16, 0, 0);
}

__device__ inline bf16x8 load8(const float* p) {
  float4 a = *(const float4*)p;
  float4 b = *(const float4*)(p + 4);
  bf16x8 r;
  r[0] = tobf(a.x); r[1] = tobf(a.y); r[2] = tobf(a.z); r[3] = tobf(a.w);
  r[4] = tobf(b.x); r[5] = tobf(b.y); r[6] = tobf(b.z); r[7] = tobf(b.w);
  return r;
}

// ================= bf16 pre-conversion of GEMM inputs ============================
#define CVT_T0 524288   // threads per q/k/v region (8 elems each)
#define CVT_T3 98304    // ipw
#define CVT_T4 32768    // opw
__global__ __launch_bounds__(256) void convert5(
    const float* __restrict__ q, const float* __restrict__ k,
    const float* __restrict__ v, const float* __restrict__ w,
    const float* __restrict__ o, bf16* __restrict__ qc, bf16* __restrict__ kc,
    bf16* __restrict__ vc, bf16* __restrict__ wc, bf16* __restrict__ oc)
{
  long long t = (long long)blockIdx.x * 256 + threadIdx.x;
  const float* src; bf16* dst; long long idx;
  if (t < CVT_T0)               { src = q; dst = qc; idx = t; }
  else if (t < 2 * CVT_T0)      { src = k; dst = kc; idx = t - CVT_T0; }
  else if (t < 3 * CVT_T0)      { src = v; dst = vc; idx = t - 2 * CVT_T0; }
  else if (t < 3 * CVT_T0 + CVT_T3) { src = w; dst = wc; idx = t - 3 * CVT_T0; }
  else                          { src = o; dst = oc; idx = t - 3 * CVT_T0 - CVT_T3; }
  *(bf16x8*)(dst + idx * 8) = load8(src + idx * 8);
}

// ================= 3-in-1 projection GEMM, m97-structure, PURE GEMM ==============
__global__ __launch_bounds__(256) void gemm_proj3(
    const bf16* __restrict__ qc, const bf16* __restrict__ kc,
    const bf16* __restrict__ vc, const bf16* __restrict__ ipwb,
    const float* __restrict__ ipb, bf16* __restrict__ pq,
    bf16* __restrict__ pk, bf16* __restrict__ v_raw)
{
  __shared__ __align__(16) char smem[33792];
  __bf16* As = (__bf16*)smem;             // [128][64] linear, 16384 B
  __bf16* Bs = (__bf16*)(smem + 16384);   // [128][64] linear, 16384 B
  const int z = blockIdx.z;
  const bf16* A = (z == 0) ? qc : (z == 1) ? kc : vc;
  const bf16* W = ipwb + (long long)z * EE * EE;
  const float* bias = ipb + z * EE;
  const float alpha = (z == 0) ? 0.125f : 1.f;
  // XCD-aware remap (bijective): bid2 in [0,256) per z
  const int bid2 = blockIdx.y * gridDim.x + blockIdx.x;
  const int xcd = bid2 & 7, sub = bid2 >> 3;       // sub in [0,32)
  const int by = (xcd << 3) + (sub >> 2);          // 0..63
  const int bx = sub & 3;                          // 0..3
  const int tm0 = by << 7, tn0 = bx << 7;          // 128 x 128
  const int t = threadIdx.x;
  const int wave = t >> 6, lane = t & 63;
  const int wrow0 = (wave & 1) << 6, wcol0 = (wave >> 1) << 6;
  const int m16 = lane & 15, quad = lane >> 4;

  const f32x4 zero = {0.f, 0.f, 0.f, 0.f};
  f32x4 acc[4][4];
#pragma unroll
  for (int mi = 0; mi < 4; ++mi)
#pragma unroll
    for (int ni = 0; ni < 4; ++ni) acc[mi][ni] = zero;

  const bf16* Ab = A + (long long)tm0 * EE;
  const bf16* Bb = W + (long long)tn0 * EE;
  const int ob_u = wave << 10;  // wave-uniform byte base within 4KB chunk

  for (int k0 = 0; k0 < EE; k0 += 64) {
#pragma unroll
    for (int c = 0; c < 4; ++c) {
      int ob = (c << 12) + ob_u;          // uniform LDS byte base
      int obl = ob + (lane << 4);         // this lane's slot
      int row = obl >> 7;                 // tile row (stride 128 B)
      int ce = (obl & 127) >> 1;          // element within row
      gload_lds16(Ab + (long long)row * EE + k0 + ce, smem + ob);
      gload_lds16(Bb + (long long)row * EE + k0 + ce, smem + 16384 + ob);
    }
    __syncthreads();
#pragma unroll
    for (int kh = 0; kh < 2; ++kh) {
      bf16x8 av[4], bv[4];
#pragma unroll
      for (int i = 0; i < 4; ++i) {
        av[i] = *(bf16x8*)(As + ((wrow0 + (i << 4) + m16) << 6) + (kh << 5) + (quad << 3));
        bv[i] = *(bf16x8*)(Bs + ((wcol0 + (i << 4) + m16) << 6) + (kh << 5) + (quad << 3));
      }
#pragma unroll
      for (int mi = 0; mi < 4; ++mi)
#pragma unroll
        for (int ni = 0; ni < 4; ++ni)
          acc[mi][ni] = MFMA(av[mi], bv[ni], acc[mi][ni]);
    }
    __syncthreads();
  }

  // ---- epilogue: stage C in LDS (bias+scale), then 128B-contiguous stores ----
  __bf16 (*Cs)[132] = (__bf16(*)[132])smem;
#pragma unroll
  for (int mi = 0; mi < 4; ++mi)
#pragma unroll
    for (int ni = 0; ni < 4; ++ni) {
      int col = wcol0 + (ni << 4) + m16;
      float bv = bias[tn0 + col];
#pragma unroll
      for (int r = 0; r < 4; ++r)
        Cs[wrow0 + (mi << 4) + (quad << 2) + r][col] =
            tobf((acc[mi][ni][r] + bv) * alpha);
    }
  __syncthreads();
  bf16* O = (z == 0) ? pq : (z == 1) ? pk : v_raw;
  const int crow = t >> 1, ch0 = (t & 1) << 6;   // 2 threads/row, 64 cols each
  long long gb = (long long)(tm0 + crow) * EE + tn0 + ch0;
#pragma unroll
  for (int j = 0; j < 64; j += 8)
    *(uint4*)(O + gb + j) = *(uint4*)&Cs[crow][ch0 + j];
}

// ================= rotary + head-reshape, pure streaming =========================
__global__ __launch_bounds__(256) void rotary_kernel(
    const bf16* __restrict__ pq, const bf16* __restrict__ pk,
    const float* __restrict__ rot_q, const float* __restrict__ rot_k,
    bf16* __restrict__ Qh, bf16* __restrict__ Kh)
{
  const bf16* src = blockIdx.y ? pk : pq;
  const float* rot = blockIdx.y ? rot_k : rot_q;
  bf16* dst = blockIdx.y ? Kh : Qh;
  const int t = threadIdx.x;
  const int row = (blockIdx.x << 2) + (t >> 6);   // l*NB + n
  const int e0 = (t & 63) << 3;                   // 8 elems per lane
  const int l = row >> 3, n = row & 7;
  bf16x8 x = *(const bf16x8*)(src + (long long)row * EE + e0);
  const float* rp = rot + ((((long long)n * LQ + l) * EE + e0) << 1);
  __bf16 vals[8];
#pragma unroll
  for (int j = 0; j < 8; j += 2) {
    float4 cs4 = *(const float4*)(rp + (j << 1));  // c0,s0,c1,s1
    float x0 = bf2f(x[j]);
    float x1 = bf2f(x[j + 1]);
    vals[j]     = tobf(x0 * cs4.x - x1 * cs4.y);
    vals[j + 1] = tobf(x1 * cs4.z + x0 * cs4.w);
  }
  const int h = e0 >> 6, d0 = e0 & 63;
  *(uint4*)(dst + (((long long)(n * NH + h) * LQ + l) * HD + d0)) = *(uint4*)vals;
}

// ================= colsum: csum[b][s] = sum_l exp(Q[l]·K[s]) (no P write) ========
__global__ __launch_bounds__(256) void colsum_kernel(
    const bf16* __restrict__ Qh, const bf16* __restrict__ Kh,
    float* __restrict__ csum)
{
  __shared__ __align__(16) __bf16 Ks[64][72];
  __shared__ __align__(16) __bf16 Qs[64][72];
  __shared__ float cpart[64][2];
  const int bid = blockIdx.y * gridDim.x + blockIdx.x;   // 0..1023
  const int xcd = bid & 7, sub = bid >> 3;               // sub in [0,128)
  const int b = (xcd << 3) + (sub >> 4);                 // 0..63
  const int st0 = (sub & 15) << 6;
  const int t = threadIdx.x;
  const int lrow = t >> 2, lcol = (t & 3) << 4;
  const int wave = t >> 6, lane = t & 63;
  const int wm = (wave & 1) << 5, wn = (wave >> 1) << 5;
  const int m16 = lane & 15, quad = lane >> 4;

  {
    const bf16* kp = Kh + ((long long)b * SK + st0 + lrow) * HD + lcol;
    *(bf16x8*)&Ks[lrow][lcol] = *(const bf16x8*)kp;
    *(bf16x8*)&Ks[lrow][lcol + 8] = *(const bf16x8*)(kp + 8);
  }
  __syncthreads();
  bf16x8 bk[2][2];   // [ni][kh]
#pragma unroll
  for (int ni = 0; ni < 2; ++ni)
#pragma unroll
    for (int kh = 0; kh < 2; ++kh)
      bk[ni][kh] = *(bf16x8*)&Ks[wn + (ni << 4) + m16][(kh << 5) + (quad << 3)];
  __syncthreads();

  const f32x4 zero = {0.f, 0.f, 0.f, 0.f};
  float colp[2] = {0.f, 0.f};
  const bf16* qbase = Qh + ((long long)b * LQ + lrow) * HD + lcol;
  bf16x8 qr0 = *(const bf16x8*)qbase;
  bf16x8 qr1 = *(const bf16x8*)(qbase + 8);
  for (int lt = 0; lt < 16; ++lt) {
    *(bf16x8*)&Qs[lrow][lcol] = qr0;
    *(bf16x8*)&Qs[lrow][lcol + 8] = qr1;
    __syncthreads();
    if (lt < 15) {            // prefetch next Q tile under compute
      const bf16* qp = qbase + (long long)((lt + 1) << 6) * HD;
      qr0 = *(const bf16x8*)qp;
      qr1 = *(const bf16x8*)(qp + 8);
    }
    f32x4 s00 = zero, s01 = zero, s10 = zero, s11 = zero;
#pragma unroll
    for (int kh = 0; kh < 2; ++kh) {
      bf16x8 a0 = *(bf16x8*)&Qs[wm + m16][(kh << 5) + (quad << 3)];
      bf16x8 a1 = *(bf16x8*)&Qs[wm + 16 + m16][(kh << 5) + (quad << 3)];
      s00 = MFMA(a0, bk[0][kh], s00);
      s01 = MFMA(a0, bk[1][kh], s01);
      s10 = MFMA(a1, bk[0][kh], s10);
      s11 = MFMA(a1, bk[1][kh], s11);
    }
    f32x4 sacc[2][2] = {{s00, s01}, {s10, s11}};
#pragma unroll
    for (int mi = 0; mi < 2; ++mi)
#pragma unroll
      for (int ni = 0; ni < 2; ++ni)
#pragma unroll
        for (int r = 0; r < 4; ++r)
          colp[ni] += __expf(sacc[mi][ni][r]);
    __syncthreads();
  }
  for (int ni = 0; ni < 2; ++ni) {
    float v = colp[ni];
    v += __shfl_down(v, 32, 64);
    v += __shfl_down(v, 16, 64);
    if (quad == 0) cpart[wn + (ni << 4) + m16][wm >> 5] = v;
  }
  __syncthreads();
  if (t < 64) csum[b * SK + st0 + t] = cpart[t][0] + cpart[t][1];
}

// ================= Vsum[b][d] = sum_s Vt[b][d][s] ================================
__global__ __launch_bounds__(256) void vsum_kernel(
    const bf16* __restrict__ Vt, float* __restrict__ Vsum)
{
  int wid = blockIdx.x * 4 + (threadIdx.x >> 6);
  int lane = threadIdx.x & 63;
  const bf16* p = Vt + (long long)wid * SK + lane * 16;
  float s = 0.f;
  bf16x8 v0 = *(const bf16x8*)p;
  bf16x8 v1 = *(const bf16x8*)(p + 8);
#pragma unroll
  for (int j = 0; j < 8; ++j) s += bf2f(v0[j]) + bf2f(v1[j]);
  for (int off = 32; off; off >>= 1) s += __shfl_down(s, off, 64);
  if (lane == 0) Vsum[wid] = s;
}

// ================= flash slot-attn: swapped QK^T, packed P writes ================
// QK computed as MFMA(K,Q) -> S^T: rows=s (quad*4+r), cols=l (lane&15).
// P stored [l][64 s] linear bf16, byte swizzle: ^= (l&7)<<4 (conflict-minimal
// for both the 8B packed writes and the 16B PV A-fragment reads).
__global__ __launch_bounds__(256) void attn_flash(
    const bf16* __restrict__ Qh, const bf16* __restrict__ Kh,
    const bf16* __restrict__ Vt, const float* __restrict__ csum,
    const float* __restrict__ Vsum, bf16* __restrict__ attn)
{
  __shared__ __align__(16) __bf16 Ks[64][72];
  __shared__ __align__(16) __bf16 Vs[64][72];
  __shared__ __align__(16) __bf16 Ps[4096];   // [64][64] swizzled
  __shared__ __align__(16) float rcs[SK];
  __shared__ float rpart[64][2];
  const int bid = blockIdx.y * gridDim.x + blockIdx.x;   // 0..1023
  const int xcd = bid & 7, sub = bid >> 3;               // sub in [0,128)
  const int b = (xcd << 3) + (sub >> 4);                 // 0..63
  const int tm0 = (sub & 15) << 6;
  const int t = threadIdx.x;
  const int lrow = t >> 2, lcol = (t & 3) << 4;
  const int wave = t >> 6, lane = t & 63;
  const int wm = (wave & 1) << 5, wn = (wave >> 1) << 5;
  const int m16 = lane & 15, quad = lane >> 4;
  const int swz = (m16 & 7) << 4;

#pragma unroll
  for (int i = 0; i < 4; ++i)
    rcs[t + i * 256] = 1.f / csum[b * SK + t + i * 256];
  {
    const bf16* qp = Qh + ((long long)b * LQ + tm0 + lrow) * HD + lcol;
    *(bf16x8*)&Ks[lrow][lcol] = *(const bf16x8*)qp;
    *(bf16x8*)&Ks[lrow][lcol + 8] = *(const bf16x8*)(qp + 8);
  }
  __syncthreads();
  bf16x8 aq[2][2];
#pragma unroll
  for (int li = 0; li < 2; ++li)
#pragma unroll
    for (int kh = 0; kh < 2; ++kh)
      aq[li][kh] = *(bf16x8*)&Ks[wm + (li << 4) + m16][(kh << 5) + (quad << 3)];
  __syncthreads();

  const f32x4 zero = {0.f, 0.f, 0.f, 0.f};
  f32x4 o00 = zero, o01 = zero, o10 = zero, o11 = zero;
  float rsuml[2] = {0.f, 0.f};

  const bf16* kbase = Kh + ((long long)b * SK + lrow) * HD + lcol;
  const bf16* vbase = Vt + ((long long)b * HD + lrow) * SK + lcol;
  bf16x8 kr0 = *(const bf16x8*)kbase;
  bf16x8 kr1 = *(const bf16x8*)(kbase + 8);
  bf16x8 vr0 = *(const bf16x8*)vbase;
  bf16x8 vr1 = *(const bf16x8*)(vbase + 8);

  for (int st = 0; st < 16; ++st) {
    *(bf16x8*)&Ks[lrow][lcol] = kr0;
    *(bf16x8*)&Ks[lrow][lcol + 8] = kr1;
    *(bf16x8*)&Vs[lrow][lcol] = vr0;
    *(bf16x8*)&Vs[lrow][lcol + 8] = vr1;
    __syncthreads();
    if (st < 15) {            // prefetch next K/V tiles under compute
      const bf16* kp = kbase + (long long)((st + 1) << 6) * HD;
      const bf16* vp = vbase + ((st + 1) << 6);
      kr0 = *(const bf16x8*)kp;
      kr1 = *(const bf16x8*)(kp + 8);
      vr0 = *(const bf16x8*)vp;
      vr1 = *(const bf16x8*)(vp + 8);
    }
    // swapped QK: s_acc[si][li] has rows = s (A=K), cols = l (B=Q)
    f32x4 s00 = zero, s01 = zero, s10 = zero, s11 = zero;
#pragma unroll
    for (int kh = 0; kh < 2; ++kh) {
      bf16x8 ak0 = *(bf16x8*)&Ks[wn + m16][(kh << 5) + (quad << 3)];
      bf16x8 ak1 = *(bf16x8*)&Ks[wn + 16 + m16][(kh << 5) + (quad << 3)];
      s00 = MFMA(ak0, aq[0][kh], s00);
      s01 = MFMA(ak0, aq[1][kh], s01);
      s10 = MFMA(ak1, aq[0][kh], s10);
      s11 = MFMA(ak1, aq[1][kh], s11);
    }
    {
      const int lA = wm + m16, lB = wm + 16 + m16;
      char* pA = (char*)Ps + lA * 128;
      char* pB = (char*)Ps + lB * 128;
#pragma unroll
      for (int si = 0; si < 2; ++si) {
        int sloc = wn + (si << 4) + (quad << 2);
        f32x4 rc4 = *(const f32x4*)&rcs[(st << 6) + sloc];
        f32x4 sA = si ? s10 : s00;   // li=0
        f32x4 sB = si ? s11 : s01;   // li=1
        __bf16 vA[4], vB[4];
#pragma unroll
        for (int r = 0; r < 4; ++r) {
          float pa = __expf(sA[r]) * rc4[r];
          rsuml[0] += pa; vA[r] = tobf(pa);
          float pb = __expf(sB[r]) * rc4[r];
          rsuml[1] += pb; vB[r] = tobf(pb);
        }
        int sbyte = (sloc << 1) ^ swz;
        *(uint2*)(pA + sbyte) = *(uint2*)vA;
        *(uint2*)(pB + sbyte) = *(uint2*)vB;
      }
    }
    __syncthreads();
#pragma unroll
    for (int kh = 0; kh < 2; ++kh) {
      int sb = (kh << 6) + (quad << 4);
      bf16x8 ap0 = *(bf16x8*)((char*)Ps + (wm + m16) * 128 + (sb ^ swz));
      bf16x8 ap1 = *(bf16x8*)((char*)Ps + (wm + 16 + m16) * 128 + (sb ^ swz));
      bf16x8 bv0 = *(bf16x8*)&Vs[wn + m16][(kh << 5) + (quad << 3)];
      bf16x8 bv1 = *(bf16x8*)&Vs[wn + 16 + m16][(kh << 5) + (quad << 3)];
      o00 = MFMA(ap0, bv0, o00);
      o01 = MFMA(ap0, bv1, o01);
      o10 = MFMA(ap1, bv0, o10);
      o11 = MFMA(ap1, bv1, o11);
    }
    __syncthreads();
  }
#pragma unroll
  for (int li = 0; li < 2; ++li) {
    float v = rsuml[li];
    v += __shfl_xor(v, 16, 64);
    v += __shfl_xor(v, 32, 64);
    if (quad == 0) rpart[wm + (li << 4) + m16][wn >> 5] = v;
  }
  __syncthreads();
  const float* vs = Vsum + b * HD;
  f32x4 oacc[2][2] = {{o00, o01}, {o10, o11}};
  for (int mi = 0; mi < 2; ++mi)
    for (int ni = 0; ni < 2; ++ni) {
      int col = wn + (ni << 4) + m16;
      float vsc = 1e-8f * vs[col];
      for (int r = 0; r < 4; ++r) {
        int row = wm + (mi << 4) + (quad << 2) + r;
        float rs = rpart[row][0] + rpart[row][1];
        Ks[row][col] = tobf((oacc[mi][ni][r] + vsc) / (rs + (float)SK * 1e-8f));
      }
    }
  __syncthreads();
  uint4 u0 = *(uint4*)&Ks[lrow][lcol];
  uint4 u1 = *(uint4*)&Ks[lrow][lcol + 8];
  long long gb = ((long long)b * LQ + tm0 + lrow) * HD + lcol;
  *(uint4*)(attn + gb) = u0;
  *(uint4*)(attn + gb + 8) = u1;
}

// ================= fully-fused mem branch (swapped QK, packed P) =================
__global__ __launch_bounds__(256) void mem_flash(
    const bf16* __restrict__ Qh, const bf16* __restrict__ km,
    const bf16* __restrict__ vmt, const int* __restrict__ mask,
    bf16* __restrict__ omb)
{
  __shared__ __align__(16) __bf16 Ks[64][72];
  __shared__ __align__(16) __bf16 Vs[64][72];
  __shared__ __align__(16) __bf16 Ps[4096];   // [64][64] swizzled
  __shared__ __align__(16) float mskf[MMEM];
  __shared__ float rpart[64][2];
  const int bid = blockIdx.y * gridDim.x + blockIdx.x;   // 0..1023
  const int xcd = bid & 7, sub = bid >> 3;               // sub in [0,128)
  const int b = (xcd << 3) + (sub >> 4);                 // 0..63
  const int tm0 = (sub & 15) << 6;
  const int n = b >> 3;
  const int t = threadIdx.x;
  const int wave = t >> 6, lane = t & 63;
  const int wm = (wave & 1) << 5, wn = (wave >> 1) << 5;
  const int m16 = lane & 15, quad = lane >> 4;
  const int lrow = t >> 2, lcol = (t & 3) << 4;
  const int swz = (m16 & 7) << 4;

  mskf[t] = mask[n * MMEM + t] ? 0.f : 1.f;
  {
    const bf16* qp = Qh + ((long long)b * LQ + tm0 + lrow) * HD + lcol;
    *(bf16x8*)&Ks[lrow][lcol] = *(const bf16x8*)qp;
    *(bf16x8*)&Ks[lrow][lcol + 8] = *(const bf16x8*)(qp + 8);
  }
  __syncthreads();
  bf16x8 aq[2][2];
#pragma unroll
  for (int li = 0; li < 2; ++li)
#pragma unroll
    for (int kh = 0; kh < 2; ++kh)
      aq[li][kh] = *(bf16x8*)&Ks[wm + (li << 4) + m16][(kh << 5) + (quad << 3)];
  __syncthreads();

  const f32x4 zero = {0.f, 0.f, 0.f, 0.f};
  f32x4 o00 = zero, o01 = zero, o10 = zero, o11 = zero;
  float rsuml[2] = {0.f, 0.f};

  const bf16* kbase = km + ((long long)b * MMEM + lrow) * HD + lcol;
  const bf16* vbase = vmt + ((long long)b * HD + lrow) * MMEM + lcol;
  bf16x8 kr0 = *(const bf16x8*)kbase;
  bf16x8 kr1 = *(const bf16x8*)(kbase + 8);
  bf16x8 vr0 = *(const bf16x8*)vbase;
  bf16x8 vr1 = *(const bf16x8*)(vbase + 8);

  for (int mt = 0; mt < 4; ++mt) {
    *(bf16x8*)&Ks[lrow][lcol] = kr0;
    *(bf16x8*)&Ks[lrow][lcol + 8] = kr1;
    *(bf16x8*)&Vs[lrow][lcol] = vr0;
    *(bf16x8*)&Vs[lrow][lcol + 8] = vr1;
    __syncthreads();
    if (mt < 3) {             // prefetch next K/V tiles under compute
      const bf16* kp = kbase + (long long)((mt + 1) << 6) * HD;
      const bf16* vp = vbase + ((mt + 1) << 6);
      kr0 = *(const bf16x8*)kp;
      kr1 = *(const bf16x8*)(kp + 8);
      vr0 = *(const bf16x8*)vp;
      vr1 = *(const bf16x8*)(vp + 8);
    }
    f32x4 s00 = zero, s01 = zero, s10 = zero, s11 = zero;
#pragma unroll
    for (int kh = 0; kh < 2; ++kh) {
      bf16x8 ak0 = *(bf16x8*)&Ks[wn + m16][(kh << 5) + (quad << 3)];
      bf16x8 ak1 = *(bf16x8*)&Ks[wn + 16 + m16][(kh << 5) + (quad << 3)];
      s00 = MFMA(ak0, aq[0][kh], s00);
      s01 = MFMA(ak0, aq[1][kh], s01);
      s10 = MFMA(ak1, aq[0][kh], s10);
      s11 = MFMA(ak1, aq[1][kh], s11);
    }
    {
      const int lA = wm + m16, lB = wm + 16 + m16;
      char* pA = (char*)Ps + lA * 128;
      char* pB = (char*)Ps + lB * 128;
#pragma unroll
      for (int si = 0; si < 2; ++si) {
        int sloc = wn + (si << 4) + (quad << 2);
        f32x4 mf4 = *(const f32x4*)&mskf[(mt << 6) + sloc];
        f32x4 sA = si ? s10 : s00;
        f32x4 sB = si ? s11 : s01;
        __bf16 vA[4], vB[4];
#pragma unroll
        for (int r = 0; r < 4; ++r) {
          float pa = __expf(sA[r]) * mf4[r];
          rsuml[0] += pa; vA[r] = tobf(pa);
          float pb = __expf(sB[r]) * mf4[r];
          rsuml[1] += pb; vB[r] = tobf(pb);
        }
        int sbyte = (sloc << 1) ^ swz;
        *(uint2*)(pA + sbyte) = *(uint2*)vA;
        *(uint2*)(pB + sbyte) = *(uint2*)vB;
      }
    }
    __syncthreads();
#pragma unroll
    for (int kh = 0; kh < 2; ++kh) {
      int sb = (kh << 6) + (quad << 4);
      bf16x8 ap0 = *(bf16x8*)((char*)Ps + (wm + m16) * 128 + (sb ^ swz));
      bf16x8 ap1 = *(bf16x8*)((char*)Ps + (wm + 16 + m16) * 128 + (sb ^ swz));
      bf16x8 bv0 = *(bf16x8*)&Vs[wn + m16][(kh << 5) + (quad << 3)];
      bf16x8 bv1 = *(bf16x8*)&Vs[wn + 16 + m16][(kh << 5) + (quad << 3)];
      o00 = MFMA(ap0, bv0, o00);
      o01 = MFMA(ap0, bv1, o01);
      o10 = MFMA(ap1, bv0, o10);
      o11 = MFMA(ap1, bv1, o11);
    }
    __syncthreads();
  }
#pragma unroll
  for (int li = 0; li < 2; ++li) {
    float v = rsuml[li];
    v += __shfl_xor(v, 16, 64);
    v += __shfl_xor(v, 32, 64);
    if (quad == 0) rpart[wm + (li << 4) + m16][wn >> 5] = v;
  }
  __syncthreads();
  f32x4 oacc[2][2] = {{o00, o01}, {o10, o11}};
  for (int mi = 0; mi < 2; ++mi)
    for (int ni = 0; ni < 2; ++ni) {
      int col = wn + (ni << 4) + m16;
      for (int r = 0; r < 4; ++r) {
        int row = wm + (mi << 4) + (quad << 2) + r;
        float rs = rpart[row][0] + rpart[row][1];
        Ks[row][col] = tobf(oacc[mi][ni][r] / rs);
      }
    }
  __syncthreads();
  uint4 u0 = *(uint4*)&Ks[lrow][lcol];
  uint4 u1 = *(uint4*)&Ks[lrow][lcol + 8];
  long long gb = ((long long)b * LQ + tm0 + lrow) * HD + lcol;
  *(uint4*)(omb + gb) = u0;
  *(uint4*)(omb + gb + 8) = u1;
}

// ================= out proj with fused gate-combine A (bf16 W) ===================
__global__ __launch_bounds__(256) void gemm_out(
    const bf16* __restrict__ attn, const bf16* __restrict__ omb,
    const float* __restrict__ gate, const bf16* __restrict__ opwb,
    const float* __restrict__ opb, float* __restrict__ out)
{
  __shared__ __align__(16) __bf16 As[64][40];
  __shared__ __align__(16) __bf16 Bs[64][40];
  __shared__ float sg[NH];
  const int bid = blockIdx.y * gridDim.x + blockIdx.x;   // 0..1023
  const int xcd = bid & 7, sub = bid >> 3;               // sub in [0,128)
  const int by = (xcd << 4) + (sub >> 3);                // 0..127
  const int bx = sub & 7;                                // 0..7
  const int tm0 = by << 6, tn0 = bx << 6;
  const int t = threadIdx.x;
  const int lrow = t >> 2, lk = (t & 3) << 3;
  const int wave = t >> 6, lane = t & 63;
  const int wm = (wave & 1) << 5, wn = (wave >> 1) << 5;
  const int m16 = lane & 15, quad = lane >> 4;

  if (t < NH) sg[t] = 1.f / (1.f + __expf(-gate[t]));
  __syncthreads();

  const f32x4 zero = {0.f, 0.f, 0.f, 0.f};
  f32x4 acc00 = zero, acc01 = zero, acc10 = zero, acc11 = zero;

  const int row = tm0 + lrow;
  const int l = row >> 3, n = row & 7;
  const bf16* bg = opwb + (long long)(tn0 + lrow) * EE + lk;
  for (int k0 = 0; k0 < EE; k0 += 32) {
    int e = k0 + lk;
    int h = e >> 6, d = e & 63;
    float g = sg[h];
    long long src = (((long long)(n * NH + h) * LQ) + l) * HD + d;
    bf16x8 a8 = *(const bf16x8*)(attn + src);
    bf16x8 o8 = *(const bf16x8*)(omb + src);
    bf16x8 ap;
#pragma unroll
    for (int j = 0; j < 8; ++j)
      ap[j] = tobf(g * bf2f(o8[j]) + (1.f - g) * bf2f(a8[j]));
    *(bf16x8*)&As[lrow][lk] = ap;
    *(bf16x8*)&Bs[lrow][lk] = *(const bf16x8*)(bg + k0);
    __syncthreads();
    bf16x8 a0 = *(bf16x8*)&As[wm + m16][quad << 3];
    bf16x8 a1 = *(bf16x8*)&As[wm + 16 + m16][quad << 3];
    bf16x8 b0 = *(bf16x8*)&Bs[wn + m16][quad << 3];
    bf16x8 b1 = *(bf16x8*)&Bs[wn + 16 + m16][quad << 3];
    acc00 = MFMA(a0, b0, acc00);
    acc01 = MFMA(a0, b1, acc01);
    acc10 = MFMA(a1, b0, acc10);
    acc11 = MFMA(a1, b1, acc11);
    __syncthreads();
  }
  f32x4 accs[2][2] = {{acc00, acc01}, {acc10, acc11}};
  for (int mi = 0; mi < 2; ++mi)
    for (int ni = 0; ni < 2; ++ni) {
      int col = tn0 + wn + (ni << 4) + m16;
      float bv = opb[col];
      long long base = (long long)(tm0 + wm + (mi << 4) + (quad << 2)) * EE + col;
      for (int r = 0; r < 4; ++r)
        out[base + (long long)r * EE] = accs[mi][ni][r] + bv;
    }
}

// ================= LDS-tiled transposes (no 2B-granular scatter) =================
__global__ __launch_bounds__(256) void v_transpose(
    const bf16* __restrict__ raw, bf16* __restrict__ Vt)
{
  __shared__ __align__(16) __bf16 Ts[64][72];
  const int bh = blockIdx.y;             // n*NH + h
  const int n = bh >> 3, h = bh & 7;
  const int s0 = blockIdx.x << 6;
  const int t = threadIdx.x;
  const int i = t >> 2, c0 = (t & 3) << 4;
  const bf16* rp = raw + ((long long)(s0 + i) * NB + n) * EE + h * HD + c0;
  *(bf16x8*)&Ts[i][c0] = *(const bf16x8*)rp;
  *(bf16x8*)&Ts[i][c0 + 8] = *(const bf16x8*)(rp + 8);
  __syncthreads();
  const int d = t >> 2, j0 = (t & 3) << 4;
  __bf16 vals[16];
#pragma unroll
  for (int j = 0; j < 16; ++j) vals[j] = Ts[j0 + j][d];
  bf16* wp = Vt + ((long long)bh * HD + d) * SK + s0 + j0;
  *(uint4*)wp = *(uint4*)&vals[0];
  *(uint4*)(wp + 8) = *(uint4*)&vals[8];
}

__global__ __launch_bounds__(256) void mem_prep(
    const float* __restrict__ k_mem, const float* __restrict__ v_mem,
    bf16* __restrict__ km, bf16* __restrict__ vmt)
{
  __shared__ __align__(16) __bf16 Ts[64][72];
  const int bh = blockIdx.y;             // n*NH + h
  const int n = bh >> 3, h = bh & 7;
  const int m0 = blockIdx.x << 6;
  const int t = threadIdx.x;
  const int i = t >> 2, c0 = (t & 3) << 4;
  const float* kp = k_mem + ((long long)(m0 + i) * NB + n) * EE + h * HD + c0;
  const float* vp = v_mem + ((long long)(m0 + i) * NB + n) * EE + h * HD + c0;
  bf16x8 kv0 = load8(kp), kv1 = load8(kp + 8);
  bf16x8 vv0 = load8(vp), vv1 = load8(vp + 8);
  bf16* kw = km + ((long long)bh * MMEM + m0 + i) * HD + c0;
  *(bf16x8*)kw = kv0;
  *(bf16x8*)(kw + 8) = kv1;
  *(bf16x8*)&Ts[i][c0] = vv0;
  *(bf16x8*)&Ts[i][c0 + 8] = vv1;
  __syncthreads();
  const int d = t >> 2, j0 = (t & 3) << 4;
  __bf16 vals[16];
#pragma unroll
  for (int j = 0; j < 16; ++j) vals[j] = Ts[j0 + j][d];
  bf16* wp = vmt + ((long long)bh * HD + d) * MMEM + m0 + j0;
  *(uint4*)wp = *(uint4*)&vals[0];
  *(uint4*)(wp + 8) = *(uint4*)&vals[8];
}

extern "C" void kernel_launch(void* const* d_in, const int* in_sizes, int n_in,
                              void* d_out, int out_size, void* d_ws, size_t ws_size,
                              hipStream_t stream) {
  const float* query = (const float*)d_in[0];
  const float* key   = (const float*)d_in[1];
  const float* value = (const float*)d_in[2];
  const float* ipw   = (const float*)d_in[3];
  const float* ipb   = (const float*)d_in[4];
  const float* opw   = (const float*)d_in[5];
  const float* opb   = (const float*)d_in[6];
  const float* rot_q = (const float*)d_in[7];
  const float* rot_k = (const float*)d_in[8];
  const float* k_mem = (const float*)d_in[9];
  const float* v_mem = (const float*)d_in[10];
  const float* gate  = (const float*)d_in[11];
  const int*  mask   = (const int*)d_in[12];
  float* out = (float*)d_out;

  char* w = (char*)d_ws;
  size_t off = 0;
  auto carve = [&](size_t bytes) -> char* {
    char* p = w + off;
    off += (bytes + 255) & ~(size_t)255;
    return p;
  };
  bf16* qc    = (bf16*)carve((size_t)LQ * NB * EE * 2);
  bf16* kc    = (bf16*)carve((size_t)SK * NB * EE * 2);
  bf16* vc    = (bf16*)carve((size_t)SK * NB * EE * 2);
  bf16* ipwb  = (bf16*)carve((size_t)3 * EE * EE * 2);
  bf16* opwb  = (bf16*)carve((size_t)EE * EE * 2);
  bf16* v_raw = (bf16*)carve((size_t)SK * NB * EE * 2);
  bf16* Qh    = (bf16*)carve((size_t)NBH * LQ * HD * 2);
  bf16* Kh    = (bf16*)carve((size_t)NBH * SK * HD * 2);
  bf16* Vt    = (bf16*)carve((size_t)NBH * HD * SK * 2);
  bf16* km    = (bf16*)carve((size_t)NBH * MMEM * HD * 2);
  bf16* vmt   = (bf16*)carve((size_t)NBH * HD * MMEM * 2);
  float* csum = (float*)carve((size_t)NBH * SK * 4);
  float* Vsum = (float*)carve((size_t)NBH * HD * 4);
  bf16* attn  = (bf16*)carve((size_t)NBH * LQ * HD * 2);
  bf16* omb   = (bf16*)carve((size_t)NBH * LQ * HD * 2);
  if (off > ws_size) {
    hipMemsetAsync(d_out, 0, (size_t)out_size * 4, stream);
    return;
  }
  // pq/pk alias attn/omb: those buffers are only written later (attn_flash /
  // mem_flash), well after rotary_kernel has consumed pq/pk.
  bf16* pq = attn;
  bf16* pk = omb;

  // 0) pre-convert GEMM inputs to bf16 (identical rounding point as before)
  convert5<<<(3 * CVT_T0 + CVT_T3 + CVT_T4) / 256, 256, 0, stream>>>(
      query, key, value, ipw, opw, qc, kc, vc, ipwb, opwb);

  // 1) q/k/v projections, pure GEMM (128x128 m97 structure, XCD-swizzled)
  gemm_proj3<<<dim3(EE / 128, (LQ * NB) / 128, 3), 256, 0, stream>>>(
      qc, kc, vc, ipwb, ipb, pq, pk, v_raw);

  // 1b) rotary + head reshape as a pure streaming kernel
  rotary_kernel<<<dim3((LQ * NB) / 4, 2), 256, 0, stream>>>(
      pq, pk, rot_q, rot_k, Qh, Kh);

  // 2) v transpose (LDS-tiled) + Vsum; mem k/v repack (LDS-tiled)
  v_transpose<<<dim3(SK / 64, NBH), 256, 0, stream>>>(v_raw, Vt);
  vsum_kernel<<<(NBH * HD) / 4, 256, 0, stream>>>(Vt, Vsum);
  mem_prep<<<dim3(MMEM / 64, NBH), 256, 0, stream>>>(k_mem, v_mem, km, vmt);

  // 3) column sums of exp(scores) -- no P materialization (XCD-swizzled)
  colsum_kernel<<<dim3(SK / 64, NBH), 256, 0, stream>>>(Qh, Kh, csum);

  // 4) flash-style slot attn (recompute scores) + mem branch (XCD-swizzled)
  attn_flash<<<dim3(LQ / 64, NBH), 256, 0, stream>>>(Qh, Kh, Vt, csum, Vsum, attn);
  mem_flash<<<dim3(LQ / 64, NBH), 256, 0, stream>>>(Qh, km, vmt, mask, omb);

  // 5) out-proj with fused sigmoid-gate combine (XCD-swizzled)
  gemm_out<<<dim3(EE / 64, (LQ * NB) / 64, 1), 256, 0, stream>>>(attn, omb, gate, opwb, opb, out);
}

// Round 5
// 304.930 us; speedup vs baseline: 1.1634x; 1.0035x over previous
//
#include <hip/hip_runtime.h>
#include <hip/hip_bf16.h>

typedef __hip_bfloat16 bf16;
typedef __bf16 bf16x8 __attribute__((ext_vector_type(8)));
typedef float f32x4 __attribute__((ext_vector_type(4)));

#define LQ 1024
#define SK 1024
#define MMEM 256
#define NB 8
#define EE 512
#define NH 8
#define HD 64
#define NBH 64  // NB*NH batched (n,h) pairs

__device__ inline __bf16 tobf(float f) {
  __hip_bfloat16 h = __float2bfloat16(f);
  return *reinterpret_cast<__bf16*>(&h);
}
__device__ inline float bf2f(__bf16 x) {
  unsigned short u; __builtin_memcpy(&u, &x, 2);
  unsigned int v = (unsigned int)u << 16;
  float f; __builtin_memcpy(&f, &v, 4);
  return f;
}
__device__ inline f32x4 MFMA(bf16x8 a, bf16x8 b, f32x4 c) {
  return __builtin_amdgcn_mfma_f32_16x16x32_bf16(a, b, c, 0, 0, 0);
}

// async global->LDS, 16B per lane. LDS dest is wave-uniform base + lane*16.
__device__ inline void gload_lds16(const bf16* g, void* l) {
  __builtin_amdgcn_global_load_lds(
      (const __attribute__((address_space(1))) void*)g,
      (__attribute__((address_space(3))) void*)l, 16, 0, 0);
}

__device__ inline bf16x8 load8(const float* p) {
  float4 a = *(const float4*)p;
  float4 b = *(const float4*)(p + 4);
  bf16x8 r;
  r[0] = tobf(a.x); r[1] = tobf(a.y); r[2] = tobf(a.z); r[3] = tobf(a.w);
  r[4] = tobf(b.x); r[5] = tobf(b.y); r[6] = tobf(b.z); r[7] = tobf(b.w);
  return r;
}

// ================= bf16 pre-conversion of GEMM inputs ============================
#define CVT_T0 524288   // threads per q/k/v region (8 elems each)
#define CVT_T3 98304    // ipw
#define CVT_T4 32768    // opw
__global__ __launch_bounds__(256) void convert5(
    const float* __restrict__ q, const float* __restrict__ k,
    const float* __restrict__ v, const float* __restrict__ w,
    const float* __restrict__ o, bf16* __restrict__ qc, bf16* __restrict__ kc,
    bf16* __restrict__ vc, bf16* __restrict__ wc, bf16* __restrict__ oc)
{
  long long t = (long long)blockIdx.x * 256 + threadIdx.x;
  const float* src; bf16* dst; long long idx;
  if (t < CVT_T0)               { src = q; dst = qc; idx = t; }
  else if (t < 2 * CVT_T0)      { src = k; dst = kc; idx = t - CVT_T0; }
  else if (t < 3 * CVT_T0)      { src = v; dst = vc; idx = t - 2 * CVT_T0; }
  else if (t < 3 * CVT_T0 + CVT_T3) { src = w; dst = wc; idx = t - 3 * CVT_T0; }
  else                          { src = o; dst = oc; idx = t - 3 * CVT_T0 - CVT_T3; }
  *(bf16x8*)(dst + idx * 8) = load8(src + idx * 8);
}

// ================= 3-in-1 projection GEMM, m97-structure, PURE GEMM ==============
__global__ __launch_bounds__(256) void gemm_proj3(
    const bf16* __restrict__ qc, const bf16* __restrict__ kc,
    const bf16* __restrict__ vc, const bf16* __restrict__ ipwb,
    const float* __restrict__ ipb, bf16* __restrict__ pq,
    bf16* __restrict__ pk, bf16* __restrict__ v_raw)
{
  __shared__ __align__(16) char smem[33792];
  __bf16* As = (__bf16*)smem;             // [128][64] linear, 16384 B
  __bf16* Bs = (__bf16*)(smem + 16384);   // [128][64] linear, 16384 B
  const int z = blockIdx.z;
  const bf16* A = (z == 0) ? qc : (z == 1) ? kc : vc;
  const bf16* W = ipwb + (long long)z * EE * EE;
  const float* bias = ipb + z * EE;
  const float alpha = (z == 0) ? 0.125f : 1.f;
  // XCD-aware remap (bijective): bid2 in [0,256) per z
  const int bid2 = blockIdx.y * gridDim.x + blockIdx.x;
  const int xcd = bid2 & 7, sub = bid2 >> 3;       // sub in [0,32)
  const int by = (xcd << 3) + (sub >> 2);          // 0..63
  const int bx = sub & 3;                          // 0..3
  const int tm0 = by << 7, tn0 = bx << 7;          // 128 x 128
  const int t = threadIdx.x;
  const int wave = t >> 6, lane = t & 63;
  const int wrow0 = (wave & 1) << 6, wcol0 = (wave >> 1) << 6;
  const int m16 = lane & 15, quad = lane >> 4;

  const f32x4 zero = {0.f, 0.f, 0.f, 0.f};
  f32x4 acc[4][4];
#pragma unroll
  for (int mi = 0; mi < 4; ++mi)
#pragma unroll
    for (int ni = 0; ni < 4; ++ni) acc[mi][ni] = zero;

  const bf16* Ab = A + (long long)tm0 * EE;
  const bf16* Bb = W + (long long)tn0 * EE;
  const int ob_u = wave << 10;  // wave-uniform byte base within 4KB chunk

  for (int k0 = 0; k0 < EE; k0 += 64) {
#pragma unroll
    for (int c = 0; c < 4; ++c) {
      int ob = (c << 12) + ob_u;          // uniform LDS byte base
      int obl = ob + (lane << 4);         // this lane's slot
      int row = obl >> 7;                 // tile row (stride 128 B)
      int ce = (obl & 127) >> 1;          // element within row
      gload_lds16(Ab + (long long)row * EE + k0 + ce, smem + ob);
      gload_lds16(Bb + (long long)row * EE + k0 + ce, smem + 16384 + ob);
    }
    __syncthreads();
#pragma unroll
    for (int kh = 0; kh < 2; ++kh) {
      bf16x8 av[4], bv[4];
#pragma unroll
      for (int i = 0; i < 4; ++i) {
        av[i] = *(bf16x8*)(As + ((wrow0 + (i << 4) + m16) << 6) + (kh << 5) + (quad << 3));
        bv[i] = *(bf16x8*)(Bs + ((wcol0 + (i << 4) + m16) << 6) + (kh << 5) + (quad << 3));
      }
#pragma unroll
      for (int mi = 0; mi < 4; ++mi)
#pragma unroll
        for (int ni = 0; ni < 4; ++ni)
          acc[mi][ni] = MFMA(av[mi], bv[ni], acc[mi][ni]);
    }
    __syncthreads();
  }

  // ---- epilogue: stage C in LDS (bias+scale), then 128B-contiguous stores ----
  __bf16 (*Cs)[132] = (__bf16(*)[132])smem;
#pragma unroll
  for (int mi = 0; mi < 4; ++mi)
#pragma unroll
    for (int ni = 0; ni < 4; ++ni) {
      int col = wcol0 + (ni << 4) + m16;
      float bv = bias[tn0 + col];
#pragma unroll
      for (int r = 0; r < 4; ++r)
        Cs[wrow0 + (mi << 4) + (quad << 2) + r][col] =
            tobf((acc[mi][ni][r] + bv) * alpha);
    }
  __syncthreads();
  bf16* O = (z == 0) ? pq : (z == 1) ? pk : v_raw;
  const int crow = t >> 1, ch0 = (t & 1) << 6;   // 2 threads/row, 64 cols each
  long long gb = (long long)(tm0 + crow) * EE + tn0 + ch0;
#pragma unroll
  for (int j = 0; j < 64; j += 8)
    *(uint4*)(O + gb + j) = *(uint4*)&Cs[crow][ch0 + j];
}

// ================= rotary + head-reshape, pure streaming =========================
__global__ __launch_bounds__(256) void rotary_kernel(
    const bf16* __restrict__ pq, const bf16* __restrict__ pk,
    const float* __restrict__ rot_q, const float* __restrict__ rot_k,
    bf16* __restrict__ Qh, bf16* __restrict__ Kh)
{
  const bf16* src = blockIdx.y ? pk : pq;
  const float* rot = blockIdx.y ? rot_k : rot_q;
  bf16* dst = blockIdx.y ? Kh : Qh;
  const int t = threadIdx.x;
  const int row = (blockIdx.x << 2) + (t >> 6);   // l*NB + n
  const int e0 = (t & 63) << 3;                   // 8 elems per lane
  const int l = row >> 3, n = row & 7;
  bf16x8 x = *(const bf16x8*)(src + (long long)row * EE + e0);
  const float* rp = rot + ((((long long)n * LQ + l) * EE + e0) << 1);
  __bf16 vals[8];
#pragma unroll
  for (int j = 0; j < 8; j += 2) {
    float4 cs4 = *(const float4*)(rp + (j << 1));  // c0,s0,c1,s1
    float x0 = bf2f(x[j]);
    float x1 = bf2f(x[j + 1]);
    vals[j]     = tobf(x0 * cs4.x - x1 * cs4.y);
    vals[j + 1] = tobf(x1 * cs4.z + x0 * cs4.w);
  }
  const int h = e0 >> 6, d0 = e0 & 63;
  *(uint4*)(dst + (((long long)(n * NH + h) * LQ + l) * HD + d0)) = *(uint4*)vals;
}

// ================= colsum: csum[b][s] = sum_l exp(Q[l]·K[s]) (no P write) ========
__global__ __launch_bounds__(256) void colsum_kernel(
    const bf16* __restrict__ Qh, const bf16* __restrict__ Kh,
    float* __restrict__ csum)
{
  __shared__ __align__(16) __bf16 Ks[64][72];
  __shared__ __align__(16) __bf16 Qs[64][72];
  __shared__ float cpart[64][2];
  const int bid = blockIdx.y * gridDim.x + blockIdx.x;   // 0..1023
  const int xcd = bid & 7, sub = bid >> 3;               // sub in [0,128)
  const int b = (xcd << 3) + (sub >> 4);                 // 0..63
  const int st0 = (sub & 15) << 6;
  const int t = threadIdx.x;
  const int lrow = t >> 2, lcol = (t & 3) << 4;
  const int wave = t >> 6, lane = t & 63;
  const int wm = (wave & 1) << 5, wn = (wave >> 1) << 5;
  const int m16 = lane & 15, quad = lane >> 4;

  {
    const bf16* kp = Kh + ((long long)b * SK + st0 + lrow) * HD + lcol;
    *(bf16x8*)&Ks[lrow][lcol] = *(const bf16x8*)kp;
    *(bf16x8*)&Ks[lrow][lcol + 8] = *(const bf16x8*)(kp + 8);
  }
  __syncthreads();
  bf16x8 bk[2][2];   // [ni][kh]
#pragma unroll
  for (int ni = 0; ni < 2; ++ni)
#pragma unroll
    for (int kh = 0; kh < 2; ++kh)
      bk[ni][kh] = *(bf16x8*)&Ks[wn + (ni << 4) + m16][(kh << 5) + (quad << 3)];
  __syncthreads();

  const f32x4 zero = {0.f, 0.f, 0.f, 0.f};
  float colp[2] = {0.f, 0.f};
  const bf16* qbase = Qh + ((long long)b * LQ + lrow) * HD + lcol;
  bf16x8 qr0 = *(const bf16x8*)qbase;
  bf16x8 qr1 = *(const bf16x8*)(qbase + 8);
  for (int lt = 0; lt < 16; ++lt) {
    *(bf16x8*)&Qs[lrow][lcol] = qr0;
    *(bf16x8*)&Qs[lrow][lcol + 8] = qr1;
    __syncthreads();
    if (lt < 15) {            // prefetch next Q tile under compute
      const bf16* qp = qbase + (long long)((lt + 1) << 6) * HD;
      qr0 = *(const bf16x8*)qp;
      qr1 = *(const bf16x8*)(qp + 8);
    }
    f32x4 s00 = zero, s01 = zero, s10 = zero, s11 = zero;
#pragma unroll
    for (int kh = 0; kh < 2; ++kh) {
      bf16x8 a0 = *(bf16x8*)&Qs[wm + m16][(kh << 5) + (quad << 3)];
      bf16x8 a1 = *(bf16x8*)&Qs[wm + 16 + m16][(kh << 5) + (quad << 3)];
      s00 = MFMA(a0, bk[0][kh], s00);
      s01 = MFMA(a0, bk[1][kh], s01);
      s10 = MFMA(a1, bk[0][kh], s10);
      s11 = MFMA(a1, bk[1][kh], s11);
    }
    f32x4 sacc[2][2] = {{s00, s01}, {s10, s11}};
#pragma unroll
    for (int mi = 0; mi < 2; ++mi)
#pragma unroll
      for (int ni = 0; ni < 2; ++ni)
#pragma unroll
        for (int r = 0; r < 4; ++r)
          colp[ni] += __expf(sacc[mi][ni][r]);
    __syncthreads();
  }
  for (int ni = 0; ni < 2; ++ni) {
    float v = colp[ni];
    v += __shfl_down(v, 32, 64);
    v += __shfl_down(v, 16, 64);
    if (quad == 0) cpart[wn + (ni << 4) + m16][wm >> 5] = v;
  }
  __syncthreads();
  if (t < 64) csum[b * SK + st0 + t] = cpart[t][0] + cpart[t][1];
}

// ================= Vsum[b][d] = sum_s Vt[b][d][s] ================================
__global__ __launch_bounds__(256) void vsum_kernel(
    const bf16* __restrict__ Vt, float* __restrict__ Vsum)
{
  int wid = blockIdx.x * 4 + (threadIdx.x >> 6);
  int lane = threadIdx.x & 63;
  const bf16* p = Vt + (long long)wid * SK + lane * 16;
  float s = 0.f;
  bf16x8 v0 = *(const bf16x8*)p;
  bf16x8 v1 = *(const bf16x8*)(p + 8);
#pragma unroll
  for (int j = 0; j < 8; ++j) s += bf2f(v0[j]) + bf2f(v1[j]);
  for (int off = 32; off; off >>= 1) s += __shfl_down(s, off, 64);
  if (lane == 0) Vsum[wid] = s;
}

// ================= fused flash: mem branch + slot attn + gate combine ============
// Swapped QK^T (MFMA(K,Q) -> rows=s, cols=l), packed 8B P writes, XOR swizzle.
// Runs the 4-tile mem-KV flash first, then the 16-tile main flash, then combines
// with the sigmoid head gate in f32 and writes ONE bf16 buffer (comb).
__global__ __launch_bounds__(256) void attn_fused(
    const bf16* __restrict__ Qh, const bf16* __restrict__ Kh,
    const bf16* __restrict__ Vt, const bf16* __restrict__ km,
    const bf16* __restrict__ vmt, const float* __restrict__ csum,
    const float* __restrict__ Vsum, const int* __restrict__ mask,
    const float* __restrict__ gate, bf16* __restrict__ comb)
{
  __shared__ __align__(16) __bf16 Ks[64][72];
  __shared__ __align__(16) __bf16 Vs[64][72];
  __shared__ __align__(16) __bf16 Ps[4096];   // [64][64] swizzled
  __shared__ __align__(16) float rcs[SK];
  __shared__ __align__(16) float mskf[MMEM];
  __shared__ float rpa[64][2];
  __shared__ float rpm[64][2];
  const int bid = blockIdx.y * gridDim.x + blockIdx.x;   // 0..1023
  const int xcd = bid & 7, sub = bid >> 3;               // sub in [0,128)
  const int b = (xcd << 3) + (sub >> 4);                 // 0..63
  const int tm0 = (sub & 15) << 6;
  const int n = b >> 3, h = b & 7;
  const int t = threadIdx.x;
  const int lrow = t >> 2, lcol = (t & 3) << 4;
  const int wave = t >> 6, lane = t & 63;
  const int wm = (wave & 1) << 5, wn = (wave >> 1) << 5;
  const int m16 = lane & 15, quad = lane >> 4;
  const int swz = (m16 & 7) << 4;

#pragma unroll
  for (int i = 0; i < 4; ++i)
    rcs[t + i * 256] = 1.f / csum[b * SK + t + i * 256];
  mskf[t] = mask[n * MMEM + t] ? 0.f : 1.f;
  {
    const bf16* qp = Qh + ((long long)b * LQ + tm0 + lrow) * HD + lcol;
    *(bf16x8*)&Ks[lrow][lcol] = *(const bf16x8*)qp;
    *(bf16x8*)&Ks[lrow][lcol + 8] = *(const bf16x8*)(qp + 8);
  }
  __syncthreads();
  bf16x8 aq[2][2];
#pragma unroll
  for (int li = 0; li < 2; ++li)
#pragma unroll
    for (int kh = 0; kh < 2; ++kh)
      aq[li][kh] = *(bf16x8*)&Ks[wm + (li << 4) + m16][(kh << 5) + (quad << 3)];
  __syncthreads();

  const f32x4 zero = {0.f, 0.f, 0.f, 0.f};
  // ---------------- mem branch (4 tiles of km/vmt) ----------------
  f32x4 m00 = zero, m01 = zero, m10 = zero, m11 = zero;
  float rsm[2] = {0.f, 0.f};
  {
    const bf16* kbase = km + ((long long)b * MMEM + lrow) * HD + lcol;
    const bf16* vbase = vmt + ((long long)b * HD + lrow) * MMEM + lcol;
    bf16x8 kr0 = *(const bf16x8*)kbase;
    bf16x8 kr1 = *(const bf16x8*)(kbase + 8);
    bf16x8 vr0 = *(const bf16x8*)vbase;
    bf16x8 vr1 = *(const bf16x8*)(vbase + 8);
    for (int mt = 0; mt < 4; ++mt) {
      *(bf16x8*)&Ks[lrow][lcol] = kr0;
      *(bf16x8*)&Ks[lrow][lcol + 8] = kr1;
      *(bf16x8*)&Vs[lrow][lcol] = vr0;
      *(bf16x8*)&Vs[lrow][lcol + 8] = vr1;
      __syncthreads();
      if (mt < 3) {
        const bf16* kp = kbase + (long long)((mt + 1) << 6) * HD;
        const bf16* vp = vbase + ((mt + 1) << 6);
        kr0 = *(const bf16x8*)kp;
        kr1 = *(const bf16x8*)(kp + 8);
        vr0 = *(const bf16x8*)vp;
        vr1 = *(const bf16x8*)(vp + 8);
      }
      f32x4 s00 = zero, s01 = zero, s10 = zero, s11 = zero;
      __builtin_amdgcn_s_setprio(1);
#pragma unroll
      for (int kh = 0; kh < 2; ++kh) {
        bf16x8 ak0 = *(bf16x8*)&Ks[wn + m16][(kh << 5) + (quad << 3)];
        bf16x8 ak1 = *(bf16x8*)&Ks[wn + 16 + m16][(kh << 5) + (quad << 3)];
        s00 = MFMA(ak0, aq[0][kh], s00);
        s01 = MFMA(ak0, aq[1][kh], s01);
        s10 = MFMA(ak1, aq[0][kh], s10);
        s11 = MFMA(ak1, aq[1][kh], s11);
      }
      __builtin_amdgcn_s_setprio(0);
      {
        char* pA = (char*)Ps + (wm + m16) * 128;
        char* pB = (char*)Ps + (wm + 16 + m16) * 128;
#pragma unroll
        for (int si = 0; si < 2; ++si) {
          int sloc = wn + (si << 4) + (quad << 2);
          f32x4 mf4 = *(const f32x4*)&mskf[(mt << 6) + sloc];
          f32x4 sA = si ? s10 : s00;
          f32x4 sB = si ? s11 : s01;
          __bf16 vA[4], vB[4];
#pragma unroll
          for (int r = 0; r < 4; ++r) {
            float pa = __expf(sA[r]) * mf4[r];
            rsm[0] += pa; vA[r] = tobf(pa);
            float pb = __expf(sB[r]) * mf4[r];
            rsm[1] += pb; vB[r] = tobf(pb);
          }
          int sbyte = (sloc << 1) ^ swz;
          *(uint2*)(pA + sbyte) = *(uint2*)vA;
          *(uint2*)(pB + sbyte) = *(uint2*)vB;
        }
      }
      __syncthreads();
      __builtin_amdgcn_s_setprio(1);
#pragma unroll
      for (int kh = 0; kh < 2; ++kh) {
        int sb = (kh << 6) + (quad << 4);
        bf16x8 ap0 = *(bf16x8*)((char*)Ps + (wm + m16) * 128 + (sb ^ swz));
        bf16x8 ap1 = *(bf16x8*)((char*)Ps + (wm + 16 + m16) * 128 + (sb ^ swz));
        bf16x8 bv0 = *(bf16x8*)&Vs[wn + m16][(kh << 5) + (quad << 3)];
        bf16x8 bv1 = *(bf16x8*)&Vs[wn + 16 + m16][(kh << 5) + (quad << 3)];
        m00 = MFMA(ap0, bv0, m00);
        m01 = MFMA(ap0, bv1, m01);
        m10 = MFMA(ap1, bv0, m10);
        m11 = MFMA(ap1, bv1, m11);
      }
      __builtin_amdgcn_s_setprio(0);
      __syncthreads();
    }
  }

  // ---------------- main branch (16 tiles of Kh/Vt) ----------------
  f32x4 o00 = zero, o01 = zero, o10 = zero, o11 = zero;
  float rsa[2] = {0.f, 0.f};
  {
    const bf16* kbase = Kh + ((long long)b * SK + lrow) * HD + lcol;
    const bf16* vbase = Vt + ((long long)b * HD + lrow) * SK + lcol;
    bf16x8 kr0 = *(const bf16x8*)kbase;
    bf16x8 kr1 = *(const bf16x8*)(kbase + 8);
    bf16x8 vr0 = *(const bf16x8*)vbase;
    bf16x8 vr1 = *(const bf16x8*)(vbase + 8);
    for (int st = 0; st < 16; ++st) {
      *(bf16x8*)&Ks[lrow][lcol] = kr0;
      *(bf16x8*)&Ks[lrow][lcol + 8] = kr1;
      *(bf16x8*)&Vs[lrow][lcol] = vr0;
      *(bf16x8*)&Vs[lrow][lcol + 8] = vr1;
      __syncthreads();
      if (st < 15) {
        const bf16* kp = kbase + (long long)((st + 1) << 6) * HD;
        const bf16* vp = vbase + ((st + 1) << 6);
        kr0 = *(const bf16x8*)kp;
        kr1 = *(const bf16x8*)(kp + 8);
        vr0 = *(const bf16x8*)vp;
        vr1 = *(const bf16x8*)(vp + 8);
      }
      f32x4 s00 = zero, s01 = zero, s10 = zero, s11 = zero;
      __builtin_amdgcn_s_setprio(1);
#pragma unroll
      for (int kh = 0; kh < 2; ++kh) {
        bf16x8 ak0 = *(bf16x8*)&Ks[wn + m16][(kh << 5) + (quad << 3)];
        bf16x8 ak1 = *(bf16x8*)&Ks[wn + 16 + m16][(kh << 5) + (quad << 3)];
        s00 = MFMA(ak0, aq[0][kh], s00);
        s01 = MFMA(ak0, aq[1][kh], s01);
        s10 = MFMA(ak1, aq[0][kh], s10);
        s11 = MFMA(ak1, aq[1][kh], s11);
      }
      __builtin_amdgcn_s_setprio(0);
      {
        char* pA = (char*)Ps + (wm + m16) * 128;
        char* pB = (char*)Ps + (wm + 16 + m16) * 128;
#pragma unroll
        for (int si = 0; si < 2; ++si) {
          int sloc = wn + (si << 4) + (quad << 2);
          f32x4 rc4 = *(const f32x4*)&rcs[(st << 6) + sloc];
          f32x4 sA = si ? s10 : s00;
          f32x4 sB = si ? s11 : s01;
          __bf16 vA[4], vB[4];
#pragma unroll
          for (int r = 0; r < 4; ++r) {
            float pa = __expf(sA[r]) * rc4[r];
            rsa[0] += pa; vA[r] = tobf(pa);
            float pb = __expf(sB[r]) * rc4[r];
            rsa[1] += pb; vB[r] = tobf(pb);
          }
          int sbyte = (sloc << 1) ^ swz;
          *(uint2*)(pA + sbyte) = *(uint2*)vA;
          *(uint2*)(pB + sbyte) = *(uint2*)vB;
        }
      }
      __syncthreads();
      __builtin_amdgcn_s_setprio(1);
#pragma unroll
      for (int kh = 0; kh < 2; ++kh) {
        int sb = (kh << 6) + (quad << 4);
        bf16x8 ap0 = *(bf16x8*)((char*)Ps + (wm + m16) * 128 + (sb ^ swz));
        bf16x8 ap1 = *(bf16x8*)((char*)Ps + (wm + 16 + m16) * 128 + (sb ^ swz));
        bf16x8 bv0 = *(bf16x8*)&Vs[wn + m16][(kh << 5) + (quad << 3)];
        bf16x8 bv1 = *(bf16x8*)&Vs[wn + 16 + m16][(kh << 5) + (quad << 3)];
        o00 = MFMA(ap0, bv0, o00);
        o01 = MFMA(ap0, bv1, o01);
        o10 = MFMA(ap1, bv0, o10);
        o11 = MFMA(ap1, bv1, o11);
      }
      __builtin_amdgcn_s_setprio(0);
      __syncthreads();
    }
  }

  // ---------------- reductions (both branches) ----------------
#pragma unroll
  for (int li = 0; li < 2; ++li) {
    float va = rsa[li];
    va += __shfl_xor(va, 16, 64);
    va += __shfl_xor(va, 32, 64);
    float vm = rsm[li];
    vm += __shfl_xor(vm, 16, 64);
    vm += __shfl_xor(vm, 32, 64);
    if (quad == 0) {
      rpa[wm + (li << 4) + m16][wn >> 5] = va;
      rpm[wm + (li << 4) + m16][wn >> 5] = vm;
    }
  }
  __syncthreads();

  // ---------------- gate combine in f32, single bf16 write ----------------
  const float* vs = Vsum + b * HD;
  const float g = 1.f / (1.f + __expf(-gate[h]));
  f32x4 oacc[2][2] = {{o00, o01}, {o10, o11}};
  f32x4 macc[2][2] = {{m00, m01}, {m10, m11}};
  for (int mi = 0; mi < 2; ++mi)
    for (int ni = 0; ni < 2; ++ni) {
      int col = wn + (ni << 4) + m16;
      float vsc = 1e-8f * vs[col];
      for (int r = 0; r < 4; ++r) {
        int row = wm + (mi << 4) + (quad << 2) + r;
        float ra = rpa[row][0] + rpa[row][1];
        float rm = rpm[row][0] + rpm[row][1];
        float oa = (oacc[mi][ni][r] + vsc) / (ra + (float)SK * 1e-8f);
        float om = macc[mi][ni][r] / rm;
        Ks[row][col] = tobf(g * om + (1.f - g) * oa);
      }
    }
  __syncthreads();
  uint4 u0 = *(uint4*)&Ks[lrow][lcol];
  uint4 u1 = *(uint4*)&Ks[lrow][lcol + 8];
  long long gb = ((long long)b * LQ + tm0 + lrow) * HD + lcol;
  *(uint4*)(comb + gb) = u0;
  *(uint4*)(comb + gb + 8) = u1;
}

// ================= out proj, m97-structure (A = fused comb buffer) ===============
// 128x128 tile, BK=64 (one head per K-step: h = k0>>6 fixed), gload_lds staging.
__global__ __launch_bounds__(256) void gemm_out(
    const bf16* __restrict__ comb, const bf16* __restrict__ opwb,
    const float* __restrict__ opb, float* __restrict__ out)
{
  __shared__ __align__(16) char smem[32768];
  __bf16* As = (__bf16*)smem;             // [128][64] linear
  __bf16* Bs = (__bf16*)(smem + 16384);   // [128][64] linear
  const int bid2 = blockIdx.y * gridDim.x + blockIdx.x;  // 0..255
  const int xcd = bid2 & 7, sub = bid2 >> 3;             // sub in [0,32)
  const int by = (xcd << 3) + (sub >> 2);                // 0..63
  const int bx = sub & 3;                                // 0..3
  const int tm0 = by << 7, tn0 = bx << 7;
  const int t = threadIdx.x;
  const int wave = t >> 6, lane = t & 63;
  const int wrow0 = (wave & 1) << 6, wcol0 = (wave >> 1) << 6;
  const int m16 = lane & 15, quad = lane >> 4;

  const f32x4 zero = {0.f, 0.f, 0.f, 0.f};
  f32x4 acc[4][4];
#pragma unroll
  for (int mi = 0; mi < 4; ++mi)
#pragma unroll
    for (int ni = 0; ni < 4; ++ni) acc[mi][ni] = zero;

  const bf16* Bb = opwb + (long long)tn0 * EE;
  const int ob_u = wave << 10;

  for (int k0 = 0; k0 < EE; k0 += 64) {
    const int h = k0 >> 6;
#pragma unroll
    for (int c = 0; c < 4; ++c) {
      int ob = (c << 12) + ob_u;
      int obl = ob + (lane << 4);
      int row = obl >> 7;
      int ce = (obl & 127) >> 1;
      int arow = tm0 + row;
      int l = arow >> 3, nn = arow & 7;
      gload_lds16(comb + (((long long)(nn * NH + h) * LQ + l) * HD + ce),
                  smem + ob);
      gload_lds16(Bb + (long long)row * EE + k0 + ce, smem + 16384 + ob);
    }
    __syncthreads();
#pragma unroll
    for (int kh = 0; kh < 2; ++kh) {
      bf16x8 av[4], bv[4];
#pragma unroll
      for (int i = 0; i < 4; ++i) {
        av[i] = *(bf16x8*)(As + ((wrow0 + (i << 4) + m16) << 6) + (kh << 5) + (quad << 3));
        bv[i] = *(bf16x8*)(Bs + ((wcol0 + (i << 4) + m16) << 6) + (kh << 5) + (quad << 3));
      }
#pragma unroll
      for (int mi = 0; mi < 4; ++mi)
#pragma unroll
        for (int ni = 0; ni < 4; ++ni)
          acc[mi][ni] = MFMA(av[mi], bv[ni], acc[mi][ni]);
    }
    __syncthreads();
  }

  // direct f32 epilogue (16-lane-contiguous 64B segments)
#pragma unroll
  for (int mi = 0; mi < 4; ++mi)
#pragma unroll
    for (int ni = 0; ni < 4; ++ni) {
      int col = tn0 + wcol0 + (ni << 4) + m16;
      float bv = opb[col];
      int row0 = tm0 + wrow0 + (mi << 4) + (quad << 2);
#pragma unroll
      for (int r = 0; r < 4; ++r)
        out[(long long)(row0 + r) * EE + col] = acc[mi][ni][r] + bv;
    }
}

// ================= LDS-tiled transposes (no 2B-granular scatter) =================
__global__ __launch_bounds__(256) void v_transpose(
    const bf16* __restrict__ raw, bf16* __restrict__ Vt)
{
  __shared__ __align__(16) __bf16 Ts[64][72];
  const int bh = blockIdx.y;             // n*NH + h
  const int n = bh >> 3, h = bh & 7;
  const int s0 = blockIdx.x << 6;
  const int t = threadIdx.x;
  const int i = t >> 2, c0 = (t & 3) << 4;
  const bf16* rp = raw + ((long long)(s0 + i) * NB + n) * EE + h * HD + c0;
  *(bf16x8*)&Ts[i][c0] = *(const bf16x8*)rp;
  *(bf16x8*)&Ts[i][c0 + 8] = *(const bf16x8*)(rp + 8);
  __syncthreads();
  const int d = t >> 2, j0 = (t & 3) << 4;
  __bf16 vals[16];
#pragma unroll
  for (int j = 0; j < 16; ++j) vals[j] = Ts[j0 + j][d];
  bf16* wp = Vt + ((long long)bh * HD + d) * SK + s0 + j0;
  *(uint4*)wp = *(uint4*)&vals[0];
  *(uint4*)(wp + 8) = *(uint4*)&vals[8];
}

__global__ __launch_bounds__(256) void mem_prep(
    const float* __restrict__ k_mem, const float* __restrict__ v_mem,
    bf16* __restrict__ km, bf16* __restrict__ vmt)
{
  __shared__ __align__(16) __bf16 Ts[64][72];
  const int bh = blockIdx.y;             // n*NH + h
  const int n = bh >> 3, h = bh & 7;
  const int m0 = blockIdx.x << 6;
  const int t = threadIdx.x;
  const int i = t >> 2, c0 = (t & 3) << 4;
  const float* kp = k_mem + ((long long)(m0 + i) * NB + n) * EE + h * HD + c0;
  const float* vp = v_mem + ((long long)(m0 + i) * NB + n) * EE + h * HD + c0;
  bf16x8 kv0 = load8(kp), kv1 = load8(kp + 8);
  bf16x8 vv0 = load8(vp), vv1 = load8(vp + 8);
  bf16* kw = km + ((long long)bh * MMEM + m0 + i) * HD + c0;
  *(bf16x8*)kw = kv0;
  *(bf16x8*)(kw + 8) = kv1;
  *(bf16x8*)&Ts[i][c0] = vv0;
  *(bf16x8*)&Ts[i][c0 + 8] = vv1;
  __syncthreads();
  const int d = t >> 2, j0 = (t & 3) << 4;
  __bf16 vals[16];
#pragma unroll
  for (int j = 0; j < 16; ++j) vals[j] = Ts[j0 + j][d];
  bf16* wp = vmt + ((long long)bh * HD + d) * MMEM + m0 + j0;
  *(uint4*)wp = *(uint4*)&vals[0];
  *(uint4*)(wp + 8) = *(uint4*)&vals[8];
}

extern "C" void kernel_launch(void* const* d_in, const int* in_sizes, int n_in,
                              void* d_out, int out_size, void* d_ws, size_t ws_size,
                              hipStream_t stream) {
  const float* query = (const float*)d_in[0];
  const float* key   = (const float*)d_in[1];
  const float* value = (const float*)d_in[2];
  const float* ipw   = (const float*)d_in[3];
  const float* ipb   = (const float*)d_in[4];
  const float* opw   = (const float*)d_in[5];
  const float* opb   = (const float*)d_in[6];
  const float* rot_q = (const float*)d_in[7];
  const float* rot_k = (const float*)d_in[8];
  const float* k_mem = (const float*)d_in[9];
  const float* v_mem = (const float*)d_in[10];
  const float* gate  = (const float*)d_in[11];
  const int*  mask   = (const int*)d_in[12];
  float* out = (float*)d_out;

  char* w = (char*)d_ws;
  size_t off = 0;
  auto carve = [&](size_t bytes) -> char* {
    char* p = w + off;
    off += (bytes + 255) & ~(size_t)255;
    return p;
  };
  bf16* qc    = (bf16*)carve((size_t)LQ * NB * EE * 2);
  bf16* kc    = (bf16*)carve((size_t)SK * NB * EE * 2);
  bf16* vc    = (bf16*)carve((size_t)SK * NB * EE * 2);
  bf16* ipwb  = (bf16*)carve((size_t)3 * EE * EE * 2);
  bf16* opwb  = (bf16*)carve((size_t)EE * EE * 2);
  bf16* v_raw = (bf16*)carve((size_t)SK * NB * EE * 2);
  bf16* Qh    = (bf16*)carve((size_t)NBH * LQ * HD * 2);
  bf16* Kh    = (bf16*)carve((size_t)NBH * SK * HD * 2);
  bf16* Vt    = (bf16*)carve((size_t)NBH * HD * SK * 2);
  bf16* km    = (bf16*)carve((size_t)NBH * MMEM * HD * 2);
  bf16* vmt   = (bf16*)carve((size_t)NBH * HD * MMEM * 2);
  float* csum = (float*)carve((size_t)NBH * SK * 4);
  float* Vsum = (float*)carve((size_t)NBH * HD * 4);
  bf16* comb  = (bf16*)carve((size_t)NBH * LQ * HD * 2);
  bf16* pkbuf = (bf16*)carve((size_t)NBH * LQ * HD * 2);
  if (off > ws_size) {
    hipMemsetAsync(d_out, 0, (size_t)out_size * 4, stream);
    return;
  }
  // pq aliases comb: comb is only written by attn_fused, well after rotary
  // consumed pq. pkbuf is rotary's K staging.
  bf16* pq = comb;
  bf16* pk = pkbuf;

  // 0) pre-convert GEMM inputs to bf16
  convert5<<<(3 * CVT_T0 + CVT_T3 + CVT_T4) / 256, 256, 0, stream>>>(
      query, key, value, ipw, opw, qc, kc, vc, ipwb, opwb);

  // 1) q/k/v projections, pure GEMM (128x128 m97 structure, XCD-swizzled)
  gemm_proj3<<<dim3(EE / 128, (LQ * NB) / 128, 3), 256, 0, stream>>>(
      qc, kc, vc, ipwb, ipb, pq, pk, v_raw);

  // 1b) rotary + head reshape as a pure streaming kernel
  rotary_kernel<<<dim3((LQ * NB) / 4, 2), 256, 0, stream>>>(
      pq, pk, rot_q, rot_k, Qh, Kh);

  // 2) v transpose (LDS-tiled) + Vsum; mem k/v repack (LDS-tiled)
  v_transpose<<<dim3(SK / 64, NBH), 256, 0, stream>>>(v_raw, Vt);
  vsum_kernel<<<(NBH * HD) / 4, 256, 0, stream>>>(Vt, Vsum);
  mem_prep<<<dim3(MMEM / 64, NBH), 256, 0, stream>>>(k_mem, v_mem, km, vmt);

  // 3) column sums of exp(scores) (XCD-swizzled)
  colsum_kernel<<<dim3(SK / 64, NBH), 256, 0, stream>>>(Qh, Kh, csum);

  // 4) fused flash (mem branch + slot attn + gate combine, XCD-swizzled)
  attn_fused<<<dim3(LQ / 64, NBH), 256, 0, stream>>>(
      Qh, Kh, Vt, km, vmt, csum, Vsum, mask, gate, comb);

  // 5) out-proj, m97 structure, single A buffer
  gemm_out<<<dim3(4, 64), 256, 0, stream>>>(comb, opwb, opb, out);
}

// Round 6
// 301.251 us; speedup vs baseline: 1.1776x; 1.0122x over previous
//
#include <hip/hip_runtime.h>
#include <hip/hip_bf16.h>

typedef __hip_bfloat16 bf16;
typedef __bf16 bf16x8 __attribute__((ext_vector_type(8)));
typedef float f32x4 __attribute__((ext_vector_type(4)));

#define LQ 1024
#define SK 1024
#define MMEM 256
#define NB 8
#define EE 512
#define NH 8
#define HD 64
#define NBH 64  // NB*NH batched (n,h) pairs

__device__ inline __bf16 tobf(float f) {
  __hip_bfloat16 h = __float2bfloat16(f);
  return *reinterpret_cast<__bf16*>(&h);
}
__device__ inline float bf2f(__bf16 x) {
  unsigned short u; __builtin_memcpy(&u, &x, 2);
  unsigned int v = (unsigned int)u << 16;
  float f; __builtin_memcpy(&f, &v, 4);
  return f;
}
__device__ inline f32x4 MFMA(bf16x8 a, bf16x8 b, f32x4 c) {
  return __builtin_amdgcn_mfma_f32_16x16x32_bf16(a, b, c, 0, 0, 0);
}

// async global->LDS, 16B per lane. LDS dest is wave-uniform base + lane*16.
__device__ inline void gload_lds16(const bf16* g, void* l) {
  __builtin_amdgcn_global_load_lds(
      (const __attribute__((address_space(1))) void*)g,
      (__attribute__((address_space(3))) void*)l, 16, 0, 0);
}

__device__ inline bf16x8 load8(const float* p) {
  float4 a = *(const float4*)p;
  float4 b = *(const float4*)(p + 4);
  bf16x8 r;
  r[0] = tobf(a.x); r[1] = tobf(a.y); r[2] = tobf(a.z); r[3] = tobf(a.w);
  r[4] = tobf(b.x); r[5] = tobf(b.y); r[6] = tobf(b.z); r[7] = tobf(b.w);
  return r;
}

// ================= bf16 pre-conversion of GEMM inputs ============================
#define CVT_T0 524288   // threads per q/k/v region (8 elems each)
#define CVT_T3 98304    // ipw
#define CVT_T4 32768    // opw
__global__ __launch_bounds__(256) void convert5(
    const float* __restrict__ q, const float* __restrict__ k,
    const float* __restrict__ v, const float* __restrict__ w,
    const float* __restrict__ o, bf16* __restrict__ qc, bf16* __restrict__ kc,
    bf16* __restrict__ vc, bf16* __restrict__ wc, bf16* __restrict__ oc)
{
  long long t = (long long)blockIdx.x * 256 + threadIdx.x;
  const float* src; bf16* dst; long long idx;
  if (t < CVT_T0)               { src = q; dst = qc; idx = t; }
  else if (t < 2 * CVT_T0)      { src = k; dst = kc; idx = t - CVT_T0; }
  else if (t < 3 * CVT_T0)      { src = v; dst = vc; idx = t - 2 * CVT_T0; }
  else if (t < 3 * CVT_T0 + CVT_T3) { src = w; dst = wc; idx = t - 3 * CVT_T0; }
  else                          { src = o; dst = oc; idx = t - 3 * CVT_T0 - CVT_T3; }
  *(bf16x8*)(dst + idx * 8) = load8(src + idx * 8);
}

// ================= 3-in-1 projection GEMM, m97-structure, PURE GEMM ==============
__global__ __launch_bounds__(256) void gemm_proj3(
    const bf16* __restrict__ qc, const bf16* __restrict__ kc,
    const bf16* __restrict__ vc, const bf16* __restrict__ ipwb,
    const float* __restrict__ ipb, bf16* __restrict__ pq,
    bf16* __restrict__ pk, bf16* __restrict__ v_raw)
{
  __shared__ __align__(16) char smem[33792];
  __bf16* As = (__bf16*)smem;             // [128][64] linear, 16384 B
  __bf16* Bs = (__bf16*)(smem + 16384);   // [128][64] linear, 16384 B
  const int z = blockIdx.z;
  const bf16* A = (z == 0) ? qc : (z == 1) ? kc : vc;
  const bf16* W = ipwb + (long long)z * EE * EE;
  const float* bias = ipb + z * EE;
  const float alpha = (z == 0) ? 0.125f : 1.f;
  // XCD-aware remap (bijective): bid2 in [0,256) per z
  const int bid2 = blockIdx.y * gridDim.x + blockIdx.x;
  const int xcd = bid2 & 7, sub = bid2 >> 3;       // sub in [0,32)
  const int by = (xcd << 3) + (sub >> 2);          // 0..63
  const int bx = sub & 3;                          // 0..3
  const int tm0 = by << 7, tn0 = bx << 7;          // 128 x 128
  const int t = threadIdx.x;
  const int wave = t >> 6, lane = t & 63;
  const int wrow0 = (wave & 1) << 6, wcol0 = (wave >> 1) << 6;
  const int m16 = lane & 15, quad = lane >> 4;

  const f32x4 zero = {0.f, 0.f, 0.f, 0.f};
  f32x4 acc[4][4];
#pragma unroll
  for (int mi = 0; mi < 4; ++mi)
#pragma unroll
    for (int ni = 0; ni < 4; ++ni) acc[mi][ni] = zero;

  const bf16* Ab = A + (long long)tm0 * EE;
  const bf16* Bb = W + (long long)tn0 * EE;
  const int ob_u = wave << 10;  // wave-uniform byte base within 4KB chunk

  for (int k0 = 0; k0 < EE; k0 += 64) {
#pragma unroll
    for (int c = 0; c < 4; ++c) {
      int ob = (c << 12) + ob_u;          // uniform LDS byte base
      int obl = ob + (lane << 4);         // this lane's slot
      int row = obl >> 7;                 // tile row (stride 128 B)
      int ce = (obl & 127) >> 1;          // element within row
      gload_lds16(Ab + (long long)row * EE + k0 + ce, smem + ob);
      gload_lds16(Bb + (long long)row * EE + k0 + ce, smem + 16384 + ob);
    }
    __syncthreads();
#pragma unroll
    for (int kh = 0; kh < 2; ++kh) {
      bf16x8 av[4], bv[4];
#pragma unroll
      for (int i = 0; i < 4; ++i) {
        av[i] = *(bf16x8*)(As + ((wrow0 + (i << 4) + m16) << 6) + (kh << 5) + (quad << 3));
        bv[i] = *(bf16x8*)(Bs + ((wcol0 + (i << 4) + m16) << 6) + (kh << 5) + (quad << 3));
      }
#pragma unroll
      for (int mi = 0; mi < 4; ++mi)
#pragma unroll
        for (int ni = 0; ni < 4; ++ni)
          acc[mi][ni] = MFMA(av[mi], bv[ni], acc[mi][ni]);
    }
    __syncthreads();
  }

  // ---- epilogue: stage C in LDS (bias+scale), then 128B-contiguous stores ----
  __bf16 (*Cs)[132] = (__bf16(*)[132])smem;
#pragma unroll
  for (int mi = 0; mi < 4; ++mi)
#pragma unroll
    for (int ni = 0; ni < 4; ++ni) {
      int col = wcol0 + (ni << 4) + m16;
      float bv = bias[tn0 + col];
#pragma unroll
      for (int r = 0; r < 4; ++r)
        Cs[wrow0 + (mi << 4) + (quad << 2) + r][col] =
            tobf((acc[mi][ni][r] + bv) * alpha);
    }
  __syncthreads();
  bf16* O = (z == 0) ? pq : (z == 1) ? pk : v_raw;
  const int crow = t >> 1, ch0 = (t & 1) << 6;   // 2 threads/row, 64 cols each
  long long gb = (long long)(tm0 + crow) * EE + tn0 + ch0;
#pragma unroll
  for (int j = 0; j < 64; j += 8)
    *(uint4*)(O + gb + j) = *(uint4*)&Cs[crow][ch0 + j];
}

// ================= rotary + head-reshape, pure streaming =========================
__global__ __launch_bounds__(256) void rotary_kernel(
    const bf16* __restrict__ pq, const bf16* __restrict__ pk,
    const float* __restrict__ rot_q, const float* __restrict__ rot_k,
    bf16* __restrict__ Qh, bf16* __restrict__ Kh)
{
  const bf16* src = blockIdx.y ? pk : pq;
  const float* rot = blockIdx.y ? rot_k : rot_q;
  bf16* dst = blockIdx.y ? Kh : Qh;
  const int t = threadIdx.x;
  const int row = (blockIdx.x << 2) + (t >> 6);   // l*NB + n
  const int e0 = (t & 63) << 3;                   // 8 elems per lane
  const int l = row >> 3, n = row & 7;
  bf16x8 x = *(const bf16x8*)(src + (long long)row * EE + e0);
  const float* rp = rot + ((((long long)n * LQ + l) * EE + e0) << 1);
  __bf16 vals[8];
#pragma unroll
  for (int j = 0; j < 8; j += 2) {
    float4 cs4 = *(const float4*)(rp + (j << 1));  // c0,s0,c1,s1
    float x0 = bf2f(x[j]);
    float x1 = bf2f(x[j + 1]);
    vals[j]     = tobf(x0 * cs4.x - x1 * cs4.y);
    vals[j + 1] = tobf(x1 * cs4.z + x0 * cs4.w);
  }
  const int h = e0 >> 6, d0 = e0 & 63;
  *(uint4*)(dst + (((long long)(n * NH + h) * LQ + l) * HD + d0)) = *(uint4*)vals;
}

// ================= colsum: csum[b][s] = sum_l exp(Q[l]·K[s]) ====================
// Q double-buffered in LDS -> ONE barrier per iteration (no cross-wave P dep).
__global__ __launch_bounds__(256) void colsum_kernel(
    const bf16* __restrict__ Qh, const bf16* __restrict__ Kh,
    float* __restrict__ csum)
{
  __shared__ __align__(16) __bf16 Ks[64][72];
  __shared__ __align__(16) __bf16 Qd[2][64][72];
  __shared__ float cpart[64][2];
  const int bid = blockIdx.y * gridDim.x + blockIdx.x;   // 0..1023
  const int xcd = bid & 7, sub = bid >> 3;               // sub in [0,128)
  const int b = (xcd << 3) + (sub >> 4);                 // 0..63
  const int st0 = (sub & 15) << 6;
  const int t = threadIdx.x;
  const int lrow = t >> 2, lcol = (t & 3) << 4;
  const int wave = t >> 6, lane = t & 63;
  const int wm = (wave & 1) << 5, wn = (wave >> 1) << 5;
  const int m16 = lane & 15, quad = lane >> 4;

  const bf16* qbase = Qh + ((long long)b * LQ + lrow) * HD + lcol;
  {
    const bf16* kp = Kh + ((long long)b * SK + st0 + lrow) * HD + lcol;
    *(bf16x8*)&Ks[lrow][lcol] = *(const bf16x8*)kp;
    *(bf16x8*)&Ks[lrow][lcol + 8] = *(const bf16x8*)(kp + 8);
    *(bf16x8*)&Qd[0][lrow][lcol] = *(const bf16x8*)qbase;
    *(bf16x8*)&Qd[0][lrow][lcol + 8] = *(const bf16x8*)(qbase + 8);
  }
  __syncthreads();
  bf16x8 bk[2][2];   // [ni][kh] -- K tile resident, read once
#pragma unroll
  for (int ni = 0; ni < 2; ++ni)
#pragma unroll
    for (int kh = 0; kh < 2; ++kh)
      bk[ni][kh] = *(bf16x8*)&Ks[wn + (ni << 4) + m16][(kh << 5) + (quad << 3)];

  const f32x4 zero = {0.f, 0.f, 0.f, 0.f};
  float colp[2] = {0.f, 0.f};
  int cur = 0;
  for (int lt = 0; lt < 16; ++lt) {
    bf16x8 qr0, qr1;
    if (lt < 15) {            // issue next-tile loads; hide under MFMA+exp
      const bf16* qp = qbase + (long long)((lt + 1) << 6) * HD;
      qr0 = *(const bf16x8*)qp;
      qr1 = *(const bf16x8*)(qp + 8);
    }
    f32x4 s00 = zero, s01 = zero, s10 = zero, s11 = zero;
    __builtin_amdgcn_s_setprio(1);
#pragma unroll
    for (int kh = 0; kh < 2; ++kh) {
      bf16x8 a0 = *(bf16x8*)&Qd[cur][wm + m16][(kh << 5) + (quad << 3)];
      bf16x8 a1 = *(bf16x8*)&Qd[cur][wm + 16 + m16][(kh << 5) + (quad << 3)];
      s00 = MFMA(a0, bk[0][kh], s00);
      s01 = MFMA(a0, bk[1][kh], s01);
      s10 = MFMA(a1, bk[0][kh], s10);
      s11 = MFMA(a1, bk[1][kh], s11);
    }
    __builtin_amdgcn_s_setprio(0);
    f32x4 sacc[2][2] = {{s00, s01}, {s10, s11}};
#pragma unroll
    for (int mi = 0; mi < 2; ++mi)
#pragma unroll
      for (int ni = 0; ni < 2; ++ni)
#pragma unroll
        for (int r = 0; r < 4; ++r)
          colp[ni] += __expf(sacc[mi][ni][r]);
    if (lt < 15) {            // stage into the OTHER buffer (no race)
      *(bf16x8*)&Qd[cur ^ 1][lrow][lcol] = qr0;
      *(bf16x8*)&Qd[cur ^ 1][lrow][lcol + 8] = qr1;
    }
    __syncthreads();          // the ONLY barrier in the loop
    cur ^= 1;
  }
  for (int ni = 0; ni < 2; ++ni) {
    float v = colp[ni];
    v += __shfl_down(v, 32, 64);
    v += __shfl_down(v, 16, 64);
    if (quad == 0) cpart[wn + (ni << 4) + m16][wm >> 5] = v;
  }
  __syncthreads();
  if (t < 64) csum[b * SK + st0 + t] = cpart[t][0] + cpart[t][1];
}

// ================= Vsum[b][d] = sum_s Vt[b][d][s] ================================
__global__ __launch_bounds__(256) void vsum_kernel(
    const bf16* __restrict__ Vt, float* __restrict__ Vsum)
{
  int wid = blockIdx.x * 4 + (threadIdx.x >> 6);
  int lane = threadIdx.x & 63;
  const bf16* p = Vt + (long long)wid * SK + lane * 16;
  float s = 0.f;
  bf16x8 v0 = *(const bf16x8*)p;
  bf16x8 v1 = *(const bf16x8*)(p + 8);
#pragma unroll
  for (int j = 0; j < 8; ++j) s += bf2f(v0[j]) + bf2f(v1[j]);
  for (int off = 32; off; off >>= 1) s += __shfl_down(s, off, 64);
  if (lane == 0) Vsum[wid] = s;
}

// ================= fused flash: mem + main + gate combine, K/V double-buffer =====
// Per tile-iteration: issue loads -> QK(buf[cur]) -> exp/P-write -> B2 ->
// ds_write loads into buf[cur^1] -> PV(Ps, Vd[cur]) -> B3.  (2 barriers, not 3;
// global-load latency hides under QK+exp.)
__global__ __launch_bounds__(256) void attn_fused(
    const bf16* __restrict__ Qh, const bf16* __restrict__ Kh,
    const bf16* __restrict__ Vt, const bf16* __restrict__ km,
    const bf16* __restrict__ vmt, const float* __restrict__ csum,
    const float* __restrict__ Vsum, const int* __restrict__ mask,
    const float* __restrict__ gate, bf16* __restrict__ comb)
{
  __shared__ __align__(16) __bf16 Kd[2][64][72];
  __shared__ __align__(16) __bf16 Vd[2][64][72];
  __shared__ __align__(16) __bf16 Ps[4096];   // [64][64] swizzled
  __shared__ __align__(16) float rcs[SK];
  __shared__ __align__(16) float mskf[MMEM];
  __shared__ float rpa[64][2];
  __shared__ float rpm[64][2];
  const int bid = blockIdx.y * gridDim.x + blockIdx.x;   // 0..1023
  const int xcd = bid & 7, sub = bid >> 3;               // sub in [0,128)
  const int b = (xcd << 3) + (sub >> 4);                 // 0..63
  const int tm0 = (sub & 15) << 6;
  const int n = b >> 3, h = b & 7;
  const int t = threadIdx.x;
  const int lrow = t >> 2, lcol = (t & 3) << 4;
  const int wave = t >> 6, lane = t & 63;
  const int wm = (wave & 1) << 5, wn = (wave >> 1) << 5;
  const int m16 = lane & 15, quad = lane >> 4;
  const int swz = (m16 & 7) << 4;

#pragma unroll
  for (int i = 0; i < 4; ++i)
    rcs[t + i * 256] = 1.f / csum[b * SK + t + i * 256];
  mskf[t] = mask[n * MMEM + t] ? 0.f : 1.f;
  {
    const bf16* qp = Qh + ((long long)b * LQ + tm0 + lrow) * HD + lcol;
    *(bf16x8*)&Kd[0][lrow][lcol] = *(const bf16x8*)qp;
    *(bf16x8*)&Kd[0][lrow][lcol + 8] = *(const bf16x8*)(qp + 8);
  }
  __syncthreads();
  bf16x8 aq[2][2];
#pragma unroll
  for (int li = 0; li < 2; ++li)
#pragma unroll
    for (int kh = 0; kh < 2; ++kh)
      aq[li][kh] = *(bf16x8*)&Kd[0][wm + (li << 4) + m16][(kh << 5) + (quad << 3)];

  const bf16* kbase_m = km + ((long long)b * MMEM + lrow) * HD + lcol;
  const bf16* vbase_m = vmt + ((long long)b * HD + lrow) * MMEM + lcol;
  // stage mem tile 0 into buf1 (Kd[0] still being read above -> different buf)
  {
    bf16x8 k0 = *(const bf16x8*)kbase_m;
    bf16x8 k1 = *(const bf16x8*)(kbase_m + 8);
    bf16x8 v0 = *(const bf16x8*)vbase_m;
    bf16x8 v1 = *(const bf16x8*)(vbase_m + 8);
    *(bf16x8*)&Kd[1][lrow][lcol] = k0;
    *(bf16x8*)&Kd[1][lrow][lcol + 8] = k1;
    *(bf16x8*)&Vd[1][lrow][lcol] = v0;
    *(bf16x8*)&Vd[1][lrow][lcol + 8] = v1;
  }
  __syncthreads();

  const f32x4 zero = {0.f, 0.f, 0.f, 0.f};
  // ---------------- mem branch (4 tiles of km/vmt) ----------------
  f32x4 m00 = zero, m01 = zero, m10 = zero, m11 = zero;
  float rsm[2] = {0.f, 0.f};
  int cur = 1;
  for (int mt = 0; mt < 4; ++mt) {
    bf16x8 kr0, kr1, vr0, vr1;
    if (mt < 3) {
      const bf16* kp = kbase_m + (long long)((mt + 1) << 6) * HD;
      const bf16* vp = vbase_m + ((mt + 1) << 6);
      kr0 = *(const bf16x8*)kp;
      kr1 = *(const bf16x8*)(kp + 8);
      vr0 = *(const bf16x8*)vp;
      vr1 = *(const bf16x8*)(vp + 8);
    }
    f32x4 s00 = zero, s01 = zero, s10 = zero, s11 = zero;
    __builtin_amdgcn_s_setprio(1);
#pragma unroll
    for (int kh = 0; kh < 2; ++kh) {
      bf16x8 ak0 = *(bf16x8*)&Kd[cur][wn + m16][(kh << 5) + (quad << 3)];
      bf16x8 ak1 = *(bf16x8*)&Kd[cur][wn + 16 + m16][(kh << 5) + (quad << 3)];
      s00 = MFMA(ak0, aq[0][kh], s00);
      s01 = MFMA(ak0, aq[1][kh], s01);
      s10 = MFMA(ak1, aq[0][kh], s10);
      s11 = MFMA(ak1, aq[1][kh], s11);
    }
    __builtin_amdgcn_s_setprio(0);
    {
      char* pA = (char*)Ps + (wm + m16) * 128;
      char* pB = (char*)Ps + (wm + 16 + m16) * 128;
#pragma unroll
      for (int si = 0; si < 2; ++si) {
        int sloc = wn + (si << 4) + (quad << 2);
        f32x4 mf4 = *(const f32x4*)&mskf[(mt << 6) + sloc];
        f32x4 sA = si ? s10 : s00;
        f32x4 sB = si ? s11 : s01;
        __bf16 vA[4], vB[4];
#pragma unroll
        for (int r = 0; r < 4; ++r) {
          float pa = __expf(sA[r]) * mf4[r];
          rsm[0] += pa; vA[r] = tobf(pa);
          float pb = __expf(sB[r]) * mf4[r];
          rsm[1] += pb; vB[r] = tobf(pb);
        }
        int sbyte = (sloc << 1) ^ swz;
        *(uint2*)(pA + sbyte) = *(uint2*)vA;
        *(uint2*)(pB + sbyte) = *(uint2*)vB;
      }
    }
    __syncthreads();   // B2: P visible; all reads of Kd[cur] (QK) done
    if (mt < 3) {      // stage next tile into the idle buffer
      *(bf16x8*)&Kd[cur ^ 1][lrow][lcol] = kr0;
      *(bf16x8*)&Kd[cur ^ 1][lrow][lcol + 8] = kr1;
      *(bf16x8*)&Vd[cur ^ 1][lrow][lcol] = vr0;
      *(bf16x8*)&Vd[cur ^ 1][lrow][lcol + 8] = vr1;
    }
    __builtin_amdgcn_s_setprio(1);
#pragma unroll
    for (int kh = 0; kh < 2; ++kh) {
      int sb = (kh << 6) + (quad << 4);
      bf16x8 ap0 = *(bf16x8*)((char*)Ps + (wm + m16) * 128 + (sb ^ swz));
      bf16x8 ap1 = *(bf16x8*)((char*)Ps + (wm + 16 + m16) * 128 + (sb ^ swz));
      bf16x8 bv0 = *(bf16x8*)&Vd[cur][wn + m16][(kh << 5) + (quad << 3)];
      bf16x8 bv1 = *(bf16x8*)&Vd[cur][wn + 16 + m16][(kh << 5) + (quad << 3)];
      m00 = MFMA(ap0, bv0, m00);
      m01 = MFMA(ap0, bv1, m01);
      m10 = MFMA(ap1, bv0, m10);
      m11 = MFMA(ap1, bv1, m11);
    }
    __builtin_amdgcn_s_setprio(0);
    __syncthreads();   // B3: PV done; staged tile + Ps safe for next iter
    cur ^= 1;
  }

  // ---------------- main branch (16 tiles of Kh/Vt) ----------------
  f32x4 o00 = zero, o01 = zero, o10 = zero, o11 = zero;
  float rsa[2] = {0.f, 0.f};
  const bf16* kbase = Kh + ((long long)b * SK + lrow) * HD + lcol;
  const bf16* vbase = Vt + ((long long)b * HD + lrow) * SK + lcol;
  {  // stage main tile 0 into buf1 (last mem iter read buf0; buf1 idle)
    bf16x8 k0 = *(const bf16x8*)kbase;
    bf16x8 k1 = *(const bf16x8*)(kbase + 8);
    bf16x8 v0 = *(const bf16x8*)vbase;
    bf16x8 v1 = *(const bf16x8*)(vbase + 8);
    *(bf16x8*)&Kd[1][lrow][lcol] = k0;
    *(bf16x8*)&Kd[1][lrow][lcol + 8] = k1;
    *(bf16x8*)&Vd[1][lrow][lcol] = v0;
    *(bf16x8*)&Vd[1][lrow][lcol + 8] = v1;
  }
  __syncthreads();
  cur = 1;
  for (int st = 0; st < 16; ++st) {
    bf16x8 kr0, kr1, vr0, vr1;
    if (st < 15) {
      const bf16* kp = kbase + (long long)((st + 1) << 6) * HD;
      const bf16* vp = vbase + ((st + 1) << 6);
      kr0 = *(const bf16x8*)kp;
      kr1 = *(const bf16x8*)(kp + 8);
      vr0 = *(const bf16x8*)vp;
      vr1 = *(const bf16x8*)(vp + 8);
    }
    f32x4 s00 = zero, s01 = zero, s10 = zero, s11 = zero;
    __builtin_amdgcn_s_setprio(1);
#pragma unroll
    for (int kh = 0; kh < 2; ++kh) {
      bf16x8 ak0 = *(bf16x8*)&Kd[cur][wn + m16][(kh << 5) + (quad << 3)];
      bf16x8 ak1 = *(bf16x8*)&Kd[cur][wn + 16 + m16][(kh << 5) + (quad << 3)];
      s00 = MFMA(ak0, aq[0][kh], s00);
      s01 = MFMA(ak0, aq[1][kh], s01);
      s10 = MFMA(ak1, aq[0][kh], s10);
      s11 = MFMA(ak1, aq[1][kh], s11);
    }
    __builtin_amdgcn_s_setprio(0);
    {
      char* pA = (char*)Ps + (wm + m16) * 128;
      char* pB = (char*)Ps + (wm + 16 + m16) * 128;
#pragma unroll
      for (int si = 0; si < 2; ++si) {
        int sloc = wn + (si << 4) + (quad << 2);
        f32x4 rc4 = *(const f32x4*)&rcs[(st << 6) + sloc];
        f32x4 sA = si ? s10 : s00;
        f32x4 sB = si ? s11 : s01;
        __bf16 vA[4], vB[4];
#pragma unroll
        for (int r = 0; r < 4; ++r) {
          float pa = __expf(sA[r]) * rc4[r];
          rsa[0] += pa; vA[r] = tobf(pa);
          float pb = __expf(sB[r]) * rc4[r];
          rsa[1] += pb; vB[r] = tobf(pb);
        }
        int sbyte = (sloc << 1) ^ swz;
        *(uint2*)(pA + sbyte) = *(uint2*)vA;
        *(uint2*)(pB + sbyte) = *(uint2*)vB;
      }
    }
    __syncthreads();   // B2
    if (st < 15) {
      *(bf16x8*)&Kd[cur ^ 1][lrow][lcol] = kr0;
      *(bf16x8*)&Kd[cur ^ 1][lrow][lcol + 8] = kr1;
      *(bf16x8*)&Vd[cur ^ 1][lrow][lcol] = vr0;
      *(bf16x8*)&Vd[cur ^ 1][lrow][lcol + 8] = vr1;
    }
    __builtin_amdgcn_s_setprio(1);
#pragma unroll
    for (int kh = 0; kh < 2; ++kh) {
      int sb = (kh << 6) + (quad << 4);
      bf16x8 ap0 = *(bf16x8*)((char*)Ps + (wm + m16) * 128 + (sb ^ swz));
      bf16x8 ap1 = *(bf16x8*)((char*)Ps + (wm + 16 + m16) * 128 + (sb ^ swz));
      bf16x8 bv0 = *(bf16x8*)&Vd[cur][wn + m16][(kh << 5) + (quad << 3)];
      bf16x8 bv1 = *(bf16x8*)&Vd[cur][wn + 16 + m16][(kh << 5) + (quad << 3)];
      o00 = MFMA(ap0, bv0, o00);
      o01 = MFMA(ap0, bv1, o01);
      o10 = MFMA(ap1, bv0, o10);
      o11 = MFMA(ap1, bv1, o11);
    }
    __builtin_amdgcn_s_setprio(0);
    __syncthreads();   // B3
    cur ^= 1;
  }

  // ---------------- reductions (both branches) ----------------
#pragma unroll
  for (int li = 0; li < 2; ++li) {
    float va = rsa[li];
    va += __shfl_xor(va, 16, 64);
    va += __shfl_xor(va, 32, 64);
    float vm = rsm[li];
    vm += __shfl_xor(vm, 16, 64);
    vm += __shfl_xor(vm, 32, 64);
    if (quad == 0) {
      rpa[wm + (li << 4) + m16][wn >> 5] = va;
      rpm[wm + (li << 4) + m16][wn >> 5] = vm;
    }
  }
  __syncthreads();

  // ---------------- gate combine in f32, single bf16 write ----------------
  const float* vs = Vsum + b * HD;
  const float g = 1.f / (1.f + __expf(-gate[h]));
  f32x4 oacc[2][2] = {{o00, o01}, {o10, o11}};
  f32x4 macc[2][2] = {{m00, m01}, {m10, m11}};
  for (int mi = 0; mi < 2; ++mi)
    for (int ni = 0; ni < 2; ++ni) {
      int col = wn + (ni << 4) + m16;
      float vsc = 1e-8f * vs[col];
      for (int r = 0; r < 4; ++r) {
        int row = wm + (mi << 4) + (quad << 2) + r;
        float ra = rpa[row][0] + rpa[row][1];
        float rm = rpm[row][0] + rpm[row][1];
        float oa = (oacc[mi][ni][r] + vsc) / (ra + (float)SK * 1e-8f);
        float om = macc[mi][ni][r] / rm;
        Kd[0][row][col] = tobf(g * om + (1.f - g) * oa);
      }
    }
  __syncthreads();
  uint4 u0 = *(uint4*)&Kd[0][lrow][lcol];
  uint4 u1 = *(uint4*)&Kd[0][lrow][lcol + 8];
  long long gb = ((long long)b * LQ + tm0 + lrow) * HD + lcol;
  *(uint4*)(comb + gb) = u0;
  *(uint4*)(comb + gb + 8) = u1;
}

// ================= out proj, m97-structure (A = fused comb buffer) ===============
__global__ __launch_bounds__(256) void gemm_out(
    const bf16* __restrict__ comb, const bf16* __restrict__ opwb,
    const float* __restrict__ opb, float* __restrict__ out)
{
  __shared__ __align__(16) char smem[32768];
  __bf16* As = (__bf16*)smem;             // [128][64] linear
  __bf16* Bs = (__bf16*)(smem + 16384);   // [128][64] linear
  const int bid2 = blockIdx.y * gridDim.x + blockIdx.x;  // 0..255
  const int xcd = bid2 & 7, sub = bid2 >> 3;             // sub in [0,32)
  const int by = (xcd << 3) + (sub >> 2);                // 0..63
  const int bx = sub & 3;                                // 0..3
  const int tm0 = by << 7, tn0 = bx << 7;
  const int t = threadIdx.x;
  const int wave = t >> 6, lane = t & 63;
  const int wrow0 = (wave & 1) << 6, wcol0 = (wave >> 1) << 6;
  const int m16 = lane & 15, quad = lane >> 4;

  const f32x4 zero = {0.f, 0.f, 0.f, 0.f};
  f32x4 acc[4][4];
#pragma unroll
  for (int mi = 0; mi < 4; ++mi)
#pragma unroll
    for (int ni = 0; ni < 4; ++ni) acc[mi][ni] = zero;

  const bf16* Bb = opwb + (long long)tn0 * EE;
  const int ob_u = wave << 10;

  for (int k0 = 0; k0 < EE; k0 += 64) {
    const int h = k0 >> 6;
#pragma unroll
    for (int c = 0; c < 4; ++c) {
      int ob = (c << 12) + ob_u;
      int obl = ob + (lane << 4);
      int row = obl >> 7;
      int ce = (obl & 127) >> 1;
      int arow = tm0 + row;
      int l = arow >> 3, nn = arow & 7;
      gload_lds16(comb + (((long long)(nn * NH + h) * LQ + l) * HD + ce),
                  smem + ob);
      gload_lds16(Bb + (long long)row * EE + k0 + ce, smem + 16384 + ob);
    }
    __syncthreads();
#pragma unroll
    for (int kh = 0; kh < 2; ++kh) {
      bf16x8 av[4], bv[4];
#pragma unroll
      for (int i = 0; i < 4; ++i) {
        av[i] = *(bf16x8*)(As + ((wrow0 + (i << 4) + m16) << 6) + (kh << 5) + (quad << 3));
        bv[i] = *(bf16x8*)(Bs + ((wcol0 + (i << 4) + m16) << 6) + (kh << 5) + (quad << 3));
      }
#pragma unroll
      for (int mi = 0; mi < 4; ++mi)
#pragma unroll
        for (int ni = 0; ni < 4; ++ni)
          acc[mi][ni] = MFMA(av[mi], bv[ni], acc[mi][ni]);
    }
    __syncthreads();
  }

  // direct f32 epilogue (16-lane-contiguous 64B segments)
#pragma unroll
  for (int mi = 0; mi < 4; ++mi)
#pragma unroll
    for (int ni = 0; ni < 4; ++ni) {
      int col = tn0 + wcol0 + (ni << 4) + m16;
      float bv = opb[col];
      int row0 = tm0 + wrow0 + (mi << 4) + (quad << 2);
#pragma unroll
      for (int r = 0; r < 4; ++r)
        out[(long long)(row0 + r) * EE + col] = acc[mi][ni][r] + bv;
    }
}

// ================= LDS-tiled transposes (no 2B-granular scatter) =================
__global__ __launch_bounds__(256) void v_transpose(
    const bf16* __restrict__ raw, bf16* __restrict__ Vt)
{
  __shared__ __align__(16) __bf16 Ts[64][72];
  const int bh = blockIdx.y;             // n*NH + h
  const int n = bh >> 3, h = bh & 7;
  const int s0 = blockIdx.x << 6;
  const int t = threadIdx.x;
  const int i = t >> 2, c0 = (t & 3) << 4;
  const bf16* rp = raw + ((long long)(s0 + i) * NB + n) * EE + h * HD + c0;
  *(bf16x8*)&Ts[i][c0] = *(const bf16x8*)rp;
  *(bf16x8*)&Ts[i][c0 + 8] = *(const bf16x8*)(rp + 8);
  __syncthreads();
  const int d = t >> 2, j0 = (t & 3) << 4;
  __bf16 vals[16];
#pragma unroll
  for (int j = 0; j < 16; ++j) vals[j] = Ts[j0 + j][d];
  bf16* wp = Vt + ((long long)bh * HD + d) * SK + s0 + j0;
  *(uint4*)wp = *(uint4*)&vals[0];
  *(uint4*)(wp + 8) = *(uint4*)&vals[8];
}

__global__ __launch_bounds__(256) void mem_prep(
    const float* __restrict__ k_mem, const float* __restrict__ v_mem,
    bf16* __restrict__ km, bf16* __restrict__ vmt)
{
  __shared__ __align__(16) __bf16 Ts[64][72];
  const int bh = blockIdx.y;             // n*NH + h
  const int n = bh >> 3, h = bh & 7;
  const int m0 = blockIdx.x << 6;
  const int t = threadIdx.x;
  const int i = t >> 2, c0 = (t & 3) << 4;
  const float* kp = k_mem + ((long long)(m0 + i) * NB + n) * EE + h * HD + c0;
  const float* vp = v_mem + ((long long)(m0 + i) * NB + n) * EE + h * HD + c0;
  bf16x8 kv0 = load8(kp), kv1 = load8(kp + 8);
  bf16x8 vv0 = load8(vp), vv1 = load8(vp + 8);
  bf16* kw = km + ((long long)bh * MMEM + m0 + i) * HD + c0;
  *(bf16x8*)kw = kv0;
  *(bf16x8*)(kw + 8) = kv1;
  *(bf16x8*)&Ts[i][c0] = vv0;
  *(bf16x8*)&Ts[i][c0 + 8] = vv1;
  __syncthreads();
  const int d = t >> 2, j0 = (t & 3) << 4;
  __bf16 vals[16];
#pragma unroll
  for (int j = 0; j < 16; ++j) vals[j] = Ts[j0 + j][d];
  bf16* wp = vmt + ((long long)bh * HD + d) * MMEM + m0 + j0;
  *(uint4*)wp = *(uint4*)&vals[0];
  *(uint4*)(wp + 8) = *(uint4*)&vals[8];
}

extern "C" void kernel_launch(void* const* d_in, const int* in_sizes, int n_in,
                              void* d_out, int out_size, void* d_ws, size_t ws_size,
                              hipStream_t stream) {
  const float* query = (const float*)d_in[0];
  const float* key   = (const float*)d_in[1];
  const float* value = (const float*)d_in[2];
  const float* ipw   = (const float*)d_in[3];
  const float* ipb   = (const float*)d_in[4];
  const float* opw   = (const float*)d_in[5];
  const float* opb   = (const float*)d_in[6];
  const float* rot_q = (const float*)d_in[7];
  const float* rot_k = (const float*)d_in[8];
  const float* k_mem = (const float*)d_in[9];
  const float* v_mem = (const float*)d_in[10];
  const float* gate  = (const float*)d_in[11];
  const int*  mask   = (const int*)d_in[12];
  float* out = (float*)d_out;

  char* w = (char*)d_ws;
  size_t off = 0;
  auto carve = [&](size_t bytes) -> char* {
    char* p = w + off;
    off += (bytes + 255) & ~(size_t)255;
    return p;
  };
  bf16* qc    = (bf16*)carve((size_t)LQ * NB * EE * 2);
  bf16* kc    = (bf16*)carve((size_t)SK * NB * EE * 2);
  bf16* vc    = (bf16*)carve((size_t)SK * NB * EE * 2);
  bf16* ipwb  = (bf16*)carve((size_t)3 * EE * EE * 2);
  bf16* opwb  = (bf16*)carve((size_t)EE * EE * 2);
  bf16* v_raw = (bf16*)carve((size_t)SK * NB * EE * 2);
  bf16* Qh    = (bf16*)carve((size_t)NBH * LQ * HD * 2);
  bf16* Kh    = (bf16*)carve((size_t)NBH * SK * HD * 2);
  bf16* Vt    = (bf16*)carve((size_t)NBH * HD * SK * 2);
  bf16* km    = (bf16*)carve((size_t)NBH * MMEM * HD * 2);
  bf16* vmt   = (bf16*)carve((size_t)NBH * HD * MMEM * 2);
  float* csum = (float*)carve((size_t)NBH * SK * 4);
  float* Vsum = (float*)carve((size_t)NBH * HD * 4);
  bf16* comb  = (bf16*)carve((size_t)NBH * LQ * HD * 2);
  bf16* pkbuf = (bf16*)carve((size_t)NBH * LQ * HD * 2);
  if (off > ws_size) {
    hipMemsetAsync(d_out, 0, (size_t)out_size * 4, stream);
    return;
  }
  // pq aliases comb: comb is only written by attn_fused, well after rotary
  // consumed pq. pkbuf is rotary's K staging.
  bf16* pq = comb;
  bf16* pk = pkbuf;

  // 0) pre-convert GEMM inputs to bf16
  convert5<<<(3 * CVT_T0 + CVT_T3 + CVT_T4) / 256, 256, 0, stream>>>(
      query, key, value, ipw, opw, qc, kc, vc, ipwb, opwb);

  // 1) q/k/v projections, pure GEMM (128x128 m97 structure, XCD-swizzled)
  gemm_proj3<<<dim3(EE / 128, (LQ * NB) / 128, 3), 256, 0, stream>>>(
      qc, kc, vc, ipwb, ipb, pq, pk, v_raw);

  // 1b) rotary + head reshape as a pure streaming kernel
  rotary_kernel<<<dim3((LQ * NB) / 4, 2), 256, 0, stream>>>(
      pq, pk, rot_q, rot_k, Qh, Kh);

  // 2) v transpose (LDS-tiled) + Vsum; mem k/v repack (LDS-tiled)
  v_transpose<<<dim3(SK / 64, NBH), 256, 0, stream>>>(v_raw, Vt);
  vsum_kernel<<<(NBH * HD) / 4, 256, 0, stream>>>(Vt, Vsum);
  mem_prep<<<dim3(MMEM / 64, NBH), 256, 0, stream>>>(k_mem, v_mem, km, vmt);

  // 3) column sums of exp(scores) (XCD-swizzled, Q-dbuf, 1 barrier/iter)
  colsum_kernel<<<dim3(SK / 64, NBH), 256, 0, stream>>>(Qh, Kh, csum);

  // 4) fused flash (K/V dbuf, 2 barriers/iter, gate combine, XCD-swizzled)
  attn_fused<<<dim3(LQ / 64, NBH), 256, 0, stream>>>(
      Qh, Kh, Vt, km, vmt, csum, Vsum, mask, gate, comb);

  // 5) out-proj, m97 structure, single A buffer
  gemm_out<<<dim3(4, 64), 256, 0, stream>>>(comb, opwb, opb, out);
}